// Round 4
// baseline (674.807 us; speedup 1.0000x reference)
//
#include <hip/hip_runtime.h>
#include <hip/hip_bf16.h>

#define DEV __device__ __forceinline__

typedef __attribute__((ext_vector_type(8))) short s8v;     // 8 bf16 (4 VGPR)
typedef __attribute__((ext_vector_type(16))) float f32x16; // MFMA 32x32 acc

DEV float siluf(float x){ return x / (1.f + expf(-x)); }

DEV float wredsum(float v){
  #pragma unroll
  for(int m = 32; m; m >>= 1) v += __shfl_xor(v, m);
  return v;
}

DEV unsigned short bf16rne(float f){
  unsigned int u = __float_as_uint(f);
  u += 0x7FFFu + ((u >> 16) & 1u);
  return (unsigned short)(u >> 16);
}
DEV float bf16tof(unsigned short h){ return __uint_as_float(((unsigned int)h) << 16); }

// ---- stats layout (float offsets within stats block) ----
#define S1 0
#define Q1 16
#define S2 32
#define Q2 64
#define S3 96
#define Q3 160
#define S4 224
#define Q4 288
#define S5 352
#define Q5 416
#define SLOSS 480
#define NSTATF 512

// Rescore if quantized gap (1/256 units) <= EPSQ. 16/256 = 0.0625 value-gap,
// ~5x margin over bf16-split error (<=0.01) + 2-quanta quantization noise.
#define EPSQ 16u
#define NCHUNK 8

// =========================================================================
// K_prep: transpose enc_w3 [64][32][25] -> w3t [(i*25+k)*64 + c]
//         transpose dec_wt [64][64][25] -> dwtt [(i*25+k)*64 + o]
__global__ void k_prep(const float* ew3, const float* dwt, float* w3t, float* dwtt){
  const int n1 = 64*32*25, n2 = 64*64*25;
  for(int i = blockIdx.x*blockDim.x + threadIdx.x; i < n1+n2; i += gridDim.x*blockDim.x){
    if(i < n1){
      int c = i/(32*25), r = i - c*(32*25), ii = r/25, k = r - ii*25;
      w3t[(ii*25 + k)*64 + c] = ew3[i];
    } else {
      int j = i - n1;
      int ii = j/(64*25), r = j - ii*(64*25), o = r/25, k = r - o*25;
      dwtt[(ii*25 + k)*64 + o] = dwt[j];
    }
  }
}

// =========================================================================
// K_prep2: split codebook to bf16 hi/lo + f32 norms; zero rescore counter.
__global__ void k_prep2(const float* __restrict__ cb, unsigned short* __restrict__ cbh,
                        unsigned short* __restrict__ cbl, float* __restrict__ cnw,
                        int* cnt){
  if(blockIdx.x == 0 && threadIdx.x == 0) *cnt = 0;
  int j = blockIdx.x*256 + threadIdx.x;
  if(j < 8192){
    float nrm = 0.f;
    #pragma unroll
    for(int k = 0; k < 64; k += 4){
      float4 v = *(const float4*)(cb + (size_t)j*64 + k);
      float vv[4] = {v.x, v.y, v.z, v.w};
      #pragma unroll
      for(int c = 0; c < 4; c++){
        float x = vv[c];
        unsigned short hi = bf16rne(x);
        float lo = x - bf16tof(hi);
        cbh[(size_t)j*64 + k + c] = hi;
        cbl[(size_t)j*64 + k + c] = bf16rne(lo);
        nrm = fmaf(x, x, nrm);
      }
    }
    cnw[j] = nrm;
  }
}

// =========================================================================
// K1: conv1 (1->16, K=5, pad2) + silu + bn1 stats
__global__ void k1(const float* __restrict__ x, const float* __restrict__ w1,
                   const float* __restrict__ b1, float* __restrict__ h1, float* stats){
  __shared__ float xs[260];
  __shared__ float ssum[16], ssq[16];
  int tid = threadIdx.x, b = blockIdx.y, t0 = blockIdx.x*256;
  if(tid < 16){ ssum[tid] = 0.f; ssq[tid] = 0.f; }
  for(int i = tid; i < 260; i += 256){
    int t = t0 + i - 2;
    xs[i] = (t >= 0 && t < 10240) ? x[b*10240 + t] : 0.f;
  }
  __syncthreads();
  int t = t0 + tid;
  #pragma unroll
  for(int c = 0; c < 16; c++){
    float a = b1[c];
    #pragma unroll
    for(int k = 0; k < 5; k++) a = fmaf(w1[c*5+k], xs[tid+k], a);
    a = siluf(a);
    h1[((b*16 + c)*10240) + t] = a;
    float s = wredsum(a), s2 = wredsum(a*a);
    if((tid & 63) == 0){ atomicAdd(&ssum[c], s); atomicAdd(&ssq[c], s2); }
  }
  __syncthreads();
  if(tid < 16){ atomicAdd(stats+S1+tid, ssum[tid]); atomicAdd(stats+Q1+tid, ssq[tid]); }
}

// =========================================================================
// K2: bn1 normalize + conv2 (16->32, K=5, pad2) + silu + bn2 stats
__global__ void k2(const float* __restrict__ h1, const float* __restrict__ w2,
                   const float* __restrict__ b2, const float* __restrict__ g1,
                   const float* __restrict__ bb1, float* __restrict__ h2out, float* stats){
  __shared__ float hs[16*264];
  __shared__ float wl[2560];
  __shared__ float A1[16], B1[16];
  __shared__ float ssum[32], ssq[32];
  int tid = threadIdx.x, b = blockIdx.y, t0 = blockIdx.x*256;
  for(int i = tid; i < 2560; i += 256) wl[i] = w2[i];
  if(tid < 16){
    float mu = stats[S1+tid]/81920.f;
    float var = stats[Q1+tid]/81920.f - mu*mu;
    float rs = rsqrtf(var + 1e-5f);
    A1[tid] = rs*g1[tid];
    B1[tid] = bb1[tid] - mu*rs*g1[tid];
  }
  if(tid < 32){ ssum[tid] = 0.f; ssq[tid] = 0.f; }
  __syncthreads();
  for(int i = tid; i < 16*260; i += 256){
    int ch = i/260, tt = i - ch*260;
    int t = t0 + tt - 2;
    hs[ch*264 + tt] = (t >= 0 && t < 10240) ? (h1[((b*16+ch)*10240)+t]*A1[ch] + B1[ch]) : 0.f;
  }
  __syncthreads();
  int t = t0 + tid;
  float acc[32];
  #pragma unroll
  for(int c = 0; c < 32; c++) acc[c] = b2[c];
  for(int i = 0; i < 16; i++){
    float z0 = hs[i*264+tid], z1 = hs[i*264+tid+1], z2 = hs[i*264+tid+2],
          z3 = hs[i*264+tid+3], z4 = hs[i*264+tid+4];
    #pragma unroll
    for(int c = 0; c < 32; c++){
      const float* wp = &wl[(c*16+i)*5];
      acc[c] = fmaf(wp[0],z0,fmaf(wp[1],z1,fmaf(wp[2],z2,fmaf(wp[3],z3,fmaf(wp[4],z4,acc[c])))));
    }
  }
  #pragma unroll
  for(int c = 0; c < 32; c++){
    float a = siluf(acc[c]);
    h2out[((b*32 + c)*10240) + t] = a;
    float s = wredsum(a), s2 = wredsum(a*a);
    if((tid & 63) == 0){ atomicAdd(&ssum[c], s); atomicAdd(&ssq[c], s2); }
  }
  __syncthreads();
  if(tid < 32){ atomicAdd(stats+S2+tid, ssum[tid]); atomicAdd(stats+Q2+tid, ssq[tid]); }
}

// =========================================================================
// K3: bn2 normalize + conv3 (32->64, K=25, stride5, pad12) + tanh + bn3 stats
__global__ void k3(const float* __restrict__ h2, const float* __restrict__ w3t,
                   const float* __restrict__ eb3, const float* __restrict__ g2,
                   const float* __restrict__ bb2, float* __restrict__ zn, float* stats){
  __shared__ float X[5*32*40];
  __shared__ float A2[32], B2[32];
  __shared__ float ssum[64], ssq[64];
  int tid = threadIdx.x, b = blockIdx.y, l0 = blockIdx.x*32;
  if(tid < 32){
    float mu = stats[S2+tid]/81920.f;
    float var = stats[Q2+tid]/81920.f - mu*mu;
    float rs = rsqrtf(var + 1e-5f);
    A2[tid] = rs*g2[tid];
    B2[tid] = bb2[tid] - mu*rs*g2[tid];
  }
  if(tid < 64){ ssum[tid] = 0.f; ssq[tid] = 0.f; }
  __syncthreads();
  for(int i2 = tid; i2 < 5*32*36; i2 += 256){
    int kk = i2/(32*36);
    int r  = i2 - kk*(32*36);
    int ch = r/36, m = r - ch*36;
    int t = 5*(l0 + m) + kk - 12;
    float v = 0.f;
    if(t >= 0 && t < 10240) v = h2[((b*32+ch)*10240)+t]*A2[ch] + B2[ch];
    X[(kk*32+ch)*40 + m] = v;
  }
  __syncthreads();
  int c = tid & 63, lslot = tid >> 6;
  float acc[8];
  float bias = eb3[c];
  #pragma unroll
  for(int s = 0; s < 8; s++) acc[s] = bias;
  for(int i = 0; i < 32; i++){
    #pragma unroll
    for(int kk = 0; kk < 5; kk++){
      float z[12];
      #pragma unroll
      for(int j = 0; j < 12; j++) z[j] = X[(kk*32+i)*40 + lslot*8 + j];
      #pragma unroll
      for(int kap = 0; kap < 5; kap++){
        float w = w3t[(i*25 + kap*5 + kk)*64 + c];
        #pragma unroll
        for(int s = 0; s < 8; s++) acc[s] = fmaf(w, z[s+kap], acc[s]);
      }
    }
  }
  float ls = 0.f, lq = 0.f;
  #pragma unroll
  for(int s = 0; s < 8; s++){
    int l = l0 + lslot*8 + s;
    float a = tanhf(acc[s]);
    zn[((b*2048 + l)*64) + c] = a;
    ls += a; lq += a*a;
  }
  atomicAdd(&ssum[c], ls); atomicAdd(&ssq[c], lq);
  __syncthreads();
  if(tid < 64){ atomicAdd(stats+S3+tid, ssum[tid]); atomicAdd(stats+Q3+tid, ssq[tid]); }
}

// =========================================================================
// K3b: bn3 normalize zn in place
__global__ void k3b(float* zn, const float* g3, const float* b3, const float* stats){
  __shared__ float A[64], B[64];
  int tid = threadIdx.x;
  if(tid < 64){
    float mu = stats[S3+tid]/16384.f;
    float var = stats[Q3+tid]/16384.f - mu*mu;
    float rs = rsqrtf(var + 1e-5f);
    A[tid] = rs*g3[tid];
    B[tid] = b3[tid] - mu*rs*g3[tid];
  }
  __syncthreads();
  for(int i = blockIdx.x*256 + tid; i < 16384*64; i += gridDim.x*256){
    int c = i & 63;
    zn[i] = zn[i]*A[c] + B[c];
  }
}

// =========================================================================
// K5m: MFMA VQ distance pass, packed-key argmin.
// key = ((uint)((d+1024)*256) << 13) | col : min-key == (dist, lowest col).
// Grid (NCHUNK=8 chunks, 256 row-groups); 4 waves (2x2), wave = 32x32 quadrant.
// C/D layout: col=lane&31, row=(reg&3)+8*(reg>>2)+4*(lane>>5)  [HW-verified]
__global__ __launch_bounds__(256) void k5m(const float* __restrict__ zn,
    const unsigned short* __restrict__ cbh, const unsigned short* __restrict__ cbl,
    const float* __restrict__ cnw, unsigned int* __restrict__ pbk,
    unsigned int* __restrict__ psk){
  int tid = threadIdx.x;
  int chunk = blockIdx.x;        // codes [chunk*1024, +1024)
  int m0 = blockIdx.y * 64;      // row group
  int lane = tid & 63, widx = tid >> 6;
  int wr = widx >> 1, wc = widx & 1;
  int h = lane >> 5;
  int row = m0 + wr*32 + (lane & 31);

  // A (z) fragments: resident in registers for the whole kernel
  s8v ah[4], al[4];
  #pragma unroll
  for(int s = 0; s < 4; s++){
    int koff = s*16 + h*8;
    const float* zp = zn + (size_t)row*64 + koff;
    #pragma unroll
    for(int i = 0; i < 8; i++){
      float v = zp[i];
      unsigned short hi = bf16rne(v);
      float lo = v - bf16tof(hi);
      ah[s][i] = (short)hi;
      al[s][i] = (short)bf16rne(lo);
    }
  }

  unsigned int bk[16], sk[16];
  #pragma unroll
  for(int r = 0; r < 16; r++){ bk[r] = 0xFFFFFFFFu; sk[r] = 0xFFFFFFFFu; }
  f32x16 zv;
  #pragma unroll
  for(int i = 0; i < 16; i++) zv[i] = 0.f;

  int c0 = chunk * (8192/NCHUNK);
  for(int it = 0; it < (8192/NCHUNK)/64; ++it){
    int col = c0 + it*64 + wc*32 + (lane & 31);
    const short* bhp = (const short*)(cbh) + (size_t)col*64;
    const short* blp = (const short*)(cbl) + (size_t)col*64;
    s8v bh[4], bl[4];
    #pragma unroll
    for(int s = 0; s < 4; s++){
      bh[s] = *(const s8v*)(bhp + s*16 + h*8);
      bl[s] = *(const s8v*)(blp + s*16 + h*8);
    }
    float cnv = cnw[col];
    f32x16 a1 = __builtin_amdgcn_mfma_f32_32x32x16_bf16(ah[0], bh[0], zv, 0, 0, 0);
    f32x16 a2 = __builtin_amdgcn_mfma_f32_32x32x16_bf16(al[0], bh[0], zv, 0, 0, 0);
    a2 = __builtin_amdgcn_mfma_f32_32x32x16_bf16(ah[0], bl[0], a2, 0, 0, 0);
    #pragma unroll
    for(int s = 1; s < 4; s++){
      a1 = __builtin_amdgcn_mfma_f32_32x32x16_bf16(ah[s], bh[s], a1, 0, 0, 0);
      a2 = __builtin_amdgcn_mfma_f32_32x32x16_bf16(al[s], bh[s], a2, 0, 0, 0);
      a2 = __builtin_amdgcn_mfma_f32_32x32x16_bf16(ah[s], bl[s], a2, 0, 0, 0);
    }
    #pragma unroll
    for(int r = 0; r < 16; r++){
      float d = fmaf(-2.f, a1[r] + a2[r], cnv);
      float q = fminf(fmaf(d, 256.f, 262144.f), 524287.f);   // (d+1024)*256, clamp<2^19
      unsigned int k = (((unsigned int)q) << 13) | (unsigned int)col;
      unsigned int mx = bk[r] > k ? bk[r] : k;
      sk[r] = sk[r] < mx ? sk[r] : mx;
      bk[r] = bk[r] < k ? bk[r] : k;
    }
  }

  // intra-wave merge across 32 cols (xor masks stay within 32-lane halves)
  #pragma unroll
  for(int m = 1; m <= 16; m <<= 1){
    #pragma unroll
    for(int r = 0; r < 16; r++){
      unsigned int ob = (unsigned int)__shfl_xor((int)bk[r], m);
      unsigned int os = (unsigned int)__shfl_xor((int)sk[r], m);
      unsigned int mx = bk[r] > ob ? bk[r] : ob;
      unsigned int mn = bk[r] < ob ? bk[r] : ob;
      unsigned int s2 = sk[r] < os ? sk[r] : os;
      sk[r] = s2 < mx ? s2 : mx;
      bk[r] = mn;
    }
  }

  __shared__ unsigned int redb[64][2], reds[64][2];
  if((lane & 31) == 0){
    #pragma unroll
    for(int r = 0; r < 16; r++){
      int lr = wr*32 + (r&3) + 8*(r>>2) + 4*h;
      redb[lr][wc] = bk[r]; reds[lr][wc] = sk[r];
    }
  }
  __syncthreads();
  if(tid < 64){
    unsigned int b0 = redb[tid][0], b1v = redb[tid][1];
    unsigned int s0 = reds[tid][0], s1v = reds[tid][1];
    unsigned int mx = b0 > b1v ? b0 : b1v;
    unsigned int bb = b0 < b1v ? b0 : b1v;
    unsigned int ss = s0 < s1v ? s0 : s1v;
    ss = ss < mx ? ss : mx;
    size_t o = (size_t)chunk*16384 + m0 + tid;
    pbk[o] = bb;
    psk[o] = ss;
  }
}

// =========================================================================
// K5r: merge NCHUNK chunk partials per row; write idx; flag close calls.
__global__ void k5r(const unsigned int* __restrict__ pbk,
                    const unsigned int* __restrict__ psk, int* __restrict__ idxw,
                    float* __restrict__ out_idx, int* __restrict__ list, int* cnt){
  int row = blockIdx.x*256 + threadIdx.x;  // grid 64
  unsigned int bk = pbk[row], sk = psk[row];
  #pragma unroll
  for(int c = 1; c < NCHUNK; c++){
    unsigned int ob = pbk[(size_t)c*16384 + row];
    unsigned int os = psk[(size_t)c*16384 + row];
    unsigned int mx = bk > ob ? bk : ob;
    bk = bk < ob ? bk : ob;
    sk = sk < os ? sk : os;
    sk = sk < mx ? sk : mx;
  }
  int idx = (int)(bk & 0x1FFFu);
  idxw[row] = idx;
  out_idx[row] = (float)idx;
  if((sk >> 13) - (bk >> 13) <= EPSQ){
    int p = atomicAdd(cnt, 1);
    list[p] = row;
  }
}

// =========================================================================
// K5x: exact f32 rescore of flagged rows (full 8192-code scan per row).
__global__ __launch_bounds__(256) void k5x(const float* __restrict__ zn,
    const float* __restrict__ cb, const int* __restrict__ list, const int* cnt,
    int* __restrict__ idxw, float* __restrict__ out_idx){
  __shared__ float zm2[64];
  __shared__ float rb[4]; __shared__ int ri[4];
  int tid = threadIdx.x;
  int n = *cnt;
  for(int e = blockIdx.x; e < n; e += gridDim.x){
    int row = list[e];
    __syncthreads();
    if(tid < 64) zm2[tid] = -2.f * zn[(size_t)row*64 + tid];
    __syncthreads();
    float bdv = 3.4e38f; int biv = 0;
    int j0 = tid*32;
    for(int j = j0; j < j0+32; j++){
      const float* cp = cb + (size_t)j*64;
      float d = 0.f;
      #pragma unroll
      for(int k = 0; k < 64; k++){
        float c = cp[k];
        d = fmaf(c, c, d);
        d = fmaf(c, zm2[k], d);
      }
      if(d < bdv){ bdv = d; biv = j; }   // ascending j keeps lowest index
    }
    #pragma unroll
    for(int m = 1; m <= 32; m <<= 1){
      float ob = __shfl_xor(bdv, m);
      int   oi = __shfl_xor(biv, m);
      if(ob < bdv || (ob == bdv && oi < biv)){ bdv = ob; biv = oi; }
    }
    if((tid & 63) == 0){ rb[tid>>6] = bdv; ri[tid>>6] = biv; }
    __syncthreads();
    if(tid == 0){
      #pragma unroll
      for(int w = 1; w < 4; w++){
        if(rb[w] < bdv || (rb[w] == bdv && ri[w] < biv)){ bdv = rb[w]; biv = ri[w]; }
      }
      idxw[row] = biv;
      out_idx[row] = (float)biv;
    }
  }
}

// =========================================================================
// K_loss: commit loss from final indices
__global__ void k_loss(const float* __restrict__ zn, const float* __restrict__ cb,
                       const int* __restrict__ idxw, float* stats){
  int row = blockIdx.x*256 + threadIdx.x;  // grid 64
  int code = idxw[row];
  const float* cp = cb + (size_t)code*64;
  const float* zp = zn + (size_t)row*64;
  float s = 0.f;
  #pragma unroll
  for(int k = 0; k < 64; k++){
    float dd = cp[k] - zp[k];
    s = fmaf(dd, dd, s);
  }
  float tot = wredsum(s);
  if((threadIdx.x & 63) == 0) atomicAdd(stats + SLOSS, tot);
}

// =========================================================================
// K6: finalize commit loss (f32 output)
__global__ void k6(const float* stats, float* out){
  if(threadIdx.x == 0) out[0] = 2.f * stats[SLOSS] / 1048576.f;
}

// =========================================================================
// K7: transposed conv (lhs_dilation=5, pad12, K=25) via 5 phase-convs
__global__ void k7(const int* __restrict__ idxp, const float* __restrict__ cb,
                   const float* __restrict__ dwtt, float* __restrict__ h4p, float* stats){
  __shared__ float zq[64*40];
  __shared__ float tb[5*64*33];
  __shared__ float ssum[64], ssq[64];
  int tid = threadIdx.x, b = blockIdx.y, u0 = blockIdx.x*32;
  if(tid < 64){ ssum[tid] = 0.f; ssq[tid] = 0.f; }
  {
    int i = tid & 63, ms = tid >> 6;
    for(int m = ms; m < 37; m += 4){
      int u2 = u0 - 2 + m;
      float v = 0.f;
      if(u2 >= 0 && u2 < 2048){
        int code = idxp[b*2048 + u2];
        v = cb[(size_t)code*64 + i];
      }
      zq[i*40 + m] = v;
    }
  }
  __syncthreads();
  int c = tid & 63, uslot = tid >> 6;
  float acc[5][8];
  #pragma unroll
  for(int v = 0; v < 5; v++)
    #pragma unroll
    for(int s = 0; s < 8; s++) acc[v][s] = 0.f;
  const int km[5] = {2,3,4,0,1};
  const int ov[5] = {2,2,2,3,3};
  for(int i = 0; i < 64; i++){
    float z[13];
    #pragma unroll
    for(int j = 0; j < 13; j++) z[j] = zq[i*40 + uslot*8 + j];
    #pragma unroll
    for(int v = 0; v < 5; v++){
      #pragma unroll
      for(int r = 0; r < 5; r++){
        int k = km[v] + 5*r;
        float w = dwtt[(i*25 + k)*64 + c];
        int off = ov[v] - r + 2;
        #pragma unroll
        for(int s = 0; s < 8; s++) acc[v][s] = fmaf(w, z[s+off], acc[v][s]);
      }
    }
  }
  float ls = 0.f, lq = 0.f;
  #pragma unroll
  for(int v = 0; v < 5; v++){
    #pragma unroll
    for(int s = 0; s < 8; s++){
      int u = u0 + uslot*8 + s;
      float a = siluf(acc[v][s]);
      tb[(v*64 + c)*33 + uslot*8 + s] = a;
      if(v == 0 || u < 2047){ ls += a; lq += a*a; }
    }
  }
  atomicAdd(&ssum[c], ls); atomicAdd(&ssq[c], lq);
  __syncthreads();
  if(tid < 64){ atomicAdd(stats+S4+tid, ssum[tid]); atomicAdd(stats+Q4+tid, ssq[tid]); }
  #pragma unroll
  for(int j = 0; j < 40; j++){
    int flat = tid + 256*j;
    int v = flat / 2048;
    int r = flat - v*2048;
    int cc = r >> 5, ur = r & 31;
    int u = u0 + ur;
    if(v == 0 || u < 2047)
      h4p[(((size_t)v*8 + b)*64 + cc)*2048 + u] = tb[(v*64 + cc)*33 + ur];
  }
}

// =========================================================================
// K8: dbn1 normalize + conv (64->64, K=5, pad2) + bias + silu + dbn2 stats
__global__ void k8(const float* __restrict__ h4p, const float* __restrict__ w2d,
                   const float* __restrict__ b2d, const float* __restrict__ g4,
                   const float* __restrict__ bb4, float* __restrict__ h5, float* stats){
  __shared__ float hw[64*136];
  __shared__ float A4[64], B4[64];
  __shared__ float ssum[64], ssq[64];
  int tid = threadIdx.x, b = blockIdx.y, t0 = blockIdx.x*128;
  if(tid < 64){
    float mu = stats[S4+tid]/81888.f;
    float var = stats[Q4+tid]/81888.f - mu*mu;
    float rs = rsqrtf(var + 1e-5f);
    A4[tid] = rs*g4[tid];
    B4[tid] = bb4[tid] - mu*rs*g4[tid];
    ssum[tid] = 0.f; ssq[tid] = 0.f;
  }
  __syncthreads();
  for(int i2 = tid; i2 < 64*132; i2 += 256){
    int ch = i2/132, tt = i2 - ch*132;
    int t = t0 + tt - 2;
    float v = 0.f;
    if(t >= 0 && t < 10236){
      int vv = t % 5, u = t / 5;
      v = h4p[(((size_t)vv*8 + b)*64 + ch)*2048 + u]*A4[ch] + B4[ch];
    }
    hw[ch*136 + tt] = v;
  }
  __syncthreads();
  int t_rel = tid & 127;
  int chalf = __builtin_amdgcn_readfirstlane(tid >> 7);
  int t = t0 + t_rel;
  float acc[32];
  #pragma unroll
  for(int cc = 0; cc < 32; cc++) acc[cc] = b2d[chalf*32 + cc];
  for(int i = 0; i < 64; i++){
    float z0 = hw[i*136 + t_rel],     z1 = hw[i*136 + t_rel + 1],
          z2 = hw[i*136 + t_rel + 2], z3 = hw[i*136 + t_rel + 3],
          z4 = hw[i*136 + t_rel + 4];
    #pragma unroll
    for(int cc = 0; cc < 32; cc++){
      const float* wp = w2d + ((chalf*32 + cc)*64 + i)*5;
      acc[cc] = fmaf(wp[0],z0,fmaf(wp[1],z1,fmaf(wp[2],z2,fmaf(wp[3],z3,fmaf(wp[4],z4,acc[cc])))));
    }
  }
  bool valid = t < 10236;
  #pragma unroll
  for(int cc = 0; cc < 32; cc++){
    int cch = chalf*32 + cc;
    float a = siluf(acc[cc]);
    float av = valid ? a : 0.f;
    float s = wredsum(av), s2 = wredsum(av*av);
    if((tid & 63) == 0){ atomicAdd(&ssum[cch], s); atomicAdd(&ssq[cch], s2); }
    if(valid) h5[((size_t)(b*64 + cch))*10236 + t] = a;
  }
  __syncthreads();
  if(tid < 64){ atomicAdd(stats+S5+tid, ssum[tid]); atomicAdd(stats+Q5+tid, ssq[tid]); }
}

// =========================================================================
// K9: dbn2 normalize + 1x1 conv (64->1) + bias, pad to 10240, f32 recon
__global__ void k9(const float* __restrict__ h5, const float* __restrict__ w3,
                   const float* __restrict__ b3, const float* __restrict__ g5,
                   const float* __restrict__ bb5, const float* stats,
                   float* __restrict__ out){
  __shared__ float WA[64], WB[64];
  int tid = threadIdx.x;
  if(tid < 64){
    float mu = stats[S5+tid]/81888.f;
    float var = stats[Q5+tid]/81888.f - mu*mu;
    float rs = rsqrtf(var + 1e-5f);
    float A = rs*g5[tid], B = bb5[tid] - mu*rs*g5[tid];
    float w = w3[tid];
    WA[tid] = w*A; WB[tid] = w*B;
  }
  __syncthreads();
  int b = blockIdx.y;
  int t = blockIdx.x*256 + tid;
  float acc = b3[0];
  if(t < 10236){
    const float* hp = h5 + (size_t)(b*64)*10236 + t;
    #pragma unroll
    for(int c = 0; c < 64; c++) acc += WA[c]*hp[(size_t)c*10236] + WB[c];
  } else acc = 0.f;
  out[b*10240 + t] = acc;
}

// =========================================================================
extern "C" void kernel_launch(void* const* d_in, const int* in_sizes, int n_in,
                              void* d_out, int out_size, void* d_ws, size_t ws_size,
                              hipStream_t stream){
  const float* x   = (const float*)d_in[0];
  const float* ew1 = (const float*)d_in[1];
  const float* eb1 = (const float*)d_in[2];
  const float* g1  = (const float*)d_in[3];
  const float* bb1 = (const float*)d_in[4];
  const float* ew2 = (const float*)d_in[5];
  const float* eb2 = (const float*)d_in[6];
  const float* g2  = (const float*)d_in[7];
  const float* bb2 = (const float*)d_in[8];
  const float* ew3 = (const float*)d_in[9];
  const float* eb3 = (const float*)d_in[10];
  const float* g3  = (const float*)d_in[11];
  const float* bb3 = (const float*)d_in[12];
  const float* cb  = (const float*)d_in[13];
  const float* dwt = (const float*)d_in[14];
  const float* g4  = (const float*)d_in[15];
  const float* bb4 = (const float*)d_in[16];
  const float* w2d = (const float*)d_in[17];
  const float* b2d = (const float*)d_in[18];
  const float* g5  = (const float*)d_in[19];
  const float* bb5 = (const float*)d_in[20];
  const float* w3d = (const float*)d_in[21];
  const float* b3d = (const float*)d_in[22];

  char* ws = (char*)d_ws;
  // Phase-disjoint overlays:
  //   [0, 5.24M)  h1 (k1->k2)   then cbh/cbl/cnw (k_prep2->k5m)   then h4p (k7->k8)
  //   [5.24M,15.7M) h2 (k2->k3) then part of h4p
  //   [15.7M,19.9M) zn (k3->k_loss)
  //   [20.97M,...) VQ partials/list/cnt (k5m->k5x), dead before k8 writes h5
  float* h1   = (float*)(ws + 0);
  unsigned short* cbh = (unsigned short*)(ws + 0);          // 1,048,576
  unsigned short* cbl = (unsigned short*)(ws + 1048576);    // 1,048,576
  float* cnw  = (float*)(ws + 2097152);                     // 32,768
  float* h2   = (float*)(ws + 5242880);
  float* zn   = (float*)(ws + 15728640);
  float* h4p  = (float*)(ws + 0);
  float* h5   = (float*)(ws + 20971520);
  int*   list = (int*)  (ws + 20971520);                    // 65,536 (overlays h5, time-disjoint)
  int*   cnt  = (int*)  (ws + 21037056);                    // 256
  unsigned int* pbk = (unsigned int*)(ws + 21037312);       // 524,288 (8 chunks)
  unsigned int* psk = (unsigned int*)(ws + 21561600);       // 524,288
  float* w3t  = (float*)(ws + 41934848);
  float* dwtt = (float*)(ws + 42139648);
  int*   idxw = (int*)  (ws + 42549248);
  float* stats= (float*)(ws + 42614784);
  if(ws_size < 42616832) return;

  float* out = (float*)d_out;  // f32: [recon 81920][idx 16384][loss 1]

  hipMemsetAsync(stats, 0, NSTATF*4, stream);
  k_prep<<<600, 256, 0, stream>>>(ew3, dwt, w3t, dwtt);
  k1<<<dim3(40,8), 256, 0, stream>>>(x, ew1, eb1, h1, stats);
  k2<<<dim3(40,8), 256, 0, stream>>>(h1, ew2, eb2, g1, bb1, h2, stats);
  k_prep2<<<32, 256, 0, stream>>>(cb, cbh, cbl, cnw, cnt);   // after k2 (overlays h1)
  k3<<<dim3(64,8), 256, 0, stream>>>(h2, w3t, eb3, g2, bb2, zn, stats);
  k3b<<<1024, 256, 0, stream>>>(zn, g3, bb3, stats);
  k5m<<<dim3(NCHUNK,256), 256, 0, stream>>>(zn, cbh, cbl, cnw, pbk, psk);
  k5r<<<64, 256, 0, stream>>>(pbk, psk, idxw, out + 81920, list, cnt);
  k5x<<<256, 256, 0, stream>>>(zn, cb, list, cnt, idxw, out + 81920);
  k_loss<<<64, 256, 0, stream>>>(zn, cb, idxw, stats);
  k6<<<1, 64, 0, stream>>>(stats, out + 98304);
  k7<<<dim3(64,8), 256, 0, stream>>>(idxw, cb, dwtt, h4p, stats);
  k8<<<dim3(80,8), 256, 0, stream>>>(h4p, w2d, b2d, g4, bb4, h5, stats);
  k9<<<dim3(40,8), 256, 0, stream>>>(h5, w3d, b3d, g5, bb5, stats, out);
}

// Round 5
// 549.731 us; speedup vs baseline: 1.2275x; 1.2275x over previous
//
#include <hip/hip_runtime.h>
#include <hip/hip_bf16.h>

#define DEV __device__ __forceinline__

typedef __attribute__((ext_vector_type(8))) short s8v;     // 8 bf16 (4 VGPR)
typedef __attribute__((ext_vector_type(16))) float f32x16; // MFMA 32x32 acc
typedef __attribute__((address_space(1))) const unsigned int u32g;
typedef __attribute__((address_space(3))) unsigned int u32l;

DEV void gl_lds(const void* g, void* l){   // 16B async global->LDS
  __builtin_amdgcn_global_load_lds((u32g*)g, (u32l*)l, 16, 0, 0);
}

DEV float siluf(float x){ return x / (1.f + expf(-x)); }

DEV float wredsum(float v){
  #pragma unroll
  for(int m = 32; m; m >>= 1) v += __shfl_xor(v, m);
  return v;
}

DEV unsigned short bf16rne(float f){
  unsigned int u = __float_as_uint(f);
  u += 0x7FFFu + ((u >> 16) & 1u);
  return (unsigned short)(u >> 16);
}
DEV float bf16tof(unsigned short h){ return __uint_as_float(((unsigned int)h) << 16); }

// ---- stats layout (float offsets within stats block) ----
#define S1 0
#define Q1 16
#define S2 32
#define Q2 64
#define S3 96
#define Q3 160
#define S4 224
#define Q4 288
#define S5 352
#define Q5 416
#define SLOSS 480
#define NSTATF 512

#define EPSQ 16u
#define NCHUNK 8

// =========================================================================
// K_prep: transpose enc_w3 [64][32][25] -> w3t [(i*25+k)*64 + c]
//         transpose dec_wt [64][64][25] -> dwtt [(i*25+k)*64 + o]
__global__ void k_prep(const float* ew3, const float* dwt, float* w3t, float* dwtt){
  const int n1 = 64*32*25, n2 = 64*64*25;
  for(int i = blockIdx.x*blockDim.x + threadIdx.x; i < n1+n2; i += gridDim.x*blockDim.x){
    if(i < n1){
      int c = i/(32*25), r = i - c*(32*25), ii = r/25, k = r - ii*25;
      w3t[(ii*25 + k)*64 + c] = ew3[i];
    } else {
      int j = i - n1;
      int ii = j/(64*25), r = j - ii*(64*25), o = r/25, k = r - o*25;
      dwtt[(ii*25 + k)*64 + o] = dwt[j];
    }
  }
}

// =========================================================================
// K_prep2: codebook -> pre-swizzled bf16 hi/lo rows (256B/code) + f32 norms.
// Row layout: logical byte o (hi: o=2d, lo: o=128+2d) stored at o ^ ((code&15)<<4).
// Linear global_load_lds copy then lands XOR-swizzled in LDS (m173 pattern).
__global__ void k_prep2(const float* __restrict__ cb, unsigned short* __restrict__ cbsw,
                        float* __restrict__ cnw, int* cnt){
  if(blockIdx.x == 0 && threadIdx.x == 0) *cnt = 0;
  int j = blockIdx.x*256 + threadIdx.x;
  if(j < 8192){
    float nrm = 0.f;
    unsigned swz = (j & 15) << 4;
    char* rowp = (char*)cbsw + (size_t)j*256;
    #pragma unroll
    for(int k = 0; k < 64; k++){
      float x = cb[(size_t)j*64 + k];
      unsigned short hi = bf16rne(x);
      float lo = x - bf16tof(hi);
      *(unsigned short*)(rowp + (((unsigned)(2*k)) ^ swz)) = hi;
      *(unsigned short*)(rowp + (((unsigned)(128 + 2*k)) ^ swz)) = bf16rne(lo);
      nrm = fmaf(x, x, nrm);
    }
    cnw[j] = nrm;
  }
}

// =========================================================================
// K1: conv1 (1->16, K=5, pad2) + silu + bn1 stats
__global__ void k1(const float* __restrict__ x, const float* __restrict__ w1,
                   const float* __restrict__ b1, float* __restrict__ h1, float* stats){
  __shared__ float xs[260];
  __shared__ float ssum[16], ssq[16];
  int tid = threadIdx.x, b = blockIdx.y, t0 = blockIdx.x*256;
  if(tid < 16){ ssum[tid] = 0.f; ssq[tid] = 0.f; }
  for(int i = tid; i < 260; i += 256){
    int t = t0 + i - 2;
    xs[i] = (t >= 0 && t < 10240) ? x[b*10240 + t] : 0.f;
  }
  __syncthreads();
  int t = t0 + tid;
  #pragma unroll
  for(int c = 0; c < 16; c++){
    float a = b1[c];
    #pragma unroll
    for(int k = 0; k < 5; k++) a = fmaf(w1[c*5+k], xs[tid+k], a);
    a = siluf(a);
    h1[((b*16 + c)*10240) + t] = a;
    float s = wredsum(a), s2 = wredsum(a*a);
    if((tid & 63) == 0){ atomicAdd(&ssum[c], s); atomicAdd(&ssq[c], s2); }
  }
  __syncthreads();
  if(tid < 16){ atomicAdd(stats+S1+tid, ssum[tid]); atomicAdd(stats+Q1+tid, ssq[tid]); }
}

// =========================================================================
// K2: bn1 normalize + conv2 (16->32, K=5, pad2) + silu + bn2 stats
__global__ void k2(const float* __restrict__ h1, const float* __restrict__ w2,
                   const float* __restrict__ b2, const float* __restrict__ g1,
                   const float* __restrict__ bb1, float* __restrict__ h2out, float* stats){
  __shared__ float hs[16*264];
  __shared__ float wl[2560];
  __shared__ float A1[16], B1[16];
  __shared__ float ssum[32], ssq[32];
  int tid = threadIdx.x, b = blockIdx.y, t0 = blockIdx.x*256;
  for(int i = tid; i < 2560; i += 256) wl[i] = w2[i];
  if(tid < 16){
    float mu = stats[S1+tid]/81920.f;
    float var = stats[Q1+tid]/81920.f - mu*mu;
    float rs = rsqrtf(var + 1e-5f);
    A1[tid] = rs*g1[tid];
    B1[tid] = bb1[tid] - mu*rs*g1[tid];
  }
  if(tid < 32){ ssum[tid] = 0.f; ssq[tid] = 0.f; }
  __syncthreads();
  for(int i = tid; i < 16*260; i += 256){
    int ch = i/260, tt = i - ch*260;
    int t = t0 + tt - 2;
    hs[ch*264 + tt] = (t >= 0 && t < 10240) ? (h1[((b*16+ch)*10240)+t]*A1[ch] + B1[ch]) : 0.f;
  }
  __syncthreads();
  int t = t0 + tid;
  float acc[32];
  #pragma unroll
  for(int c = 0; c < 32; c++) acc[c] = b2[c];
  for(int i = 0; i < 16; i++){
    float z0 = hs[i*264+tid], z1 = hs[i*264+tid+1], z2 = hs[i*264+tid+2],
          z3 = hs[i*264+tid+3], z4 = hs[i*264+tid+4];
    #pragma unroll
    for(int c = 0; c < 32; c++){
      const float* wp = &wl[(c*16+i)*5];
      acc[c] = fmaf(wp[0],z0,fmaf(wp[1],z1,fmaf(wp[2],z2,fmaf(wp[3],z3,fmaf(wp[4],z4,acc[c])))));
    }
  }
  #pragma unroll
  for(int c = 0; c < 32; c++){
    float a = siluf(acc[c]);
    h2out[((b*32 + c)*10240) + t] = a;
    float s = wredsum(a), s2 = wredsum(a*a);
    if((tid & 63) == 0){ atomicAdd(&ssum[c], s); atomicAdd(&ssq[c], s2); }
  }
  __syncthreads();
  if(tid < 32){ atomicAdd(stats+S2+tid, ssum[tid]); atomicAdd(stats+Q2+tid, ssq[tid]); }
}

// =========================================================================
// K3: bn2 normalize + conv3 (32->64, K=25, stride5, pad12) + tanh + bn3 stats
__global__ void k3(const float* __restrict__ h2, const float* __restrict__ w3t,
                   const float* __restrict__ eb3, const float* __restrict__ g2,
                   const float* __restrict__ bb2, float* __restrict__ zn, float* stats){
  __shared__ float X[5*32*40];
  __shared__ float A2[32], B2[32];
  __shared__ float ssum[64], ssq[64];
  int tid = threadIdx.x, b = blockIdx.y, l0 = blockIdx.x*32;
  if(tid < 32){
    float mu = stats[S2+tid]/81920.f;
    float var = stats[Q2+tid]/81920.f - mu*mu;
    float rs = rsqrtf(var + 1e-5f);
    A2[tid] = rs*g2[tid];
    B2[tid] = bb2[tid] - mu*rs*g2[tid];
  }
  if(tid < 64){ ssum[tid] = 0.f; ssq[tid] = 0.f; }
  __syncthreads();
  for(int i2 = tid; i2 < 5*32*36; i2 += 256){
    int kk = i2/(32*36);
    int r  = i2 - kk*(32*36);
    int ch = r/36, m = r - ch*36;
    int t = 5*(l0 + m) + kk - 12;
    float v = 0.f;
    if(t >= 0 && t < 10240) v = h2[((b*32+ch)*10240)+t]*A2[ch] + B2[ch];
    X[(kk*32+ch)*40 + m] = v;
  }
  __syncthreads();
  int c = tid & 63, lslot = tid >> 6;
  float acc[8];
  float bias = eb3[c];
  #pragma unroll
  for(int s = 0; s < 8; s++) acc[s] = bias;
  for(int i = 0; i < 32; i++){
    #pragma unroll
    for(int kk = 0; kk < 5; kk++){
      float z[12];
      #pragma unroll
      for(int j = 0; j < 12; j++) z[j] = X[(kk*32+i)*40 + lslot*8 + j];
      #pragma unroll
      for(int kap = 0; kap < 5; kap++){
        float w = w3t[(i*25 + kap*5 + kk)*64 + c];
        #pragma unroll
        for(int s = 0; s < 8; s++) acc[s] = fmaf(w, z[s+kap], acc[s]);
      }
    }
  }
  float ls = 0.f, lq = 0.f;
  #pragma unroll
  for(int s = 0; s < 8; s++){
    int l = l0 + lslot*8 + s;
    float a = tanhf(acc[s]);
    zn[((b*2048 + l)*64) + c] = a;
    ls += a; lq += a*a;
  }
  atomicAdd(&ssum[c], ls); atomicAdd(&ssq[c], lq);
  __syncthreads();
  if(tid < 64){ atomicAdd(stats+S3+tid, ssum[tid]); atomicAdd(stats+Q3+tid, ssq[tid]); }
}

// =========================================================================
// K3b: bn3 normalize zn in place
__global__ void k3b(float* zn, const float* g3, const float* b3, const float* stats){
  __shared__ float A[64], B[64];
  int tid = threadIdx.x;
  if(tid < 64){
    float mu = stats[S3+tid]/16384.f;
    float var = stats[Q3+tid]/16384.f - mu*mu;
    float rs = rsqrtf(var + 1e-5f);
    A[tid] = rs*g3[tid];
    B[tid] = b3[tid] - mu*rs*g3[tid];
  }
  __syncthreads();
  for(int i = blockIdx.x*256 + tid; i < 16384*64; i += gridDim.x*256){
    int c = i & 63;
    zn[i] = zn[i]*A[c] + B[c];
  }
}

// =========================================================================
// K5m v2: MFMA VQ pass with double-buffered LDS codebook staging.
// global_load_lds (linear dest) + pre-swizzled source rows; ds_read_b128 with
// the same XOR -> 2-way bank aliasing (free). 2-phase pipeline, one barrier/tile.
__global__ __launch_bounds__(256) void k5m(const float* __restrict__ zn,
    const unsigned short* __restrict__ cbsw, const float* __restrict__ cnw,
    unsigned int* __restrict__ pbk, unsigned int* __restrict__ psk){
  __shared__ __align__(16) unsigned char cbuf[2][16384];
  __shared__ unsigned int redb[64][2], reds[64][2];
  int tid = threadIdx.x;
  int chunk = blockIdx.x;        // codes [chunk*1024, +1024)
  int m0 = blockIdx.y * 64;
  int lane = tid & 63, widx = tid >> 6;
  int wr = widx >> 1, wc = widx & 1;
  int h = lane >> 5;
  int row = m0 + wr*32 + (lane & 31);

  // A (z) fragments, vectorized loads, resident all kernel
  s8v ah[4], al[4];
  const float* zp = zn + (size_t)row*64;
  #pragma unroll
  for(int s = 0; s < 4; s++){
    float4 v0 = *(const float4*)(zp + s*16 + h*8);
    float4 v1 = *(const float4*)(zp + s*16 + h*8 + 4);
    float vv[8] = {v0.x,v0.y,v0.z,v0.w,v1.x,v1.y,v1.z,v1.w};
    #pragma unroll
    for(int i = 0; i < 8; i++){
      unsigned short hi = bf16rne(vv[i]);
      ah[s][i] = (short)hi;
      al[s][i] = (short)bf16rne(vv[i] - bf16tof(hi));
    }
  }

  unsigned int bk[16], sk[16];
  #pragma unroll
  for(int r = 0; r < 16; r++){ bk[r] = 0xFFFFFFFFu; sk[r] = 0xFFFFFFFFu; }
  f32x16 zv;
  #pragma unroll
  for(int i = 0; i < 16; i++) zv[i] = 0.f;

  int c0 = chunk * 1024;
  const char* csrc = (const char*)cbsw + (size_t)c0*256;
  // prologue: stage tile 0
  #pragma unroll
  for(int c2 = 0; c2 < 4; c2++)
    gl_lds(csrc + c2*4096 + tid*16, &cbuf[0][0] + c2*4096 + tid*16);
  __syncthreads();

  int cl = wc*32 + (lane & 31);
  unsigned swz = (unsigned)(cl & 15) << 4;
  for(int tile = 0; tile < 16; ++tile){
    int bsel = tile & 1;
    if(tile < 15){
      const char* ns = csrc + (size_t)(tile+1)*16384;
      #pragma unroll
      for(int c2 = 0; c2 < 4; c2++)
        gl_lds(ns + c2*4096 + tid*16, &cbuf[bsel^1][0] + c2*4096 + tid*16);
    }
    const unsigned char* bp = &cbuf[bsel][0] + cl*256;
    s8v bh[4], bl[4];
    #pragma unroll
    for(int s = 0; s < 4; s++){
      bh[s] = *(const s8v*)(bp + (((unsigned)(s*32 + h*16)) ^ swz));
      bl[s] = *(const s8v*)(bp + (((unsigned)(128 + s*32 + h*16)) ^ swz));
    }
    int col = c0 + tile*64 + cl;
    float cnv = cnw[col];
    f32x16 a1 = __builtin_amdgcn_mfma_f32_32x32x16_bf16(ah[0], bh[0], zv, 0, 0, 0);
    f32x16 a2 = __builtin_amdgcn_mfma_f32_32x32x16_bf16(al[0], bh[0], zv, 0, 0, 0);
    a2 = __builtin_amdgcn_mfma_f32_32x32x16_bf16(ah[0], bl[0], a2, 0, 0, 0);
    #pragma unroll
    for(int s = 1; s < 4; s++){
      a1 = __builtin_amdgcn_mfma_f32_32x32x16_bf16(ah[s], bh[s], a1, 0, 0, 0);
      a2 = __builtin_amdgcn_mfma_f32_32x32x16_bf16(al[s], bh[s], a2, 0, 0, 0);
      a2 = __builtin_amdgcn_mfma_f32_32x32x16_bf16(ah[s], bl[s], a2, 0, 0, 0);
    }
    #pragma unroll
    for(int r = 0; r < 16; r++){
      float d = fmaf(-2.f, a1[r] + a2[r], cnv);
      float q = fminf(fmaf(d, 256.f, 262144.f), 524287.f);
      unsigned int k = (((unsigned int)q) << 13) | (unsigned int)col;
      unsigned int mx = bk[r] > k ? bk[r] : k;
      sk[r] = sk[r] < mx ? sk[r] : mx;
      bk[r] = bk[r] < k ? bk[r] : k;
    }
    __syncthreads();   // tile+1 staged & everyone done with bsel
  }

  #pragma unroll
  for(int m = 1; m <= 16; m <<= 1){
    #pragma unroll
    for(int r = 0; r < 16; r++){
      unsigned int ob = (unsigned int)__shfl_xor((int)bk[r], m);
      unsigned int os = (unsigned int)__shfl_xor((int)sk[r], m);
      unsigned int mx = bk[r] > ob ? bk[r] : ob;
      unsigned int mn = bk[r] < ob ? bk[r] : ob;
      unsigned int s2 = sk[r] < os ? sk[r] : os;
      sk[r] = s2 < mx ? s2 : mx;
      bk[r] = mn;
    }
  }
  if((lane & 31) == 0){
    #pragma unroll
    for(int r = 0; r < 16; r++){
      int lr = wr*32 + (r&3) + 8*(r>>2) + 4*h;
      redb[lr][wc] = bk[r]; reds[lr][wc] = sk[r];
    }
  }
  __syncthreads();
  if(tid < 64){
    unsigned int b0 = redb[tid][0], b1v = redb[tid][1];
    unsigned int s0 = reds[tid][0], s1v = reds[tid][1];
    unsigned int mx = b0 > b1v ? b0 : b1v;
    unsigned int bb = b0 < b1v ? b0 : b1v;
    unsigned int ss = s0 < s1v ? s0 : s1v;
    ss = ss < mx ? ss : mx;
    size_t o = (size_t)chunk*16384 + m0 + tid;
    pbk[o] = bb;
    psk[o] = ss;
  }
}

// =========================================================================
// K5r: merge chunk partials; write idx; flag close calls.
__global__ void k5r(const unsigned int* __restrict__ pbk,
                    const unsigned int* __restrict__ psk, int* __restrict__ idxw,
                    float* __restrict__ out_idx, int* __restrict__ list, int* cnt){
  int row = blockIdx.x*256 + threadIdx.x;  // grid 64
  unsigned int bk = pbk[row], sk = psk[row];
  #pragma unroll
  for(int c = 1; c < NCHUNK; c++){
    unsigned int ob = pbk[(size_t)c*16384 + row];
    unsigned int os = psk[(size_t)c*16384 + row];
    unsigned int mx = bk > ob ? bk : ob;
    bk = bk < ob ? bk : ob;
    sk = sk < os ? sk : os;
    sk = sk < mx ? sk : mx;
  }
  int idx = (int)(bk & 0x1FFFu);
  idxw[row] = idx;
  out_idx[row] = (float)idx;
  if((sk >> 13) - (bk >> 13) <= EPSQ){
    int p = atomicAdd(cnt, 1);
    list[p] = row;
  }
}

// =========================================================================
// K5x: exact f32 rescore of flagged rows.
__global__ __launch_bounds__(256) void k5x(const float* __restrict__ zn,
    const float* __restrict__ cb, const int* __restrict__ list, const int* cnt,
    int* __restrict__ idxw, float* __restrict__ out_idx){
  __shared__ float zm2[64];
  __shared__ float rb[4]; __shared__ int ri[4];
  int tid = threadIdx.x;
  int n = *cnt;
  for(int e = blockIdx.x; e < n; e += gridDim.x){
    int row = list[e];
    __syncthreads();
    if(tid < 64) zm2[tid] = -2.f * zn[(size_t)row*64 + tid];
    __syncthreads();
    float bdv = 3.4e38f; int biv = 0;
    int j0 = tid*32;
    for(int j = j0; j < j0+32; j++){
      const float* cp = cb + (size_t)j*64;
      float d = 0.f;
      #pragma unroll
      for(int k = 0; k < 64; k++){
        float c = cp[k];
        d = fmaf(c, c, d);
        d = fmaf(c, zm2[k], d);
      }
      if(d < bdv){ bdv = d; biv = j; }
    }
    #pragma unroll
    for(int m = 1; m <= 32; m <<= 1){
      float ob = __shfl_xor(bdv, m);
      int   oi = __shfl_xor(biv, m);
      if(ob < bdv || (ob == bdv && oi < biv)){ bdv = ob; biv = oi; }
    }
    if((tid & 63) == 0){ rb[tid>>6] = bdv; ri[tid>>6] = biv; }
    __syncthreads();
    if(tid == 0){
      #pragma unroll
      for(int w = 1; w < 4; w++){
        if(rb[w] < bdv || (rb[w] == bdv && ri[w] < biv)){ bdv = rb[w]; biv = ri[w]; }
      }
      idxw[row] = biv;
      out_idx[row] = (float)biv;
    }
  }
}

// =========================================================================
// K_loss: commit loss from final indices
__global__ void k_loss(const float* __restrict__ zn, const float* __restrict__ cb,
                       const int* __restrict__ idxw, float* stats){
  int row = blockIdx.x*256 + threadIdx.x;  // grid 64
  int code = idxw[row];
  const float* cp = cb + (size_t)code*64;
  const float* zp = zn + (size_t)row*64;
  float s = 0.f;
  #pragma unroll
  for(int k = 0; k < 64; k++){
    float dd = cp[k] - zp[k];
    s = fmaf(dd, dd, s);
  }
  float tot = wredsum(s);
  if((threadIdx.x & 63) == 0) atomicAdd(stats + SLOSS, tot);
}

// =========================================================================
// K6: finalize commit loss
__global__ void k6(const float* stats, float* out){
  if(threadIdx.x == 0) out[0] = 2.f * stats[SLOSS] / 1048576.f;
}

// =========================================================================
// K7: transposed conv + silu + dbn1 stats. Output: h4t bf16 [b][10248 pad][64ch],
// rows pre-XOR-swizzled (byte ^ ((t&7)<<4)) so k8 can global_load_lds linearly.
__global__ void k7(const int* __restrict__ idxp, const float* __restrict__ cb,
                   const float* __restrict__ dwtt, unsigned short* __restrict__ h4t,
                   float* stats){
  __shared__ float zq[64*40];
  __shared__ float tb[5*64*33];
  __shared__ float ssum[64], ssq[64];
  int tid = threadIdx.x, b = blockIdx.y, u0 = blockIdx.x*32;
  if(tid < 64){ ssum[tid] = 0.f; ssq[tid] = 0.f; }
  {
    int i = tid & 63, ms = tid >> 6;
    for(int m = ms; m < 37; m += 4){
      int u2 = u0 - 2 + m;
      float v = 0.f;
      if(u2 >= 0 && u2 < 2048){
        int code = idxp[b*2048 + u2];
        v = cb[(size_t)code*64 + i];
      }
      zq[i*40 + m] = v;
    }
  }
  __syncthreads();
  int c = tid & 63, uslot = tid >> 6;
  float acc[5][8];
  #pragma unroll
  for(int v = 0; v < 5; v++)
    #pragma unroll
    for(int s = 0; s < 8; s++) acc[v][s] = 0.f;
  const int km[5] = {2,3,4,0,1};
  const int ov[5] = {2,2,2,3,3};
  for(int i = 0; i < 64; i++){
    float z[13];
    #pragma unroll
    for(int j = 0; j < 13; j++) z[j] = zq[i*40 + uslot*8 + j];
    #pragma unroll
    for(int v = 0; v < 5; v++){
      #pragma unroll
      for(int r = 0; r < 5; r++){
        int k = km[v] + 5*r;
        float w = dwtt[(i*25 + k)*64 + c];
        int off = ov[v] - r + 2;
        #pragma unroll
        for(int s = 0; s < 8; s++) acc[v][s] = fmaf(w, z[s+off], acc[v][s]);
      }
    }
  }
  float ls = 0.f, lq = 0.f;
  #pragma unroll
  for(int v = 0; v < 5; v++){
    #pragma unroll
    for(int s = 0; s < 8; s++){
      int u = u0 + uslot*8 + s;
      float a = siluf(acc[v][s]);
      tb[(v*64 + c)*33 + uslot*8 + s] = a;
      if(v == 0 || u < 2047){ ls += a; lq += a*a; }
    }
  }
  atomicAdd(&ssum[c], ls); atomicAdd(&ssq[c], lq);
  __syncthreads();
  if(tid < 64){ atomicAdd(stats+S4+tid, ssum[tid]); atomicAdd(stats+Q4+tid, ssq[tid]); }
  // store: (t, ch-pair) order, bf16 pairs packed to u32, row-swizzled
  #pragma unroll
  for(int j = 0; j < 20; j++){
    int flat = j*256 + tid;          // 5120 ch-pairs
    int tl = flat >> 5;              // 0..159
    int chp = flat & 31;
    int t = u0*5 + tl;
    if(t < 10236){
      int v = tl % 5, ul = tl / 5;
      float f0 = tb[(v*64 + 2*chp)*33 + ul];
      float f1 = tb[(v*64 + 2*chp + 1)*33 + ul];
      unsigned int pk = (unsigned int)bf16rne(f0) | ((unsigned int)bf16rne(f1) << 16);
      size_t rowb = ((size_t)b*10248 + 2 + t)*128;
      *(unsigned int*)((char*)h4t + rowb + (((unsigned)(4*chp)) ^ (((unsigned)t & 7) << 4))) = pk;
    }
  }
}

// =========================================================================
// K8w: fold dbn1 into decoder conv2 weights. W'[c][i][k]=W*A4[i] (bf16,
// swizzled for LDS), beta[c]=b2d[c]+sum W*B4[i]. (Boundary taps deviate on
// 4 of 10236 positions -- far below tolerance.)
__global__ void k8w(const float* __restrict__ w2d, const float* __restrict__ b2d,
                    const float* __restrict__ g4, const float* __restrict__ bb4,
                    const float* __restrict__ stats, unsigned short* __restrict__ wbt,
                    float* __restrict__ beta){
  __shared__ float A4[64], B4[64];
  int tid = threadIdx.x;
  if(tid < 64){
    float mu = stats[S4+tid]/81888.f;
    float var = stats[Q4+tid]/81888.f - mu*mu;
    float rs = rsqrtf(var + 1e-5f);
    A4[tid] = rs*g4[tid];
    B4[tid] = bb4[tid] - mu*rs*g4[tid];
  }
  __syncthreads();
  for(int e = tid; e < 64*64*5; e += 256){
    int c = e/320, r = e - c*320, i = r/5, k = r - i*5;
    unsigned short hw = bf16rne(w2d[e] * A4[i]);
    int row = k*64 + c;
    *(unsigned short*)((char*)wbt + (size_t)row*128 + (((unsigned)(2*i)) ^ (((unsigned)c & 7) << 4))) = hw;
  }
  if(tid < 64){
    float s = b2d[tid];
    for(int i = 0; i < 64; i++){
      float wsum = 0.f;
      #pragma unroll
      for(int k = 0; k < 5; k++) wsum += w2d[(tid*64 + i)*5 + k];
      s += wsum * B4[i];
    }
    beta[tid] = s;
  }
}

// =========================================================================
// K8 v2: decoder conv2 as MFMA GEMM. Block = 128 t x 64 ch, K = 5 taps x 64 in.
// A = h4t window staged via global_load_lds (pre-swizzled rows); B = folded
// weights staged likewise. 4 waves, each 32t x 64ch (two 32x32 acc).
__global__ __launch_bounds__(256) void k8(const unsigned short* __restrict__ h4t,
    const unsigned short* __restrict__ wbt, const float* __restrict__ beta,
    unsigned short* __restrict__ h5b, float* stats){
  __shared__ __align__(16) unsigned char lA[17408];   // 136 rows x 128B
  __shared__ __align__(16) unsigned char lB[40960];   // 320 rows x 128B
  __shared__ float ssum[64], ssq[64];
  int tid = threadIdx.x, b = blockIdx.y, t0 = blockIdx.x*128;
  if(tid < 64){ ssum[tid] = 0.f; ssq[tid] = 0.f; }
  #pragma unroll
  for(int c2 = 0; c2 < 10; c2++)
    gl_lds((const char*)wbt + c2*4096 + tid*16, lB + c2*4096 + tid*16);
  const char* srcA = (const char*)h4t + ((size_t)b*10248 + t0)*128; // rows t0-2..t0+134
  #pragma unroll
  for(int c2 = 0; c2 < 4; c2++)
    gl_lds(srcA + c2*4096 + tid*16, lA + c2*4096 + tid*16);
  if(tid < 64) gl_lds(srcA + 16384 + tid*16, lA + 16384 + tid*16);
  __syncthreads();

  int lane = tid & 63, h = lane >> 5, cl = lane & 31;
  int wt0 = (tid >> 6) * 32;
  f32x16 acc0, acc1;
  #pragma unroll
  for(int i = 0; i < 16; i++){ acc0[i] = 0.f; acc1[i] = 0.f; }
  unsigned bswz = (unsigned)(cl & 7) << 4;
  #pragma unroll
  for(int k = 0; k < 5; k++){
    int l = wt0 + cl + k;                       // LDS row = t - (t0-2)
    unsigned aswz = (unsigned)((l + 6) & 7) << 4; // == (t&7)<<4
    int arow = l*128;
    int brow = (k*64 + cl)*128;
    #pragma unroll
    for(int s = 0; s < 4; s++){
      unsigned o = (unsigned)(s*32 + h*16);
      s8v a  = *(const s8v*)(lA + arow + (o ^ aswz));
      s8v b0 = *(const s8v*)(lB + brow + (o ^ bswz));
      s8v b1 = *(const s8v*)(lB + brow + 4096 + (o ^ bswz));
      acc0 = __builtin_amdgcn_mfma_f32_32x32x16_bf16(a, b0, acc0, 0, 0, 0);
      acc1 = __builtin_amdgcn_mfma_f32_32x32x16_bf16(a, b1, acc1, 0, 0, 0);
    }
  }
  float bet0 = beta[cl], bet1 = beta[32 + cl];
  float ps0 = 0.f, pq0 = 0.f, ps1 = 0.f, pq1 = 0.f;
  #pragma unroll
  for(int r = 0; r < 16; r++){
    int t = t0 + wt0 + (r&3) + 8*(r>>2) + 4*h;
    float v0 = siluf(acc0[r] + bet0);
    float v1 = siluf(acc1[r] + bet1);
    if(t < 10236){
      size_t o = ((size_t)b*10240 + t)*64;
      h5b[o + cl]      = bf16rne(v0);
      h5b[o + 32 + cl] = bf16rne(v1);
      ps0 += v0; pq0 += v0*v0; ps1 += v1; pq1 += v1*v1;
    }
  }
  atomicAdd(&ssum[cl], ps0);      atomicAdd(&ssq[cl], pq0);
  atomicAdd(&ssum[32 + cl], ps1); atomicAdd(&ssq[32 + cl], pq1);
  __syncthreads();
  if(tid < 64){ atomicAdd(stats+S5+tid, ssum[tid]); atomicAdd(stats+Q5+tid, ssq[tid]); }
}

// =========================================================================
// K9: dbn2 normalize + 1x1 conv (64->1) + bias; h5b bf16 [b][t][ch]
__global__ void k9(const unsigned short* __restrict__ h5b, const float* __restrict__ w3,
                   const float* __restrict__ b3, const float* __restrict__ g5,
                   const float* __restrict__ bb5, const float* stats,
                   float* __restrict__ out){
  __shared__ float WA[64], WB[64];
  int tid = threadIdx.x;
  if(tid < 64){
    float mu = stats[S5+tid]/81888.f;
    float var = stats[Q5+tid]/81888.f - mu*mu;
    float rs = rsqrtf(var + 1e-5f);
    float A = rs*g5[tid], B = bb5[tid] - mu*rs*g5[tid];
    float w = w3[tid];
    WA[tid] = w*A; WB[tid] = w*B;
  }
  __syncthreads();
  int b = blockIdx.y;
  int t = blockIdx.x*256 + tid;
  float acc = b3[0];
  if(t < 10236){
    const unsigned short* hp = h5b + ((size_t)b*10240 + t)*64;
    #pragma unroll
    for(int q = 0; q < 8; q++){
      uint4 u = *(const uint4*)(hp + q*8);
      unsigned int ua[4] = {u.x, u.y, u.z, u.w};
      #pragma unroll
      for(int w = 0; w < 4; w++){
        int c = q*8 + w*2;
        acc += WA[c]*bf16tof((unsigned short)(ua[w] & 0xFFFFu)) + WB[c];
        acc += WA[c+1]*bf16tof((unsigned short)(ua[w] >> 16)) + WB[c+1];
      }
    }
  } else acc = 0.f;
  out[b*10240 + t] = acc;
}

// =========================================================================
extern "C" void kernel_launch(void* const* d_in, const int* in_sizes, int n_in,
                              void* d_out, int out_size, void* d_ws, size_t ws_size,
                              hipStream_t stream){
  const float* x   = (const float*)d_in[0];
  const float* ew1 = (const float*)d_in[1];
  const float* eb1 = (const float*)d_in[2];
  const float* g1  = (const float*)d_in[3];
  const float* bb1 = (const float*)d_in[4];
  const float* ew2 = (const float*)d_in[5];
  const float* eb2 = (const float*)d_in[6];
  const float* g2  = (const float*)d_in[7];
  const float* bb2 = (const float*)d_in[8];
  const float* ew3 = (const float*)d_in[9];
  const float* eb3 = (const float*)d_in[10];
  const float* g3  = (const float*)d_in[11];
  const float* bb3 = (const float*)d_in[12];
  const float* cb  = (const float*)d_in[13];
  const float* dwt = (const float*)d_in[14];
  const float* g4  = (const float*)d_in[15];
  const float* bb4 = (const float*)d_in[16];
  const float* w2d = (const float*)d_in[17];
  const float* b2d = (const float*)d_in[18];
  const float* g5  = (const float*)d_in[19];
  const float* bb5 = (const float*)d_in[20];
  const float* w3d = (const float*)d_in[21];
  const float* b3d = (const float*)d_in[22];

  char* ws = (char*)d_ws;
  // Phase-disjoint overlays:
  //  [0,2.13M)  cbsw+cnw (k_prep2 -> k5m)  / h1 (k1->k2, earlier) / h4t (k7->k8, later)
  //  [0,10.49M) h4t bf16 padded [8][10248][64] (memset before k7)
  //  [5.24M,15.73M) h2 (k2->k3); [15.73M,19.92M) zn (k3->k_loss)
  //  [20.97M,31.46M) h5b bf16 (k8->k9); list/cnt/pbk/psk overlay it (dead by k7)
  float* h1   = (float*)(ws + 0);
  unsigned short* cbsw = (unsigned short*)(ws + 0);         // 2,097,152
  float* cnw  = (float*)(ws + 2097152);                     // 32,768
  float* h2   = (float*)(ws + 5242880);
  float* zn   = (float*)(ws + 15728640);
  unsigned short* h4t = (unsigned short*)(ws + 0);          // 10,493,952
  unsigned short* h5b = (unsigned short*)(ws + 20971520);   // 10,485,760
  int*   list = (int*)  (ws + 20971520);                    // 65,536 (time-disjoint)
  int*   cnt  = (int*)  (ws + 21037056);                    // 256
  unsigned int* pbk = (unsigned int*)(ws + 21037312);       // 524,288
  unsigned int* psk = (unsigned int*)(ws + 21561600);       // 524,288
  unsigned short* wbt = (unsigned short*)(ws + 31457280);   // 40,960
  float* beta = (float*)(ws + 31498240);                    // 256
  float* w3t  = (float*)(ws + 41934848);
  float* dwtt = (float*)(ws + 42139648);
  int*   idxw = (int*)  (ws + 42549248);
  float* stats= (float*)(ws + 42614784);
  if(ws_size < 42616832) return;

  float* out = (float*)d_out;  // f32: [recon 81920][idx 16384][loss 1]

  hipMemsetAsync(stats, 0, NSTATF*4, stream);
  k_prep<<<600, 256, 0, stream>>>(ew3, dwt, w3t, dwtt);
  k1<<<dim3(40,8), 256, 0, stream>>>(x, ew1, eb1, h1, stats);
  k2<<<dim3(40,8), 256, 0, stream>>>(h1, ew2, eb2, g1, bb1, h2, stats);
  k_prep2<<<32, 256, 0, stream>>>(cb, cbsw, cnw, cnt);   // after k2 (overlays h1)
  k3<<<dim3(64,8), 256, 0, stream>>>(h2, w3t, eb3, g2, bb2, zn, stats);
  k3b<<<1024, 256, 0, stream>>>(zn, g3, bb3, stats);
  k5m<<<dim3(NCHUNK,256), 256, 0, stream>>>(zn, cbsw, cnw, pbk, psk);
  k5r<<<64, 256, 0, stream>>>(pbk, psk, idxw, out + 81920, list, cnt);
  k5x<<<256, 256, 0, stream>>>(zn, cb, list, cnt, idxw, out + 81920);
  k_loss<<<64, 256, 0, stream>>>(zn, cb, idxw, stats);
  k6<<<1, 64, 0, stream>>>(stats, out + 98304);
  hipMemsetAsync(h4t, 0, 10493952, stream);               // zero incl. pads
  k7<<<dim3(64,8), 256, 0, stream>>>(idxw, cb, dwtt, h4t, stats);
  k8w<<<1, 256, 0, stream>>>(w2d, b2d, g4, bb4, stats, wbt, beta);
  k8<<<dim3(80,8), 256, 0, stream>>>(h4t, wbt, beta, h5b, stats);
  k9<<<dim3(40,8), 256, 0, stream>>>(h5b, w3d, b3d, g5, bb5, stats, out);
}

// Round 6
// 465.598 us; speedup vs baseline: 1.4493x; 1.1807x over previous
//
#include <hip/hip_runtime.h>
#include <hip/hip_bf16.h>

#define DEV __device__ __forceinline__

typedef __attribute__((ext_vector_type(8))) short s8v;     // 8 bf16 (4 VGPR)
typedef __attribute__((ext_vector_type(16))) float f32x16; // MFMA 32x32 acc
typedef __attribute__((address_space(1))) const unsigned int u32g;
typedef __attribute__((address_space(3))) unsigned int u32l;

DEV void gl_lds(const void* g, void* l){   // 16B async global->LDS
  __builtin_amdgcn_global_load_lds((u32g*)g, (u32l*)l, 16, 0, 0);
}

DEV float siluf(float x){ return x / (1.f + expf(-x)); }

DEV float wredsum(float v){
  #pragma unroll
  for(int m = 32; m; m >>= 1) v += __shfl_xor(v, m);
  return v;
}

DEV unsigned short bf16rne(float f){
  unsigned int u = __float_as_uint(f);
  u += 0x7FFFu + ((u >> 16) & 1u);
  return (unsigned short)(u >> 16);
}
DEV float bf16tof(unsigned short h){ return __uint_as_float(((unsigned int)h) << 16); }

// ---- stats layout (float offsets within stats block) ----
#define S1 0
#define Q1 16
#define S2 32
#define Q2 64
#define S3 96
#define Q3 160
#define S4 224
#define Q4 288
#define S5 352
#define Q5 416
#define SLOSS 480
#define NSTATF 512

// Rescore flag threshold in 1/256 quanta. Danger zone = 2*e_m*256 + 2 quanta
// with e_m (3-term bf16-split MFMA error) <= ~1.5e-3 -> ~3 quanta. 6 = 2x margin.
#define EPSQ 6u
#define NCHUNK 8

// =========================================================================
// K_prep: transpose enc_w3 [64][32][25] -> w3t [(i*25+k)*64 + c]
//         transpose dec_wt [64][64][25] -> dwtt [(i*25+k)*64 + o]
__global__ void k_prep(const float* ew3, const float* dwt, float* w3t, float* dwtt){
  const int n1 = 64*32*25, n2 = 64*64*25;
  for(int i = blockIdx.x*blockDim.x + threadIdx.x; i < n1+n2; i += gridDim.x*blockDim.x){
    if(i < n1){
      int c = i/(32*25), r = i - c*(32*25), ii = r/25, k = r - ii*25;
      w3t[(ii*25 + k)*64 + c] = ew3[i];
    } else {
      int j = i - n1;
      int ii = j/(64*25), r = j - ii*(64*25), o = r/25, k = r - o*25;
      dwtt[(ii*25 + k)*64 + o] = dwt[j];
    }
  }
}

// =========================================================================
// K_prep2: codebook -> pre-swizzled bf16 hi/lo rows (256B/code) + f32 norms.
__global__ void k_prep2(const float* __restrict__ cb, unsigned short* __restrict__ cbsw,
                        float* __restrict__ cnw, int* cnt){
  if(blockIdx.x == 0 && threadIdx.x == 0) *cnt = 0;
  int j = blockIdx.x*256 + threadIdx.x;
  if(j < 8192){
    float nrm = 0.f;
    unsigned swz = (j & 15) << 4;
    char* rowp = (char*)cbsw + (size_t)j*256;
    #pragma unroll
    for(int k = 0; k < 64; k++){
      float x = cb[(size_t)j*64 + k];
      unsigned short hi = bf16rne(x);
      float lo = x - bf16tof(hi);
      *(unsigned short*)(rowp + (((unsigned)(2*k)) ^ swz)) = hi;
      *(unsigned short*)(rowp + (((unsigned)(128 + 2*k)) ^ swz)) = bf16rne(lo);
      nrm = fmaf(x, x, nrm);
    }
    cnw[j] = nrm;
  }
}

// =========================================================================
// K1: conv1 (1->16, K=5, pad2) + silu + bn1 stats
__global__ void k1(const float* __restrict__ x, const float* __restrict__ w1,
                   const float* __restrict__ b1, float* __restrict__ h1, float* stats){
  __shared__ float xs[260];
  __shared__ float ssum[16], ssq[16];
  int tid = threadIdx.x, b = blockIdx.y, t0 = blockIdx.x*256;
  if(tid < 16){ ssum[tid] = 0.f; ssq[tid] = 0.f; }
  for(int i = tid; i < 260; i += 256){
    int t = t0 + i - 2;
    xs[i] = (t >= 0 && t < 10240) ? x[b*10240 + t] : 0.f;
  }
  __syncthreads();
  int t = t0 + tid;
  #pragma unroll
  for(int c = 0; c < 16; c++){
    float a = b1[c];
    #pragma unroll
    for(int k = 0; k < 5; k++) a = fmaf(w1[c*5+k], xs[tid+k], a);
    a = siluf(a);
    h1[((b*16 + c)*10240) + t] = a;
    float s = wredsum(a), s2 = wredsum(a*a);
    if((tid & 63) == 0){ atomicAdd(&ssum[c], s); atomicAdd(&ssq[c], s2); }
  }
  __syncthreads();
  if(tid < 16){ atomicAdd(stats+S1+tid, ssum[tid]); atomicAdd(stats+Q1+tid, ssq[tid]); }
}

// =========================================================================
// K2: bn1 normalize + conv2 (16->32, K=5, pad2) + silu + bn2 stats
__global__ void k2(const float* __restrict__ h1, const float* __restrict__ w2,
                   const float* __restrict__ b2, const float* __restrict__ g1,
                   const float* __restrict__ bb1, float* __restrict__ h2out, float* stats){
  __shared__ float hs[16*264];
  __shared__ float wl[2560];
  __shared__ float A1[16], B1[16];
  __shared__ float ssum[32], ssq[32];
  int tid = threadIdx.x, b = blockIdx.y, t0 = blockIdx.x*256;
  for(int i = tid; i < 2560; i += 256) wl[i] = w2[i];
  if(tid < 16){
    float mu = stats[S1+tid]/81920.f;
    float var = stats[Q1+tid]/81920.f - mu*mu;
    float rs = rsqrtf(var + 1e-5f);
    A1[tid] = rs*g1[tid];
    B1[tid] = bb1[tid] - mu*rs*g1[tid];
  }
  if(tid < 32){ ssum[tid] = 0.f; ssq[tid] = 0.f; }
  __syncthreads();
  for(int i = tid; i < 16*260; i += 256){
    int ch = i/260, tt = i - ch*260;
    int t = t0 + tt - 2;
    hs[ch*264 + tt] = (t >= 0 && t < 10240) ? (h1[((b*16+ch)*10240)+t]*A1[ch] + B1[ch]) : 0.f;
  }
  __syncthreads();
  int t = t0 + tid;
  float acc[32];
  #pragma unroll
  for(int c = 0; c < 32; c++) acc[c] = b2[c];
  for(int i = 0; i < 16; i++){
    float z0 = hs[i*264+tid], z1 = hs[i*264+tid+1], z2 = hs[i*264+tid+2],
          z3 = hs[i*264+tid+3], z4 = hs[i*264+tid+4];
    #pragma unroll
    for(int c = 0; c < 32; c++){
      const float* wp = &wl[(c*16+i)*5];
      acc[c] = fmaf(wp[0],z0,fmaf(wp[1],z1,fmaf(wp[2],z2,fmaf(wp[3],z3,fmaf(wp[4],z4,acc[c])))));
    }
  }
  #pragma unroll
  for(int c = 0; c < 32; c++){
    float a = siluf(acc[c]);
    h2out[((b*32 + c)*10240) + t] = a;
    float s = wredsum(a), s2 = wredsum(a*a);
    if((tid & 63) == 0){ atomicAdd(&ssum[c], s); atomicAdd(&ssq[c], s2); }
  }
  __syncthreads();
  if(tid < 32){ atomicAdd(stats+S2+tid, ssum[tid]); atomicAdd(stats+Q2+tid, ssq[tid]); }
}

// =========================================================================
// K3: bn2 normalize + conv3 (32->64, K=25, stride5, pad12) + tanh + bn3 stats
__global__ void k3(const float* __restrict__ h2, const float* __restrict__ w3t,
                   const float* __restrict__ eb3, const float* __restrict__ g2,
                   const float* __restrict__ bb2, float* __restrict__ zn, float* stats){
  __shared__ float X[5*32*40];
  __shared__ float A2[32], B2[32];
  __shared__ float ssum[64], ssq[64];
  int tid = threadIdx.x, b = blockIdx.y, l0 = blockIdx.x*32;
  if(tid < 32){
    float mu = stats[S2+tid]/81920.f;
    float var = stats[Q2+tid]/81920.f - mu*mu;
    float rs = rsqrtf(var + 1e-5f);
    A2[tid] = rs*g2[tid];
    B2[tid] = bb2[tid] - mu*rs*g2[tid];
  }
  if(tid < 64){ ssum[tid] = 0.f; ssq[tid] = 0.f; }
  __syncthreads();
  for(int i2 = tid; i2 < 5*32*36; i2 += 256){
    int kk = i2/(32*36);
    int r  = i2 - kk*(32*36);
    int ch = r/36, m = r - ch*36;
    int t = 5*(l0 + m) + kk - 12;
    float v = 0.f;
    if(t >= 0 && t < 10240) v = h2[((b*32+ch)*10240)+t]*A2[ch] + B2[ch];
    X[(kk*32+ch)*40 + m] = v;
  }
  __syncthreads();
  int c = tid & 63, lslot = tid >> 6;
  float acc[8];
  float bias = eb3[c];
  #pragma unroll
  for(int s = 0; s < 8; s++) acc[s] = bias;
  for(int i = 0; i < 32; i++){
    #pragma unroll
    for(int kk = 0; kk < 5; kk++){
      float z[12];
      #pragma unroll
      for(int j = 0; j < 12; j++) z[j] = X[(kk*32+i)*40 + lslot*8 + j];
      #pragma unroll
      for(int kap = 0; kap < 5; kap++){
        float w = w3t[(i*25 + kap*5 + kk)*64 + c];
        #pragma unroll
        for(int s = 0; s < 8; s++) acc[s] = fmaf(w, z[s+kap], acc[s]);
      }
    }
  }
  float ls = 0.f, lq = 0.f;
  #pragma unroll
  for(int s = 0; s < 8; s++){
    int l = l0 + lslot*8 + s;
    float a = tanhf(acc[s]);
    zn[((b*2048 + l)*64) + c] = a;
    ls += a; lq += a*a;
  }
  atomicAdd(&ssum[c], ls); atomicAdd(&ssq[c], lq);
  __syncthreads();
  if(tid < 64){ atomicAdd(stats+S3+tid, ssum[tid]); atomicAdd(stats+Q3+tid, ssq[tid]); }
}

// =========================================================================
// K3b: bn3 normalize zn in place
__global__ void k3b(float* zn, const float* g3, const float* b3, const float* stats){
  __shared__ float A[64], B[64];
  int tid = threadIdx.x;
  if(tid < 64){
    float mu = stats[S3+tid]/16384.f;
    float var = stats[Q3+tid]/16384.f - mu*mu;
    float rs = rsqrtf(var + 1e-5f);
    A[tid] = rs*g3[tid];
    B[tid] = b3[tid] - mu*rs*g3[tid];
  }
  __syncthreads();
  for(int i = blockIdx.x*256 + tid; i < 16384*64; i += gridDim.x*256){
    int c = i & 63;
    zn[i] = zn[i]*A[c] + B[c];
  }
}

// =========================================================================
// K5m: MFMA VQ pass with double-buffered LDS codebook staging (unchanged).
__global__ __launch_bounds__(256) void k5m(const float* __restrict__ zn,
    const unsigned short* __restrict__ cbsw, const float* __restrict__ cnw,
    unsigned int* __restrict__ pbk, unsigned int* __restrict__ psk){
  __shared__ __align__(16) unsigned char cbuf[2][16384];
  __shared__ unsigned int redb[64][2], reds[64][2];
  int tid = threadIdx.x;
  int chunk = blockIdx.x;
  int m0 = blockIdx.y * 64;
  int lane = tid & 63, widx = tid >> 6;
  int wr = widx >> 1, wc = widx & 1;
  int h = lane >> 5;
  int row = m0 + wr*32 + (lane & 31);

  s8v ah[4], al[4];
  const float* zp = zn + (size_t)row*64;
  #pragma unroll
  for(int s = 0; s < 4; s++){
    float4 v0 = *(const float4*)(zp + s*16 + h*8);
    float4 v1 = *(const float4*)(zp + s*16 + h*8 + 4);
    float vv[8] = {v0.x,v0.y,v0.z,v0.w,v1.x,v1.y,v1.z,v1.w};
    #pragma unroll
    for(int i = 0; i < 8; i++){
      unsigned short hi = bf16rne(vv[i]);
      ah[s][i] = (short)hi;
      al[s][i] = (short)bf16rne(vv[i] - bf16tof(hi));
    }
  }

  unsigned int bk[16], sk[16];
  #pragma unroll
  for(int r = 0; r < 16; r++){ bk[r] = 0xFFFFFFFFu; sk[r] = 0xFFFFFFFFu; }
  f32x16 zv;
  #pragma unroll
  for(int i = 0; i < 16; i++) zv[i] = 0.f;

  int c0 = chunk * 1024;
  const char* csrc = (const char*)cbsw + (size_t)c0*256;
  #pragma unroll
  for(int c2 = 0; c2 < 4; c2++)
    gl_lds(csrc + c2*4096 + tid*16, &cbuf[0][0] + c2*4096 + tid*16);
  __syncthreads();

  int cl = wc*32 + (lane & 31);
  unsigned swz = (unsigned)(cl & 15) << 4;
  for(int tile = 0; tile < 16; ++tile){
    int bsel = tile & 1;
    if(tile < 15){
      const char* ns = csrc + (size_t)(tile+1)*16384;
      #pragma unroll
      for(int c2 = 0; c2 < 4; c2++)
        gl_lds(ns + c2*4096 + tid*16, &cbuf[bsel^1][0] + c2*4096 + tid*16);
    }
    const unsigned char* bp = &cbuf[bsel][0] + cl*256;
    s8v bh[4], bl[4];
    #pragma unroll
    for(int s = 0; s < 4; s++){
      bh[s] = *(const s8v*)(bp + (((unsigned)(s*32 + h*16)) ^ swz));
      bl[s] = *(const s8v*)(bp + (((unsigned)(128 + s*32 + h*16)) ^ swz));
    }
    int col = c0 + tile*64 + cl;
    float cnv = cnw[col];
    f32x16 a1 = __builtin_amdgcn_mfma_f32_32x32x16_bf16(ah[0], bh[0], zv, 0, 0, 0);
    f32x16 a2 = __builtin_amdgcn_mfma_f32_32x32x16_bf16(al[0], bh[0], zv, 0, 0, 0);
    a2 = __builtin_amdgcn_mfma_f32_32x32x16_bf16(ah[0], bl[0], a2, 0, 0, 0);
    #pragma unroll
    for(int s = 1; s < 4; s++){
      a1 = __builtin_amdgcn_mfma_f32_32x32x16_bf16(ah[s], bh[s], a1, 0, 0, 0);
      a2 = __builtin_amdgcn_mfma_f32_32x32x16_bf16(al[s], bh[s], a2, 0, 0, 0);
      a2 = __builtin_amdgcn_mfma_f32_32x32x16_bf16(ah[s], bl[s], a2, 0, 0, 0);
    }
    #pragma unroll
    for(int r = 0; r < 16; r++){
      float d = fmaf(-2.f, a1[r] + a2[r], cnv);
      float q = fminf(fmaf(d, 256.f, 262144.f), 524287.f);
      unsigned int k = (((unsigned int)q) << 13) | (unsigned int)col;
      unsigned int mx = bk[r] > k ? bk[r] : k;
      sk[r] = sk[r] < mx ? sk[r] : mx;
      bk[r] = bk[r] < k ? bk[r] : k;
    }
    __syncthreads();
  }

  #pragma unroll
  for(int m = 1; m <= 16; m <<= 1){
    #pragma unroll
    for(int r = 0; r < 16; r++){
      unsigned int ob = (unsigned int)__shfl_xor((int)bk[r], m);
      unsigned int os = (unsigned int)__shfl_xor((int)sk[r], m);
      unsigned int mx = bk[r] > ob ? bk[r] : ob;
      unsigned int mn = bk[r] < ob ? bk[r] : ob;
      unsigned int s2 = sk[r] < os ? sk[r] : os;
      sk[r] = s2 < mx ? s2 : mx;
      bk[r] = mn;
    }
  }
  if((lane & 31) == 0){
    #pragma unroll
    for(int r = 0; r < 16; r++){
      int lr = wr*32 + (r&3) + 8*(r>>2) + 4*h;
      redb[lr][wc] = bk[r]; reds[lr][wc] = sk[r];
    }
  }
  __syncthreads();
  if(tid < 64){
    unsigned int b0 = redb[tid][0], b1v = redb[tid][1];
    unsigned int s0 = reds[tid][0], s1v = reds[tid][1];
    unsigned int mx = b0 > b1v ? b0 : b1v;
    unsigned int bb = b0 < b1v ? b0 : b1v;
    unsigned int ss = s0 < s1v ? s0 : s1v;
    ss = ss < mx ? ss : mx;
    size_t o = (size_t)chunk*16384 + m0 + tid;
    pbk[o] = bb;
    psk[o] = ss;
  }
}

// =========================================================================
// K5r: merge chunk partials; write idx; flag close calls.
__global__ void k5r(const unsigned int* __restrict__ pbk,
                    const unsigned int* __restrict__ psk, int* __restrict__ idxw,
                    float* __restrict__ out_idx, int* __restrict__ list, int* cnt){
  int row = blockIdx.x*256 + threadIdx.x;  // grid 64
  unsigned int bk = pbk[row], sk = psk[row];
  #pragma unroll
  for(int c = 1; c < NCHUNK; c++){
    unsigned int ob = pbk[(size_t)c*16384 + row];
    unsigned int os = psk[(size_t)c*16384 + row];
    unsigned int mx = bk > ob ? bk : ob;
    bk = bk < ob ? bk : ob;
    sk = sk < os ? sk : os;
    sk = sk < mx ? sk : mx;
  }
  int idx = (int)(bk & 0x1FFFu);
  idxw[row] = idx;
  out_idx[row] = (float)idx;
  if((sk >> 13) - (bk >> 13) <= EPSQ){
    int p = atomicAdd(cnt, 1);
    list[p] = row;
  }
}

// =========================================================================
// K5x v2: exact f32 rescore, row-parallel. Wave = 1 flagged row x 64 code
// lanes; z row in VGPRs; codes streamed from L1/L2 (64-code tiles reused
// across the block's 4 waves). Grid (8 chunks x 256 row-slots).
// Writes per-chunk partial (bd, bi) -> merged by k5x2.
__global__ __launch_bounds__(256) void k5x(const float* __restrict__ zn,
    const float* __restrict__ cb, const float* __restrict__ cnw,
    const int* __restrict__ list, const int* cnt,
    float* __restrict__ pxd, int* __restrict__ pxi){
  int tid = threadIdx.x;
  int chunk = blockIdx.x;
  int n = *cnt;
  int rgrp = tid >> 6, cs = tid & 63;
  int c0 = chunk * 1024;
  for(int bat = blockIdx.y; bat*4 < n; bat += 256){
    int e = bat*4 + rgrp;
    int ec = e < n ? e : n-1;
    int row = list[ec];
    // z row into regs (broadcast loads, wave-uniform address)
    float4 zr[16];
    const float4* zp = (const float4*)(zn + (size_t)row*64);
    #pragma unroll
    for(int q = 0; q < 16; q++) zr[q] = zp[q];
    float bd = 3.4e38f; int bi = 0;
    for(int step = 0; step < 16; step++){
      int j = c0 + step*64 + cs;
      const float4* cp = (const float4*)(cb + (size_t)j*64);
      float cnv = cnw[j];
      float da = 0.f, db = 0.f;   // 2-way ILP on the dot chain
      #pragma unroll
      for(int q = 0; q < 16; q += 2){
        float4 ca = cp[q], cb4 = cp[q+1];
        da = fmaf(ca.x, zr[q].x, da);  da = fmaf(ca.y, zr[q].y, da);
        da = fmaf(ca.z, zr[q].z, da);  da = fmaf(ca.w, zr[q].w, da);
        db = fmaf(cb4.x, zr[q+1].x, db); db = fmaf(cb4.y, zr[q+1].y, db);
        db = fmaf(cb4.z, zr[q+1].z, db); db = fmaf(cb4.w, zr[q+1].w, db);
      }
      float d = fmaf(-2.f, da + db, cnv);
      if(d < bd){ bd = d; bi = j; }   // j ascending per lane -> first-min
    }
    // 64-lane lex reduce (d, j)
    #pragma unroll
    for(int m = 1; m <= 32; m <<= 1){
      float od = __shfl_xor(bd, m);
      int   oi = __shfl_xor(bi, m);
      if(od < bd || (od == bd && oi < bi)){ bd = od; bi = oi; }
    }
    if(cs == 0 && e < n){
      pxd[(size_t)chunk*16384 + e] = bd;
      pxi[(size_t)chunk*16384 + e] = bi;
    }
  }
}

// =========================================================================
// K5x2: merge 8 chunk partials per flagged row -> final idx.
__global__ void k5x2(const float* __restrict__ pxd, const int* __restrict__ pxi,
                     const int* __restrict__ list, const int* cnt,
                     int* __restrict__ idxw, float* __restrict__ out_idx){
  int e = blockIdx.x*256 + threadIdx.x;  // grid 64
  int n = *cnt;
  if(e >= n) return;
  float bd = pxd[e]; int bi = pxi[e];
  #pragma unroll
  for(int c = 1; c < NCHUNK; c++){
    float od = pxd[(size_t)c*16384 + e];
    int   oi = pxi[(size_t)c*16384 + e];
    if(od < bd || (od == bd && oi < bi)){ bd = od; bi = oi; }
  }
  int row = list[e];
  idxw[row] = bi;
  out_idx[row] = (float)bi;
}

// =========================================================================
// K_loss: commit loss from final indices
__global__ void k_loss(const float* __restrict__ zn, const float* __restrict__ cb,
                       const int* __restrict__ idxw, float* stats){
  int row = blockIdx.x*256 + threadIdx.x;  // grid 64
  int code = idxw[row];
  const float* cp = cb + (size_t)code*64;
  const float* zp = zn + (size_t)row*64;
  float s = 0.f;
  #pragma unroll
  for(int k = 0; k < 64; k++){
    float dd = cp[k] - zp[k];
    s = fmaf(dd, dd, s);
  }
  float tot = wredsum(s);
  if((threadIdx.x & 63) == 0) atomicAdd(stats + SLOSS, tot);
}

// =========================================================================
// K6: finalize commit loss
__global__ void k6(const float* stats, float* out){
  if(threadIdx.x == 0) out[0] = 2.f * stats[SLOSS] / 1048576.f;
}

// =========================================================================
// K7: transposed conv + silu + dbn1 stats -> h4t bf16 [b][10248 pad][64ch],
// rows pre-XOR-swizzled (byte ^ ((t&7)<<4)).
__global__ void k7(const int* __restrict__ idxp, const float* __restrict__ cb,
                   const float* __restrict__ dwtt, unsigned short* __restrict__ h4t,
                   float* stats){
  __shared__ float zq[64*40];
  __shared__ float tb[5*64*33];
  __shared__ float ssum[64], ssq[64];
  int tid = threadIdx.x, b = blockIdx.y, u0 = blockIdx.x*32;
  if(tid < 64){ ssum[tid] = 0.f; ssq[tid] = 0.f; }
  {
    int i = tid & 63, ms = tid >> 6;
    for(int m = ms; m < 37; m += 4){
      int u2 = u0 - 2 + m;
      float v = 0.f;
      if(u2 >= 0 && u2 < 2048){
        int code = idxp[b*2048 + u2];
        v = cb[(size_t)code*64 + i];
      }
      zq[i*40 + m] = v;
    }
  }
  __syncthreads();
  int c = tid & 63, uslot = tid >> 6;
  float acc[5][8];
  #pragma unroll
  for(int v = 0; v < 5; v++)
    #pragma unroll
    for(int s = 0; s < 8; s++) acc[v][s] = 0.f;
  const int km[5] = {2,3,4,0,1};
  const int ov[5] = {2,2,2,3,3};
  for(int i = 0; i < 64; i++){
    float z[13];
    #pragma unroll
    for(int j = 0; j < 13; j++) z[j] = zq[i*40 + uslot*8 + j];
    #pragma unroll
    for(int v = 0; v < 5; v++){
      #pragma unroll
      for(int r = 0; r < 5; r++){
        int k = km[v] + 5*r;
        float w = dwtt[(i*25 + k)*64 + c];
        int off = ov[v] - r + 2;
        #pragma unroll
        for(int s = 0; s < 8; s++) acc[v][s] = fmaf(w, z[s+off], acc[v][s]);
      }
    }
  }
  float ls = 0.f, lq = 0.f;
  #pragma unroll
  for(int v = 0; v < 5; v++){
    #pragma unroll
    for(int s = 0; s < 8; s++){
      int u = u0 + uslot*8 + s;
      float a = siluf(acc[v][s]);
      tb[(v*64 + c)*33 + uslot*8 + s] = a;
      if(v == 0 || u < 2047){ ls += a; lq += a*a; }
    }
  }
  atomicAdd(&ssum[c], ls); atomicAdd(&ssq[c], lq);
  __syncthreads();
  if(tid < 64){ atomicAdd(stats+S4+tid, ssum[tid]); atomicAdd(stats+Q4+tid, ssq[tid]); }
  #pragma unroll
  for(int j = 0; j < 20; j++){
    int flat = j*256 + tid;
    int tl = flat >> 5;
    int chp = flat & 31;
    int t = u0*5 + tl;
    if(t < 10236){
      int v = tl % 5, ul = tl / 5;
      float f0 = tb[(v*64 + 2*chp)*33 + ul];
      float f1 = tb[(v*64 + 2*chp + 1)*33 + ul];
      unsigned int pk = (unsigned int)bf16rne(f0) | ((unsigned int)bf16rne(f1) << 16);
      size_t rowb = ((size_t)b*10248 + 2 + t)*128;
      *(unsigned int*)((char*)h4t + rowb + (((unsigned)(4*chp)) ^ (((unsigned)t & 7) << 4))) = pk;
    }
  }
}

// =========================================================================
// K8w: fold dbn1 into decoder conv2 weights (bf16, swizzled) + beta.
__global__ void k8w(const float* __restrict__ w2d, const float* __restrict__ b2d,
                    const float* __restrict__ g4, const float* __restrict__ bb4,
                    const float* __restrict__ stats, unsigned short* __restrict__ wbt,
                    float* __restrict__ beta){
  __shared__ float A4[64], B4[64];
  int tid = threadIdx.x;
  if(tid < 64){
    float mu = stats[S4+tid]/81888.f;
    float var = stats[Q4+tid]/81888.f - mu*mu;
    float rs = rsqrtf(var + 1e-5f);
    A4[tid] = rs*g4[tid];
    B4[tid] = bb4[tid] - mu*rs*g4[tid];
  }
  __syncthreads();
  for(int e = tid; e < 64*64*5; e += 256){
    int c = e/320, r = e - c*320, i = r/5, k = r - i*5;
    unsigned short hw = bf16rne(w2d[e] * A4[i]);
    int row = k*64 + c;
    *(unsigned short*)((char*)wbt + (size_t)row*128 + (((unsigned)(2*i)) ^ (((unsigned)c & 7) << 4))) = hw;
  }
  if(tid < 64){
    float s = b2d[tid];
    for(int i = 0; i < 64; i++){
      float wsum = 0.f;
      #pragma unroll
      for(int k = 0; k < 5; k++) wsum += w2d[(tid*64 + i)*5 + k];
      s += wsum * B4[i];
    }
    beta[tid] = s;
  }
}

// =========================================================================
// K8: decoder conv2 as MFMA GEMM (unchanged).
__global__ __launch_bounds__(256) void k8(const unsigned short* __restrict__ h4t,
    const unsigned short* __restrict__ wbt, const float* __restrict__ beta,
    unsigned short* __restrict__ h5b, float* stats){
  __shared__ __align__(16) unsigned char lA[17408];
  __shared__ __align__(16) unsigned char lB[40960];
  __shared__ float ssum[64], ssq[64];
  int tid = threadIdx.x, b = blockIdx.y, t0 = blockIdx.x*128;
  if(tid < 64){ ssum[tid] = 0.f; ssq[tid] = 0.f; }
  #pragma unroll
  for(int c2 = 0; c2 < 10; c2++)
    gl_lds((const char*)wbt + c2*4096 + tid*16, lB + c2*4096 + tid*16);
  const char* srcA = (const char*)h4t + ((size_t)b*10248 + t0)*128;
  #pragma unroll
  for(int c2 = 0; c2 < 4; c2++)
    gl_lds(srcA + c2*4096 + tid*16, lA + c2*4096 + tid*16);
  if(tid < 64) gl_lds(srcA + 16384 + tid*16, lA + 16384 + tid*16);
  __syncthreads();

  int lane = tid & 63, h = lane >> 5, cl = lane & 31;
  int wt0 = (tid >> 6) * 32;
  f32x16 acc0, acc1;
  #pragma unroll
  for(int i = 0; i < 16; i++){ acc0[i] = 0.f; acc1[i] = 0.f; }
  unsigned bswz = (unsigned)(cl & 7) << 4;
  #pragma unroll
  for(int k = 0; k < 5; k++){
    int l = wt0 + cl + k;
    unsigned aswz = (unsigned)((l + 6) & 7) << 4;
    int arow = l*128;
    int brow = (k*64 + cl)*128;
    #pragma unroll
    for(int s = 0; s < 4; s++){
      unsigned o = (unsigned)(s*32 + h*16);
      s8v a  = *(const s8v*)(lA + arow + (o ^ aswz));
      s8v b0 = *(const s8v*)(lB + brow + (o ^ bswz));
      s8v b1 = *(const s8v*)(lB + brow + 4096 + (o ^ bswz));
      acc0 = __builtin_amdgcn_mfma_f32_32x32x16_bf16(a, b0, acc0, 0, 0, 0);
      acc1 = __builtin_amdgcn_mfma_f32_32x32x16_bf16(a, b1, acc1, 0, 0, 0);
    }
  }
  float bet0 = beta[cl], bet1 = beta[32 + cl];
  float ps0 = 0.f, pq0 = 0.f, ps1 = 0.f, pq1 = 0.f;
  #pragma unroll
  for(int r = 0; r < 16; r++){
    int t = t0 + wt0 + (r&3) + 8*(r>>2) + 4*h;
    float v0 = siluf(acc0[r] + bet0);
    float v1 = siluf(acc1[r] + bet1);
    if(t < 10236){
      size_t o = ((size_t)b*10240 + t)*64;
      h5b[o + cl]      = bf16rne(v0);
      h5b[o + 32 + cl] = bf16rne(v1);
      ps0 += v0; pq0 += v0*v0; ps1 += v1; pq1 += v1*v1;
    }
  }
  atomicAdd(&ssum[cl], ps0);      atomicAdd(&ssq[cl], pq0);
  atomicAdd(&ssum[32 + cl], ps1); atomicAdd(&ssq[32 + cl], pq1);
  __syncthreads();
  if(tid < 64){ atomicAdd(stats+S5+tid, ssum[tid]); atomicAdd(stats+Q5+tid, ssq[tid]); }
}

// =========================================================================
// K9: dbn2 normalize + 1x1 conv (64->1) + bias
__global__ void k9(const unsigned short* __restrict__ h5b, const float* __restrict__ w3,
                   const float* __restrict__ b3, const float* __restrict__ g5,
                   const float* __restrict__ bb5, const float* stats,
                   float* __restrict__ out){
  __shared__ float WA[64], WB[64];
  int tid = threadIdx.x;
  if(tid < 64){
    float mu = stats[S5+tid]/81888.f;
    float var = stats[Q5+tid]/81888.f - mu*mu;
    float rs = rsqrtf(var + 1e-5f);
    float A = rs*g5[tid], B = bb5[tid] - mu*rs*g5[tid];
    float w = w3[tid];
    WA[tid] = w*A; WB[tid] = w*B;
  }
  __syncthreads();
  int b = blockIdx.y;
  int t = blockIdx.x*256 + tid;
  float acc = b3[0];
  if(t < 10236){
    const unsigned short* hp = h5b + ((size_t)b*10240 + t)*64;
    #pragma unroll
    for(int q = 0; q < 8; q++){
      uint4 u = *(const uint4*)(hp + q*8);
      unsigned int ua[4] = {u.x, u.y, u.z, u.w};
      #pragma unroll
      for(int w = 0; w < 4; w++){
        int c = q*8 + w*2;
        acc += WA[c]*bf16tof((unsigned short)(ua[w] & 0xFFFFu)) + WB[c];
        acc += WA[c+1]*bf16tof((unsigned short)(ua[w] >> 16)) + WB[c+1];
      }
    }
  } else acc = 0.f;
  out[b*10240 + t] = acc;
}

// =========================================================================
extern "C" void kernel_launch(void* const* d_in, const int* in_sizes, int n_in,
                              void* d_out, int out_size, void* d_ws, size_t ws_size,
                              hipStream_t stream){
  const float* x   = (const float*)d_in[0];
  const float* ew1 = (const float*)d_in[1];
  const float* eb1 = (const float*)d_in[2];
  const float* g1  = (const float*)d_in[3];
  const float* bb1 = (const float*)d_in[4];
  const float* ew2 = (const float*)d_in[5];
  const float* eb2 = (const float*)d_in[6];
  const float* g2  = (const float*)d_in[7];
  const float* bb2 = (const float*)d_in[8];
  const float* ew3 = (const float*)d_in[9];
  const float* eb3 = (const float*)d_in[10];
  const float* g3  = (const float*)d_in[11];
  const float* bb3 = (const float*)d_in[12];
  const float* cb  = (const float*)d_in[13];
  const float* dwt = (const float*)d_in[14];
  const float* g4  = (const float*)d_in[15];
  const float* bb4 = (const float*)d_in[16];
  const float* w2d = (const float*)d_in[17];
  const float* b2d = (const float*)d_in[18];
  const float* g5  = (const float*)d_in[19];
  const float* bb5 = (const float*)d_in[20];
  const float* w3d = (const float*)d_in[21];
  const float* b3d = (const float*)d_in[22];

  char* ws = (char*)d_ws;
  float* h1   = (float*)(ws + 0);
  unsigned short* cbsw = (unsigned short*)(ws + 0);         // 2,097,152
  float* cnw  = (float*)(ws + 2097152);                     // 32,768
  float* h2   = (float*)(ws + 5242880);
  float* zn   = (float*)(ws + 15728640);
  unsigned short* h4t = (unsigned short*)(ws + 0);          // 10,493,952
  unsigned short* h5b = (unsigned short*)(ws + 20971520);   // 10,485,760
  int*   list = (int*)  (ws + 20971520);                    // 65,536 (time-disjoint vs h5b)
  int*   cnt  = (int*)  (ws + 21037056);                    // 256
  unsigned int* pbk = (unsigned int*)(ws + 21037312);       // 524,288
  unsigned int* psk = (unsigned int*)(ws + 21561600);       // 524,288
  float* pxd  = (float*)(ws + 22085888);                    // 524,288
  int*   pxi  = (int*)  (ws + 22610176);                    // 524,288
  unsigned short* wbt = (unsigned short*)(ws + 31457280);   // 40,960
  float* beta = (float*)(ws + 31498240);                    // 256
  float* w3t  = (float*)(ws + 41934848);
  float* dwtt = (float*)(ws + 42139648);
  int*   idxw = (int*)  (ws + 42549248);
  float* stats= (float*)(ws + 42614784);
  if(ws_size < 42616832) return;

  float* out = (float*)d_out;  // f32: [recon 81920][idx 16384][loss 1]

  hipMemsetAsync(stats, 0, NSTATF*4, stream);
  k_prep<<<600, 256, 0, stream>>>(ew3, dwt, w3t, dwtt);
  k1<<<dim3(40,8), 256, 0, stream>>>(x, ew1, eb1, h1, stats);
  k2<<<dim3(40,8), 256, 0, stream>>>(h1, ew2, eb2, g1, bb1, h2, stats);
  k_prep2<<<32, 256, 0, stream>>>(cb, cbsw, cnw, cnt);
  k3<<<dim3(64,8), 256, 0, stream>>>(h2, w3t, eb3, g2, bb2, zn, stats);
  k3b<<<1024, 256, 0, stream>>>(zn, g3, bb3, stats);
  k5m<<<dim3(NCHUNK,256), 256, 0, stream>>>(zn, cbsw, cnw, pbk, psk);
  k5r<<<64, 256, 0, stream>>>(pbk, psk, idxw, out + 81920, list, cnt);
  k5x<<<dim3(NCHUNK,256), 256, 0, stream>>>(zn, cb, cnw, list, cnt, pxd, pxi);
  k5x2<<<64, 256, 0, stream>>>(pxd, pxi, list, cnt, idxw, out + 81920);
  k_loss<<<64, 256, 0, stream>>>(zn, cb, idxw, stats);
  k6<<<1, 64, 0, stream>>>(stats, out + 98304);
  hipMemsetAsync(h4t, 0, 10493952, stream);
  k7<<<dim3(64,8), 256, 0, stream>>>(idxw, cb, dwtt, h4t, stats);
  k8w<<<1, 256, 0, stream>>>(w2d, b2d, g4, bb4, stats, wbt, beta);
  k8<<<dim3(80,8), 256, 0, stream>>>(h4t, wbt, beta, h5b, stats);
  k9<<<dim3(40,8), 256, 0, stream>>>(h5b, w3d, b3d, g5, bb5, stats, out);
}

// Round 7
// 455.305 us; speedup vs baseline: 1.4821x; 1.0226x over previous
//
#include <hip/hip_runtime.h>
#include <hip/hip_bf16.h>

#define DEV __device__ __forceinline__

typedef __attribute__((ext_vector_type(8))) short s8v;     // 8 bf16 (4 VGPR)
typedef __attribute__((ext_vector_type(16))) float f32x16; // MFMA 32x32 acc
typedef __attribute__((address_space(1))) const unsigned int u32g;
typedef __attribute__((address_space(3))) unsigned int u32l;

DEV void gl_lds(const void* g, void* l){   // 16B async global->LDS
  __builtin_amdgcn_global_load_lds((u32g*)g, (u32l*)l, 16, 0, 0);
}

DEV float siluf(float x){ return x / (1.f + expf(-x)); }

DEV float wredsum(float v){
  #pragma unroll
  for(int m = 32; m; m >>= 1) v += __shfl_xor(v, m);
  return v;
}

DEV unsigned short bf16rne(float f){
  unsigned int u = __float_as_uint(f);
  u += 0x7FFFu + ((u >> 16) & 1u);
  return (unsigned short)(u >> 16);
}
DEV float bf16tof(unsigned short h){ return __uint_as_float(((unsigned int)h) << 16); }

// sk' = min(sk, max(bk, k)) given bk<=sk  ==  median(sk, bk, k), one VALU op.
DEV unsigned umed3(unsigned a, unsigned b, unsigned c){
  unsigned d;
  asm("v_med3_u32 %0, %1, %2, %3" : "=v"(d) : "v"(a), "v"(b), "v"(c));
  return d;
}

// ---- stats layout (float offsets within stats block) ----
#define S1 0
#define Q1 16
#define S2 32
#define Q2 64
#define S3 96
#define Q3 160
#define S4 224
#define Q4 288
#define S5 352
#define Q5 416
#define SLOSS 480
#define NSTATF 512

#define EPSQ 6u
#define NCHUNK 8

// =========================================================================
// K_prep: transpose enc_w3 [64][32][25] -> w3t; dec_wt [64][64][25] -> dwtt
__global__ void k_prep(const float* ew3, const float* dwt, float* w3t, float* dwtt){
  const int n1 = 64*32*25, n2 = 64*64*25;
  for(int i = blockIdx.x*blockDim.x + threadIdx.x; i < n1+n2; i += gridDim.x*blockDim.x){
    if(i < n1){
      int c = i/(32*25), r = i - c*(32*25), ii = r/25, k = r - ii*25;
      w3t[(ii*25 + k)*64 + c] = ew3[i];
    } else {
      int j = i - n1;
      int ii = j/(64*25), r = j - ii*(64*25), o = r/25, k = r - o*25;
      dwtt[(ii*25 + k)*64 + o] = dwt[j];
    }
  }
}

// =========================================================================
// K_prep2: codebook -> pre-swizzled bf16 hi/lo rows + norms (raw and folded).
__global__ void k_prep2(const float* __restrict__ cb, unsigned short* __restrict__ cbsw,
                        float* __restrict__ cnw, float* __restrict__ cnw2, int* cnt){
  if(blockIdx.x == 0 && threadIdx.x == 0) *cnt = 0;
  int j = blockIdx.x*256 + threadIdx.x;
  if(j < 8192){
    float nrm = 0.f;
    unsigned swz = (j & 15) << 4;
    char* rowp = (char*)cbsw + (size_t)j*256;
    #pragma unroll
    for(int k = 0; k < 64; k++){
      float x = cb[(size_t)j*64 + k];
      unsigned short hi = bf16rne(x);
      float lo = x - bf16tof(hi);
      *(unsigned short*)(rowp + (((unsigned)(2*k)) ^ swz)) = hi;
      *(unsigned short*)(rowp + (((unsigned)(128 + 2*k)) ^ swz)) = bf16rne(lo);
      nrm = fmaf(x, x, nrm);
    }
    cnw[j] = nrm;
    cnw2[j] = (nrm + 1024.f) * 256.f;   // folded offset+scale for k5m
  }
}

// =========================================================================
// K1: conv1 (1->16, K=5, pad2) + silu + bn1 stats
__global__ void k1(const float* __restrict__ x, const float* __restrict__ w1,
                   const float* __restrict__ b1, float* __restrict__ h1, float* stats){
  __shared__ float xs[260];
  __shared__ float ssum[16], ssq[16];
  int tid = threadIdx.x, b = blockIdx.y, t0 = blockIdx.x*256;
  if(tid < 16){ ssum[tid] = 0.f; ssq[tid] = 0.f; }
  for(int i = tid; i < 260; i += 256){
    int t = t0 + i - 2;
    xs[i] = (t >= 0 && t < 10240) ? x[b*10240 + t] : 0.f;
  }
  __syncthreads();
  int t = t0 + tid;
  #pragma unroll
  for(int c = 0; c < 16; c++){
    float a = b1[c];
    #pragma unroll
    for(int k = 0; k < 5; k++) a = fmaf(w1[c*5+k], xs[tid+k], a);
    a = siluf(a);
    h1[((b*16 + c)*10240) + t] = a;
    float s = wredsum(a), s2 = wredsum(a*a);
    if((tid & 63) == 0){ atomicAdd(&ssum[c], s); atomicAdd(&ssq[c], s2); }
  }
  __syncthreads();
  if(tid < 16){ atomicAdd(stats+S1+tid, ssum[tid]); atomicAdd(stats+Q1+tid, ssq[tid]); }
}

// =========================================================================
// K2: bn1 normalize + conv2 (16->32, K=5, pad2) + silu + bn2 stats
__global__ void k2(const float* __restrict__ h1, const float* __restrict__ w2,
                   const float* __restrict__ b2, const float* __restrict__ g1,
                   const float* __restrict__ bb1, float* __restrict__ h2out, float* stats){
  __shared__ float hs[16*264];
  __shared__ float wl[2560];
  __shared__ float A1[16], B1[16];
  __shared__ float ssum[32], ssq[32];
  int tid = threadIdx.x, b = blockIdx.y, t0 = blockIdx.x*256;
  for(int i = tid; i < 2560; i += 256) wl[i] = w2[i];
  if(tid < 16){
    float mu = stats[S1+tid]/81920.f;
    float var = stats[Q1+tid]/81920.f - mu*mu;
    float rs = rsqrtf(var + 1e-5f);
    A1[tid] = rs*g1[tid];
    B1[tid] = bb1[tid] - mu*rs*g1[tid];
  }
  if(tid < 32){ ssum[tid] = 0.f; ssq[tid] = 0.f; }
  __syncthreads();
  for(int i = tid; i < 16*260; i += 256){
    int ch = i/260, tt = i - ch*260;
    int t = t0 + tt - 2;
    hs[ch*264 + tt] = (t >= 0 && t < 10240) ? (h1[((b*16+ch)*10240)+t]*A1[ch] + B1[ch]) : 0.f;
  }
  __syncthreads();
  int t = t0 + tid;
  float acc[32];
  #pragma unroll
  for(int c = 0; c < 32; c++) acc[c] = b2[c];
  for(int i = 0; i < 16; i++){
    float z0 = hs[i*264+tid], z1 = hs[i*264+tid+1], z2 = hs[i*264+tid+2],
          z3 = hs[i*264+tid+3], z4 = hs[i*264+tid+4];
    #pragma unroll
    for(int c = 0; c < 32; c++){
      const float* wp = &wl[(c*16+i)*5];
      acc[c] = fmaf(wp[0],z0,fmaf(wp[1],z1,fmaf(wp[2],z2,fmaf(wp[3],z3,fmaf(wp[4],z4,acc[c])))));
    }
  }
  #pragma unroll
  for(int c = 0; c < 32; c++){
    float a = siluf(acc[c]);
    h2out[((b*32 + c)*10240) + t] = a;
    float s = wredsum(a), s2 = wredsum(a*a);
    if((tid & 63) == 0){ atomicAdd(&ssum[c], s); atomicAdd(&ssq[c], s2); }
  }
  __syncthreads();
  if(tid < 32){ atomicAdd(stats+S2+tid, ssum[tid]); atomicAdd(stats+Q2+tid, ssq[tid]); }
}

// =========================================================================
// K3: bn2 normalize + conv3 (32->64, K=25, stride5, pad12) + tanh + bn3 stats
__global__ void k3(const float* __restrict__ h2, const float* __restrict__ w3t,
                   const float* __restrict__ eb3, const float* __restrict__ g2,
                   const float* __restrict__ bb2, float* __restrict__ zn, float* stats){
  __shared__ float X[5*32*40];
  __shared__ float A2[32], B2[32];
  __shared__ float ssum[64], ssq[64];
  int tid = threadIdx.x, b = blockIdx.y, l0 = blockIdx.x*32;
  if(tid < 32){
    float mu = stats[S2+tid]/81920.f;
    float var = stats[Q2+tid]/81920.f - mu*mu;
    float rs = rsqrtf(var + 1e-5f);
    A2[tid] = rs*g2[tid];
    B2[tid] = bb2[tid] - mu*rs*g2[tid];
  }
  if(tid < 64){ ssum[tid] = 0.f; ssq[tid] = 0.f; }
  __syncthreads();
  for(int i2 = tid; i2 < 5*32*36; i2 += 256){
    int kk = i2/(32*36);
    int r  = i2 - kk*(32*36);
    int ch = r/36, m = r - ch*36;
    int t = 5*(l0 + m) + kk - 12;
    float v = 0.f;
    if(t >= 0 && t < 10240) v = h2[((b*32+ch)*10240)+t]*A2[ch] + B2[ch];
    X[(kk*32+ch)*40 + m] = v;
  }
  __syncthreads();
  int c = tid & 63, lslot = tid >> 6;
  float acc[8];
  float bias = eb3[c];
  #pragma unroll
  for(int s = 0; s < 8; s++) acc[s] = bias;
  for(int i = 0; i < 32; i++){
    #pragma unroll
    for(int kk = 0; kk < 5; kk++){
      float z[12];
      #pragma unroll
      for(int j = 0; j < 12; j++) z[j] = X[(kk*32+i)*40 + lslot*8 + j];
      #pragma unroll
      for(int kap = 0; kap < 5; kap++){
        float w = w3t[(i*25 + kap*5 + kk)*64 + c];
        #pragma unroll
        for(int s = 0; s < 8; s++) acc[s] = fmaf(w, z[s+kap], acc[s]);
      }
    }
  }
  float ls = 0.f, lq = 0.f;
  #pragma unroll
  for(int s = 0; s < 8; s++){
    int l = l0 + lslot*8 + s;
    float a = tanhf(acc[s]);
    zn[((b*2048 + l)*64) + c] = a;
    ls += a; lq += a*a;
  }
  atomicAdd(&ssum[c], ls); atomicAdd(&ssq[c], lq);
  __syncthreads();
  if(tid < 64){ atomicAdd(stats+S3+tid, ssum[tid]); atomicAdd(stats+Q3+tid, ssq[tid]); }
}

// =========================================================================
// K3b: bn3 normalize zn in place
__global__ void k3b(float* zn, const float* g3, const float* b3, const float* stats){
  __shared__ float A[64], B[64];
  int tid = threadIdx.x;
  if(tid < 64){
    float mu = stats[S3+tid]/16384.f;
    float var = stats[Q3+tid]/16384.f - mu*mu;
    float rs = rsqrtf(var + 1e-5f);
    A[tid] = rs*g3[tid];
    B[tid] = b3[tid] - mu*rs*g3[tid];
  }
  __syncthreads();
  for(int i = blockIdx.x*256 + tid; i < 16384*64; i += gridDim.x*256){
    int c = i & 63;
    zn[i] = zn[i]*A[c] + B[c];
  }
}

// =========================================================================
// K5m: MFMA VQ pass, LDS-staged codebook, lean packed-key epilogue.
// Per element: 2 fma (folded cnw2) + clamp + cvt + lshl_or + med3 + min = 7 ops.
__global__ __launch_bounds__(256, 3) void k5m(const float* __restrict__ zn,
    const unsigned short* __restrict__ cbsw, const float* __restrict__ cnw2,
    unsigned int* __restrict__ pbk, unsigned int* __restrict__ psk){
  __shared__ __align__(16) unsigned char cbuf[2][16384];
  __shared__ unsigned int redb[64][2], reds[64][2];
  int tid = threadIdx.x;
  int chunk = blockIdx.x;
  int m0 = blockIdx.y * 64;
  int lane = tid & 63, widx = tid >> 6;
  int wr = widx >> 1, wc = widx & 1;
  int h = lane >> 5;
  int row = m0 + wr*32 + (lane & 31);

  s8v ah[4], al[4];
  const float* zp = zn + (size_t)row*64;
  #pragma unroll
  for(int s = 0; s < 4; s++){
    float4 v0 = *(const float4*)(zp + s*16 + h*8);
    float4 v1 = *(const float4*)(zp + s*16 + h*8 + 4);
    float vv[8] = {v0.x,v0.y,v0.z,v0.w,v1.x,v1.y,v1.z,v1.w};
    #pragma unroll
    for(int i = 0; i < 8; i++){
      unsigned short hi = bf16rne(vv[i]);
      ah[s][i] = (short)hi;
      al[s][i] = (short)bf16rne(vv[i] - bf16tof(hi));
    }
  }

  unsigned int bk[16], sk[16];
  #pragma unroll
  for(int r = 0; r < 16; r++){ bk[r] = 0xFFFFFFFFu; sk[r] = 0xFFFFFFFFu; }
  f32x16 zv;
  #pragma unroll
  for(int i = 0; i < 16; i++) zv[i] = 0.f;

  int c0 = chunk * 1024;
  const char* csrc = (const char*)cbsw + (size_t)c0*256;
  #pragma unroll
  for(int c2 = 0; c2 < 4; c2++)
    gl_lds(csrc + c2*4096 + tid*16, &cbuf[0][0] + c2*4096 + tid*16);
  __syncthreads();

  int cl = wc*32 + (lane & 31);
  unsigned swz = (unsigned)(cl & 15) << 4;
  unsigned col = (unsigned)(c0 + cl);          // advances by 64/tile
  for(int tile = 0; tile < 16; ++tile){
    int bsel = tile & 1;
    if(tile < 15){
      const char* ns = csrc + (size_t)(tile+1)*16384;
      #pragma unroll
      for(int c2 = 0; c2 < 4; c2++)
        gl_lds(ns + c2*4096 + tid*16, &cbuf[bsel^1][0] + c2*4096 + tid*16);
    }
    const unsigned char* bp = &cbuf[bsel][0] + cl*256;
    s8v bh[4], bl[4];
    #pragma unroll
    for(int s = 0; s < 4; s++){
      bh[s] = *(const s8v*)(bp + (((unsigned)(s*32 + h*16)) ^ swz));
      bl[s] = *(const s8v*)(bp + (((unsigned)(128 + s*32 + h*16)) ^ swz));
    }
    float cnv2 = cnw2[col];
    f32x16 a1 = __builtin_amdgcn_mfma_f32_32x32x16_bf16(ah[0], bh[0], zv, 0, 0, 0);
    f32x16 a2 = __builtin_amdgcn_mfma_f32_32x32x16_bf16(al[0], bh[0], zv, 0, 0, 0);
    a2 = __builtin_amdgcn_mfma_f32_32x32x16_bf16(ah[0], bl[0], a2, 0, 0, 0);
    #pragma unroll
    for(int s = 1; s < 4; s++){
      a1 = __builtin_amdgcn_mfma_f32_32x32x16_bf16(ah[s], bh[s], a1, 0, 0, 0);
      a2 = __builtin_amdgcn_mfma_f32_32x32x16_bf16(al[s], bh[s], a2, 0, 0, 0);
      a2 = __builtin_amdgcn_mfma_f32_32x32x16_bf16(ah[s], bl[s], a2, 0, 0, 0);
    }
    #pragma unroll
    for(int r = 0; r < 16; r++){
      // q = (d + 1024)*256 with d = cnv - 2(a1+a2), folded into 2 fma
      float q = fmaf(-512.f, a1[r], cnv2);
      q = fmaf(-512.f, a2[r], q);
      q = fminf(q, 524287.f);
      unsigned k = (((unsigned)q) << 13) | col;
      unsigned nb = bk[r] < k ? bk[r] : k;     // v_min_u32
      sk[r] = umed3(sk[r], bk[r], k);          // = min(sk, max(bk,k))
      bk[r] = nb;
    }
    col += 64;
    __syncthreads();
  }

  #pragma unroll
  for(int m = 1; m <= 16; m <<= 1){
    #pragma unroll
    for(int r = 0; r < 16; r++){
      unsigned int ob = (unsigned int)__shfl_xor((int)bk[r], m);
      unsigned int os = (unsigned int)__shfl_xor((int)sk[r], m);
      unsigned int s2 = sk[r] < os ? sk[r] : os;
      sk[r] = umed3(s2, bk[r], ob);
      bk[r] = bk[r] < ob ? bk[r] : ob;
    }
  }
  if((lane & 31) == 0){
    #pragma unroll
    for(int r = 0; r < 16; r++){
      int lr = wr*32 + (r&3) + 8*(r>>2) + 4*h;
      redb[lr][wc] = bk[r]; reds[lr][wc] = sk[r];
    }
  }
  __syncthreads();
  if(tid < 64){
    unsigned int b0 = redb[tid][0], b1v = redb[tid][1];
    unsigned int s0 = reds[tid][0], s1v = reds[tid][1];
    unsigned int ss = s0 < s1v ? s0 : s1v;
    ss = umed3(ss, b0, b1v);
    unsigned int bb = b0 < b1v ? b0 : b1v;
    size_t o = (size_t)chunk*16384 + m0 + tid;
    pbk[o] = bb;
    psk[o] = ss;
  }
}

// =========================================================================
// K5r: merge chunk partials; write idx; flag close calls.
__global__ void k5r(const unsigned int* __restrict__ pbk,
                    const unsigned int* __restrict__ psk, int* __restrict__ idxw,
                    float* __restrict__ out_idx, int* __restrict__ list, int* cnt){
  int row = blockIdx.x*256 + threadIdx.x;  // grid 64
  unsigned int bk = pbk[row], sk = psk[row];
  #pragma unroll
  for(int c = 1; c < NCHUNK; c++){
    unsigned int ob = pbk[(size_t)c*16384 + row];
    unsigned int os = psk[(size_t)c*16384 + row];
    unsigned int s2 = sk < os ? sk : os;
    sk = umed3(s2, bk, ob);
    bk = bk < ob ? bk : ob;
  }
  int idx = (int)(bk & 0x1FFFu);
  idxw[row] = idx;
  out_idx[row] = (float)idx;
  if((sk >> 13) - (bk >> 13) <= EPSQ){
    int p = atomicAdd(cnt, 1);
    list[p] = row;
  }
}

// =========================================================================
// K5x: exact f32 rescore, row-parallel (unchanged).
__global__ __launch_bounds__(256) void k5x(const float* __restrict__ zn,
    const float* __restrict__ cb, const float* __restrict__ cnw,
    const int* __restrict__ list, const int* cnt,
    float* __restrict__ pxd, int* __restrict__ pxi){
  int tid = threadIdx.x;
  int chunk = blockIdx.x;
  int n = *cnt;
  int rgrp = tid >> 6, cs = tid & 63;
  int c0 = chunk * 1024;
  for(int bat = blockIdx.y; bat*4 < n; bat += 256){
    int e = bat*4 + rgrp;
    int ec = e < n ? e : n-1;
    int row = list[ec];
    float4 zr[16];
    const float4* zp = (const float4*)(zn + (size_t)row*64);
    #pragma unroll
    for(int q = 0; q < 16; q++) zr[q] = zp[q];
    float bd = 3.4e38f; int bi = 0;
    for(int step = 0; step < 16; step++){
      int j = c0 + step*64 + cs;
      const float4* cp = (const float4*)(cb + (size_t)j*64);
      float cnv = cnw[j];
      float da = 0.f, db = 0.f;
      #pragma unroll
      for(int q = 0; q < 16; q += 2){
        float4 ca = cp[q], cb4 = cp[q+1];
        da = fmaf(ca.x, zr[q].x, da);  da = fmaf(ca.y, zr[q].y, da);
        da = fmaf(ca.z, zr[q].z, da);  da = fmaf(ca.w, zr[q].w, da);
        db = fmaf(cb4.x, zr[q+1].x, db); db = fmaf(cb4.y, zr[q+1].y, db);
        db = fmaf(cb4.z, zr[q+1].z, db); db = fmaf(cb4.w, zr[q+1].w, db);
      }
      float d = fmaf(-2.f, da + db, cnv);
      if(d < bd){ bd = d; bi = j; }
    }
    #pragma unroll
    for(int m = 1; m <= 32; m <<= 1){
      float od = __shfl_xor(bd, m);
      int   oi = __shfl_xor(bi, m);
      if(od < bd || (od == bd && oi < bi)){ bd = od; bi = oi; }
    }
    if(cs == 0 && e < n){
      pxd[(size_t)chunk*16384 + e] = bd;
      pxi[(size_t)chunk*16384 + e] = bi;
    }
  }
}

// =========================================================================
// K5x2: merge chunk partials per flagged row -> final idx.
__global__ void k5x2(const float* __restrict__ pxd, const int* __restrict__ pxi,
                     const int* __restrict__ list, const int* cnt,
                     int* __restrict__ idxw, float* __restrict__ out_idx){
  int e = blockIdx.x*256 + threadIdx.x;  // grid 64
  int n = *cnt;
  if(e >= n) return;
  float bd = pxd[e]; int bi = pxi[e];
  #pragma unroll
  for(int c = 1; c < NCHUNK; c++){
    float od = pxd[(size_t)c*16384 + e];
    int   oi = pxi[(size_t)c*16384 + e];
    if(od < bd || (od == bd && oi < bi)){ bd = od; bi = oi; }
  }
  int row = list[e];
  idxw[row] = bi;
  out_idx[row] = (float)bi;
}

// =========================================================================
// K_loss: commit loss from final indices
__global__ void k_loss(const float* __restrict__ zn, const float* __restrict__ cb,
                       const int* __restrict__ idxw, float* stats){
  int row = blockIdx.x*256 + threadIdx.x;  // grid 64
  int code = idxw[row];
  const float* cp = cb + (size_t)code*64;
  const float* zp = zn + (size_t)row*64;
  float s = 0.f;
  #pragma unroll
  for(int k = 0; k < 64; k++){
    float dd = cp[k] - zp[k];
    s = fmaf(dd, dd, s);
  }
  float tot = wredsum(s);
  if((threadIdx.x & 63) == 0) atomicAdd(stats + SLOSS, tot);
}

// =========================================================================
// K6: finalize commit loss
__global__ void k6(const float* stats, float* out){
  if(threadIdx.x == 0) out[0] = 2.f * stats[SLOSS] / 1048576.f;
}

// =========================================================================
// K7z: zero only h4t pad rows (r in {0,1} U [10238,10248) per batch).
__global__ void k7z(unsigned int* __restrict__ h4t){
  for(int i = threadIdx.x; i < 3072; i += 256){
    int b = i / 384, r = i - b*384;
    int row12 = r >> 5, word = r & 31;
    int row = row12 < 2 ? row12 : 10236 + row12;
    h4t[((size_t)b*10248 + row)*32 + word] = 0u;
  }
}

// =========================================================================
// K7: transposed conv + silu + dbn1 stats -> h4t bf16 [b][10248 pad][64ch],
// rows pre-XOR-swizzled (byte ^ ((t&7)<<4)).
__global__ void k7(const int* __restrict__ idxp, const float* __restrict__ cb,
                   const float* __restrict__ dwtt, unsigned short* __restrict__ h4t,
                   float* stats){
  __shared__ float zq[64*40];
  __shared__ float tb[5*64*33];
  __shared__ float ssum[64], ssq[64];
  int tid = threadIdx.x, b = blockIdx.y, u0 = blockIdx.x*32;
  if(tid < 64){ ssum[tid] = 0.f; ssq[tid] = 0.f; }
  {
    int i = tid & 63, ms = tid >> 6;
    for(int m = ms; m < 37; m += 4){
      int u2 = u0 - 2 + m;
      float v = 0.f;
      if(u2 >= 0 && u2 < 2048){
        int code = idxp[b*2048 + u2];
        v = cb[(size_t)code*64 + i];
      }
      zq[i*40 + m] = v;
    }
  }
  __syncthreads();
  int c = tid & 63, uslot = tid >> 6;
  float acc[5][8];
  #pragma unroll
  for(int v = 0; v < 5; v++)
    #pragma unroll
    for(int s = 0; s < 8; s++) acc[v][s] = 0.f;
  const int km[5] = {2,3,4,0,1};
  const int ov[5] = {2,2,2,3,3};
  for(int i = 0; i < 64; i++){
    float z[13];
    #pragma unroll
    for(int j = 0; j < 13; j++) z[j] = zq[i*40 + uslot*8 + j];
    #pragma unroll
    for(int v = 0; v < 5; v++){
      #pragma unroll
      for(int r = 0; r < 5; r++){
        int k = km[v] + 5*r;
        float w = dwtt[(i*25 + k)*64 + c];
        int off = ov[v] - r + 2;
        #pragma unroll
        for(int s = 0; s < 8; s++) acc[v][s] = fmaf(w, z[s+off], acc[v][s]);
      }
    }
  }
  float ls = 0.f, lq = 0.f;
  #pragma unroll
  for(int v = 0; v < 5; v++){
    #pragma unroll
    for(int s = 0; s < 8; s++){
      int u = u0 + uslot*8 + s;
      float a = siluf(acc[v][s]);
      tb[(v*64 + c)*33 + uslot*8 + s] = a;
      if(v == 0 || u < 2047){ ls += a; lq += a*a; }
    }
  }
  atomicAdd(&ssum[c], ls); atomicAdd(&ssq[c], lq);
  __syncthreads();
  if(tid < 64){ atomicAdd(stats+S4+tid, ssum[tid]); atomicAdd(stats+Q4+tid, ssq[tid]); }
  #pragma unroll
  for(int j = 0; j < 20; j++){
    int flat = j*256 + tid;
    int tl = flat >> 5;
    int chp = flat & 31;
    int t = u0*5 + tl;
    if(t < 10236){
      int v = tl % 5, ul = tl / 5;
      float f0 = tb[(v*64 + 2*chp)*33 + ul];
      float f1 = tb[(v*64 + 2*chp + 1)*33 + ul];
      unsigned int pk = (unsigned int)bf16rne(f0) | ((unsigned int)bf16rne(f1) << 16);
      size_t rowb = ((size_t)b*10248 + 2 + t)*128;
      *(unsigned int*)((char*)h4t + rowb + (((unsigned)(4*chp)) ^ (((unsigned)t & 7) << 4))) = pk;
    }
  }
}

// =========================================================================
// K8w: fold dbn1 into decoder conv2 weights (bf16, swizzled) + beta.
__global__ void k8w(const float* __restrict__ w2d, const float* __restrict__ b2d,
                    const float* __restrict__ g4, const float* __restrict__ bb4,
                    const float* __restrict__ stats, unsigned short* __restrict__ wbt,
                    float* __restrict__ beta){
  __shared__ float A4[64], B4[64];
  int tid = threadIdx.x;
  if(tid < 64){
    float mu = stats[S4+tid]/81888.f;
    float var = stats[Q4+tid]/81888.f - mu*mu;
    float rs = rsqrtf(var + 1e-5f);
    A4[tid] = rs*g4[tid];
    B4[tid] = bb4[tid] - mu*rs*g4[tid];
  }
  __syncthreads();
  for(int e = tid; e < 64*64*5; e += 256){
    int c = e/320, r = e - c*320, i = r/5, k = r - i*5;
    unsigned short hw = bf16rne(w2d[e] * A4[i]);
    int row = k*64 + c;
    *(unsigned short*)((char*)wbt + (size_t)row*128 + (((unsigned)(2*i)) ^ (((unsigned)c & 7) << 4))) = hw;
  }
  if(tid < 64){
    float s = b2d[tid];
    for(int i = 0; i < 64; i++){
      float wsum = 0.f;
      #pragma unroll
      for(int k = 0; k < 5; k++) wsum += w2d[(tid*64 + i)*5 + k];
      s += wsum * B4[i];
    }
    beta[tid] = s;
  }
}

// =========================================================================
// K8: decoder conv2 as MFMA GEMM (unchanged).
__global__ __launch_bounds__(256) void k8(const unsigned short* __restrict__ h4t,
    const unsigned short* __restrict__ wbt, const float* __restrict__ beta,
    unsigned short* __restrict__ h5b, float* stats){
  __shared__ __align__(16) unsigned char lA[17408];
  __shared__ __align__(16) unsigned char lB[40960];
  __shared__ float ssum[64], ssq[64];
  int tid = threadIdx.x, b = blockIdx.y, t0 = blockIdx.x*128;
  if(tid < 64){ ssum[tid] = 0.f; ssq[tid] = 0.f; }
  #pragma unroll
  for(int c2 = 0; c2 < 10; c2++)
    gl_lds((const char*)wbt + c2*4096 + tid*16, lB + c2*4096 + tid*16);
  const char* srcA = (const char*)h4t + ((size_t)b*10248 + t0)*128;
  #pragma unroll
  for(int c2 = 0; c2 < 4; c2++)
    gl_lds(srcA + c2*4096 + tid*16, lA + c2*4096 + tid*16);
  if(tid < 64) gl_lds(srcA + 16384 + tid*16, lA + 16384 + tid*16);
  __syncthreads();

  int lane = tid & 63, h = lane >> 5, cl = lane & 31;
  int wt0 = (tid >> 6) * 32;
  f32x16 acc0, acc1;
  #pragma unroll
  for(int i = 0; i < 16; i++){ acc0[i] = 0.f; acc1[i] = 0.f; }
  unsigned bswz = (unsigned)(cl & 7) << 4;
  #pragma unroll
  for(int k = 0; k < 5; k++){
    int l = wt0 + cl + k;
    unsigned aswz = (unsigned)((l + 6) & 7) << 4;
    int arow = l*128;
    int brow = (k*64 + cl)*128;
    #pragma unroll
    for(int s = 0; s < 4; s++){
      unsigned o = (unsigned)(s*32 + h*16);
      s8v a  = *(const s8v*)(lA + arow + (o ^ aswz));
      s8v b0 = *(const s8v*)(lB + brow + (o ^ bswz));
      s8v b1 = *(const s8v*)(lB + brow + 4096 + (o ^ bswz));
      acc0 = __builtin_amdgcn_mfma_f32_32x32x16_bf16(a, b0, acc0, 0, 0, 0);
      acc1 = __builtin_amdgcn_mfma_f32_32x32x16_bf16(a, b1, acc1, 0, 0, 0);
    }
  }
  float bet0 = beta[cl], bet1 = beta[32 + cl];
  float ps0 = 0.f, pq0 = 0.f, ps1 = 0.f, pq1 = 0.f;
  #pragma unroll
  for(int r = 0; r < 16; r++){
    int t = t0 + wt0 + (r&3) + 8*(r>>2) + 4*h;
    float v0 = siluf(acc0[r] + bet0);
    float v1 = siluf(acc1[r] + bet1);
    if(t < 10236){
      size_t o = ((size_t)b*10240 + t)*64;
      h5b[o + cl]      = bf16rne(v0);
      h5b[o + 32 + cl] = bf16rne(v1);
      ps0 += v0; pq0 += v0*v0; ps1 += v1; pq1 += v1*v1;
    }
  }
  atomicAdd(&ssum[cl], ps0);      atomicAdd(&ssq[cl], pq0);
  atomicAdd(&ssum[32 + cl], ps1); atomicAdd(&ssq[32 + cl], pq1);
  __syncthreads();
  if(tid < 64){ atomicAdd(stats+S5+tid, ssum[tid]); atomicAdd(stats+Q5+tid, ssq[tid]); }
}

// =========================================================================
// K9: dbn2 normalize + 1x1 conv (64->1) + bias
__global__ void k9(const unsigned short* __restrict__ h5b, const float* __restrict__ w3,
                   const float* __restrict__ b3, const float* __restrict__ g5,
                   const float* __restrict__ bb5, const float* stats,
                   float* __restrict__ out){
  __shared__ float WA[64], WB[64];
  int tid = threadIdx.x;
  if(tid < 64){
    float mu = stats[S5+tid]/81888.f;
    float var = stats[Q5+tid]/81888.f - mu*mu;
    float rs = rsqrtf(var + 1e-5f);
    float A = rs*g5[tid], B = bb5[tid] - mu*rs*g5[tid];
    float w = w3[tid];
    WA[tid] = w*A; WB[tid] = w*B;
  }
  __syncthreads();
  int b = blockIdx.y;
  int t = blockIdx.x*256 + tid;
  float acc = b3[0];
  if(t < 10236){
    const unsigned short* hp = h5b + ((size_t)b*10240 + t)*64;
    #pragma unroll
    for(int q = 0; q < 8; q++){
      uint4 u = *(const uint4*)(hp + q*8);
      unsigned int ua[4] = {u.x, u.y, u.z, u.w};
      #pragma unroll
      for(int w = 0; w < 4; w++){
        int c = q*8 + w*2;
        acc += WA[c]*bf16tof((unsigned short)(ua[w] & 0xFFFFu)) + WB[c];
        acc += WA[c+1]*bf16tof((unsigned short)(ua[w] >> 16)) + WB[c+1];
      }
    }
  } else acc = 0.f;
  out[b*10240 + t] = acc;
}

// =========================================================================
extern "C" void kernel_launch(void* const* d_in, const int* in_sizes, int n_in,
                              void* d_out, int out_size, void* d_ws, size_t ws_size,
                              hipStream_t stream){
  const float* x   = (const float*)d_in[0];
  const float* ew1 = (const float*)d_in[1];
  const float* eb1 = (const float*)d_in[2];
  const float* g1  = (const float*)d_in[3];
  const float* bb1 = (const float*)d_in[4];
  const float* ew2 = (const float*)d_in[5];
  const float* eb2 = (const float*)d_in[6];
  const float* g2  = (const float*)d_in[7];
  const float* bb2 = (const float*)d_in[8];
  const float* ew3 = (const float*)d_in[9];
  const float* eb3 = (const float*)d_in[10];
  const float* g3  = (const float*)d_in[11];
  const float* bb3 = (const float*)d_in[12];
  const float* cb  = (const float*)d_in[13];
  const float* dwt = (const float*)d_in[14];
  const float* g4  = (const float*)d_in[15];
  const float* bb4 = (const float*)d_in[16];
  const float* w2d = (const float*)d_in[17];
  const float* b2d = (const float*)d_in[18];
  const float* g5  = (const float*)d_in[19];
  const float* bb5 = (const float*)d_in[20];
  const float* w3d = (const float*)d_in[21];
  const float* b3d = (const float*)d_in[22];

  char* ws = (char*)d_ws;
  float* h1   = (float*)(ws + 0);
  unsigned short* cbsw = (unsigned short*)(ws + 0);         // 2,097,152
  float* cnw  = (float*)(ws + 2097152);                     // 32,768
  float* cnw2 = (float*)(ws + 2129920);                     // 32,768
  float* h2   = (float*)(ws + 5242880);
  float* zn   = (float*)(ws + 15728640);
  unsigned short* h4t = (unsigned short*)(ws + 0);          // 10,493,952
  unsigned short* h5b = (unsigned short*)(ws + 20971520);   // 10,485,760
  int*   list = (int*)  (ws + 20971520);                    // 65,536 (time-disjoint vs h5b)
  int*   cnt  = (int*)  (ws + 21037056);                    // 256
  unsigned int* pbk = (unsigned int*)(ws + 21037312);       // 524,288
  unsigned int* psk = (unsigned int*)(ws + 21561600);       // 524,288
  float* pxd  = (float*)(ws + 22085888);                    // 524,288
  int*   pxi  = (int*)  (ws + 22610176);                    // 524,288
  unsigned short* wbt = (unsigned short*)(ws + 31457280);   // 40,960
  float* beta = (float*)(ws + 31498240);                    // 256
  float* w3t  = (float*)(ws + 41934848);
  float* dwtt = (float*)(ws + 42139648);
  int*   idxw = (int*)  (ws + 42549248);
  float* stats= (float*)(ws + 42614784);
  if(ws_size < 42616832) return;

  float* out = (float*)d_out;  // f32: [recon 81920][idx 16384][loss 1]

  hipMemsetAsync(stats, 0, NSTATF*4, stream);
  k_prep<<<600, 256, 0, stream>>>(ew3, dwt, w3t, dwtt);
  k1<<<dim3(40,8), 256, 0, stream>>>(x, ew1, eb1, h1, stats);
  k2<<<dim3(40,8), 256, 0, stream>>>(h1, ew2, eb2, g1, bb1, h2, stats);
  k_prep2<<<32, 256, 0, stream>>>(cb, cbsw, cnw, cnw2, cnt);
  k3<<<dim3(64,8), 256, 0, stream>>>(h2, w3t, eb3, g2, bb2, zn, stats);
  k3b<<<1024, 256, 0, stream>>>(zn, g3, bb3, stats);
  k5m<<<dim3(NCHUNK,256), 256, 0, stream>>>(zn, cbsw, cnw2, pbk, psk);
  k5r<<<64, 256, 0, stream>>>(pbk, psk, idxw, out + 81920, list, cnt);
  k5x<<<dim3(NCHUNK,256), 256, 0, stream>>>(zn, cb, cnw, list, cnt, pxd, pxi);
  k5x2<<<64, 256, 0, stream>>>(pxd, pxi, list, cnt, idxw, out + 81920);
  k_loss<<<64, 256, 0, stream>>>(zn, cb, idxw, stats);
  k6<<<1, 64, 0, stream>>>(stats, out + 98304);
  k7z<<<1, 256, 0, stream>>>((unsigned int*)h4t);
  k7<<<dim3(64,8), 256, 0, stream>>>(idxw, cb, dwtt, h4t, stats);
  k8w<<<1, 256, 0, stream>>>(w2d, b2d, g4, bb4, stats, wbt, beta);
  k8<<<dim3(80,8), 256, 0, stream>>>(h4t, wbt, beta, h5b, stats);
  k9<<<dim3(40,8), 256, 0, stream>>>(h5b, w3d, b3d, g5, bb5, stats, out);
}

// Round 8
// 407.137 us; speedup vs baseline: 1.6574x; 1.1183x over previous
//
#include <hip/hip_runtime.h>
#include <hip/hip_bf16.h>

#define DEV __device__ __forceinline__

typedef __attribute__((ext_vector_type(8))) short s8v;     // 8 bf16 (4 VGPR)
typedef __attribute__((ext_vector_type(16))) float f32x16; // MFMA 32x32 acc
typedef __attribute__((address_space(1))) const unsigned int u32g;
typedef __attribute__((address_space(3))) unsigned int u32l;

DEV void gl_lds(const void* g, void* l){   // 16B async global->LDS
  __builtin_amdgcn_global_load_lds((u32g*)g, (u32l*)l, 16, 0, 0);
}

DEV float siluf(float x){ return x / (1.f + expf(-x)); }

DEV float wredsum(float v){
  #pragma unroll
  for(int m = 32; m; m >>= 1) v += __shfl_xor(v, m);
  return v;
}

DEV unsigned short bf16rne(float f){
  unsigned int u = __float_as_uint(f);
  u += 0x7FFFu + ((u >> 16) & 1u);
  return (unsigned short)(u >> 16);
}
DEV float bf16tof(unsigned short h){ return __uint_as_float(((unsigned int)h) << 16); }

// sk' = min(sk, max(bk, k)) given bk<=sk  ==  median(sk, bk, k), one VALU op.
DEV unsigned umed3(unsigned a, unsigned b, unsigned c){
  unsigned d;
  asm("v_med3_u32 %0, %1, %2, %3" : "=v"(d) : "v"(a), "v"(b), "v"(c));
  return d;
}

// ---- stats layout (float offsets within stats block) ----
#define S1 0
#define Q1 16
#define S2 32
#define Q2 64
#define S3 96
#define Q3 160
#define S4 224
#define Q4 288
#define S5 352
#define Q5 416
#define SLOSS 480
#define NSTATF 512

#define EPSQ 6u
#define NCHUNK 8

// =========================================================================
// K_prep: transpose enc_w3 -> w3t; dec_wt -> dwtt (f32) and wb7 (bf16 GEMM-B:
// wb7[(k*64 + o)*64 + i] = bf16(dwt[i][o][k]))
__global__ void k_prep(const float* ew3, const float* dwt, float* w3t, float* dwtt,
                       unsigned short* wb7){
  const int n1 = 64*32*25, n2 = 64*64*25;
  for(int i = blockIdx.x*blockDim.x + threadIdx.x; i < n1+n2; i += gridDim.x*blockDim.x){
    if(i < n1){
      int c = i/(32*25), r = i - c*(32*25), ii = r/25, k = r - ii*25;
      w3t[(ii*25 + k)*64 + c] = ew3[i];
    } else {
      int j = i - n1;
      int ii = j/(64*25), r = j - ii*(64*25), o = r/25, k = r - o*25;
      float w = dwt[j];
      dwtt[(ii*25 + k)*64 + o] = w;
      wb7[((size_t)(k*64 + o))*64 + ii] = bf16rne(w);
    }
  }
}

// =========================================================================
// K_prep2: codebook -> pre-swizzled bf16 hi/lo rows + norms + plain bf16 cbb.
__global__ void k_prep2(const float* __restrict__ cb, unsigned short* __restrict__ cbsw,
                        float* __restrict__ cnw, float* __restrict__ cnw2,
                        unsigned short* __restrict__ cbb, int* cnt){
  if(blockIdx.x == 0 && threadIdx.x == 0) *cnt = 0;
  int j = blockIdx.x*256 + threadIdx.x;
  if(j < 8192){
    float nrm = 0.f;
    unsigned swz = (j & 15) << 4;
    char* rowp = (char*)cbsw + (size_t)j*256;
    #pragma unroll
    for(int k = 0; k < 64; k++){
      float x = cb[(size_t)j*64 + k];
      unsigned short hi = bf16rne(x);
      float lo = x - bf16tof(hi);
      *(unsigned short*)(rowp + (((unsigned)(2*k)) ^ swz)) = hi;
      *(unsigned short*)(rowp + (((unsigned)(128 + 2*k)) ^ swz)) = bf16rne(lo);
      cbb[(size_t)j*64 + k] = hi;
      nrm = fmaf(x, x, nrm);
    }
    cnw[j] = nrm;
    cnw2[j] = (nrm + 1024.f) * 256.f;
  }
}

// =========================================================================
// K1: conv1 (1->16, K=5, pad2) + silu + bn1 stats
__global__ void k1(const float* __restrict__ x, const float* __restrict__ w1,
                   const float* __restrict__ b1, float* __restrict__ h1, float* stats){
  __shared__ float xs[260];
  __shared__ float ssum[16], ssq[16];
  int tid = threadIdx.x, b = blockIdx.y, t0 = blockIdx.x*256;
  if(tid < 16){ ssum[tid] = 0.f; ssq[tid] = 0.f; }
  for(int i = tid; i < 260; i += 256){
    int t = t0 + i - 2;
    xs[i] = (t >= 0 && t < 10240) ? x[b*10240 + t] : 0.f;
  }
  __syncthreads();
  int t = t0 + tid;
  #pragma unroll
  for(int c = 0; c < 16; c++){
    float a = b1[c];
    #pragma unroll
    for(int k = 0; k < 5; k++) a = fmaf(w1[c*5+k], xs[tid+k], a);
    a = siluf(a);
    h1[((b*16 + c)*10240) + t] = a;
    float s = wredsum(a), s2 = wredsum(a*a);
    if((tid & 63) == 0){ atomicAdd(&ssum[c], s); atomicAdd(&ssq[c], s2); }
  }
  __syncthreads();
  if(tid < 16){ atomicAdd(stats+S1+tid, ssum[tid]); atomicAdd(stats+Q1+tid, ssq[tid]); }
}

// =========================================================================
// K2: bn1 normalize + conv2 (16->32, K=5, pad2) + silu + bn2 stats
__global__ void k2(const float* __restrict__ h1, const float* __restrict__ w2,
                   const float* __restrict__ b2, const float* __restrict__ g1,
                   const float* __restrict__ bb1, float* __restrict__ h2out, float* stats){
  __shared__ float hs[16*264];
  __shared__ float wl[2560];
  __shared__ float A1[16], B1[16];
  __shared__ float ssum[32], ssq[32];
  int tid = threadIdx.x, b = blockIdx.y, t0 = blockIdx.x*256;
  for(int i = tid; i < 2560; i += 256) wl[i] = w2[i];
  if(tid < 16){
    float mu = stats[S1+tid]/81920.f;
    float var = stats[Q1+tid]/81920.f - mu*mu;
    float rs = rsqrtf(var + 1e-5f);
    A1[tid] = rs*g1[tid];
    B1[tid] = bb1[tid] - mu*rs*g1[tid];
  }
  if(tid < 32){ ssum[tid] = 0.f; ssq[tid] = 0.f; }
  __syncthreads();
  for(int i = tid; i < 16*260; i += 256){
    int ch = i/260, tt = i - ch*260;
    int t = t0 + tt - 2;
    hs[ch*264 + tt] = (t >= 0 && t < 10240) ? (h1[((b*16+ch)*10240)+t]*A1[ch] + B1[ch]) : 0.f;
  }
  __syncthreads();
  int t = t0 + tid;
  float acc[32];
  #pragma unroll
  for(int c = 0; c < 32; c++) acc[c] = b2[c];
  for(int i = 0; i < 16; i++){
    float z0 = hs[i*264+tid], z1 = hs[i*264+tid+1], z2 = hs[i*264+tid+2],
          z3 = hs[i*264+tid+3], z4 = hs[i*264+tid+4];
    #pragma unroll
    for(int c = 0; c < 32; c++){
      const float* wp = &wl[(c*16+i)*5];
      acc[c] = fmaf(wp[0],z0,fmaf(wp[1],z1,fmaf(wp[2],z2,fmaf(wp[3],z3,fmaf(wp[4],z4,acc[c])))));
    }
  }
  #pragma unroll
  for(int c = 0; c < 32; c++){
    float a = siluf(acc[c]);
    h2out[((b*32 + c)*10240) + t] = a;
    float s = wredsum(a), s2 = wredsum(a*a);
    if((tid & 63) == 0){ atomicAdd(&ssum[c], s); atomicAdd(&ssq[c], s2); }
  }
  __syncthreads();
  if(tid < 32){ atomicAdd(stats+S2+tid, ssum[tid]); atomicAdd(stats+Q2+tid, ssq[tid]); }
}

// =========================================================================
// K3: bn2 normalize + conv3 (32->64, K=25, stride5, pad12) + tanh + bn3 stats
__global__ void k3(const float* __restrict__ h2, const float* __restrict__ w3t,
                   const float* __restrict__ eb3, const float* __restrict__ g2,
                   const float* __restrict__ bb2, float* __restrict__ zn, float* stats){
  __shared__ float X[5*32*40];
  __shared__ float A2[32], B2[32];
  __shared__ float ssum[64], ssq[64];
  int tid = threadIdx.x, b = blockIdx.y, l0 = blockIdx.x*32;
  if(tid < 32){
    float mu = stats[S2+tid]/81920.f;
    float var = stats[Q2+tid]/81920.f - mu*mu;
    float rs = rsqrtf(var + 1e-5f);
    A2[tid] = rs*g2[tid];
    B2[tid] = bb2[tid] - mu*rs*g2[tid];
  }
  if(tid < 64){ ssum[tid] = 0.f; ssq[tid] = 0.f; }
  __syncthreads();
  for(int i2 = tid; i2 < 5*32*36; i2 += 256){
    int kk = i2/(32*36);
    int r  = i2 - kk*(32*36);
    int ch = r/36, m = r - ch*36;
    int t = 5*(l0 + m) + kk - 12;
    float v = 0.f;
    if(t >= 0 && t < 10240) v = h2[((b*32+ch)*10240)+t]*A2[ch] + B2[ch];
    X[(kk*32+ch)*40 + m] = v;
  }
  __syncthreads();
  int c = tid & 63, lslot = tid >> 6;
  float acc[8];
  float bias = eb3[c];
  #pragma unroll
  for(int s = 0; s < 8; s++) acc[s] = bias;
  for(int i = 0; i < 32; i++){
    #pragma unroll
    for(int kk = 0; kk < 5; kk++){
      float z[12];
      #pragma unroll
      for(int j = 0; j < 12; j++) z[j] = X[(kk*32+i)*40 + lslot*8 + j];
      #pragma unroll
      for(int kap = 0; kap < 5; kap++){
        float w = w3t[(i*25 + kap*5 + kk)*64 + c];
        #pragma unroll
        for(int s = 0; s < 8; s++) acc[s] = fmaf(w, z[s+kap], acc[s]);
      }
    }
  }
  float ls = 0.f, lq = 0.f;
  #pragma unroll
  for(int s = 0; s < 8; s++){
    int l = l0 + lslot*8 + s;
    float a = tanhf(acc[s]);
    zn[((b*2048 + l)*64) + c] = a;
    ls += a; lq += a*a;
  }
  atomicAdd(&ssum[c], ls); atomicAdd(&ssq[c], lq);
  __syncthreads();
  if(tid < 64){ atomicAdd(stats+S3+tid, ssum[tid]); atomicAdd(stats+Q3+tid, ssq[tid]); }
}

// =========================================================================
// K3b: bn3 normalize zn in place
__global__ void k3b(float* zn, const float* g3, const float* b3, const float* stats){
  __shared__ float A[64], B[64];
  int tid = threadIdx.x;
  if(tid < 64){
    float mu = stats[S3+tid]/16384.f;
    float var = stats[Q3+tid]/16384.f - mu*mu;
    float rs = rsqrtf(var + 1e-5f);
    A[tid] = rs*g3[tid];
    B[tid] = b3[tid] - mu*rs*g3[tid];
  }
  __syncthreads();
  for(int i = blockIdx.x*256 + tid; i < 16384*64; i += gridDim.x*256){
    int c = i & 63;
    zn[i] = zn[i]*A[c] + B[c];
  }
}

// =========================================================================
// K5m: MFMA VQ pass, LDS-staged codebook, lean packed-key epilogue.
__global__ __launch_bounds__(256, 3) void k5m(const float* __restrict__ zn,
    const unsigned short* __restrict__ cbsw, const float* __restrict__ cnw2,
    unsigned int* __restrict__ pbk, unsigned int* __restrict__ psk){
  __shared__ __align__(16) unsigned char cbuf[2][16384];
  __shared__ unsigned int redb[64][2], reds[64][2];
  int tid = threadIdx.x;
  int chunk = blockIdx.x;
  int m0 = blockIdx.y * 64;
  int lane = tid & 63, widx = tid >> 6;
  int wr = widx >> 1, wc = widx & 1;
  int h = lane >> 5;
  int row = m0 + wr*32 + (lane & 31);

  s8v ah[4], al[4];
  const float* zp = zn + (size_t)row*64;
  #pragma unroll
  for(int s = 0; s < 4; s++){
    float4 v0 = *(const float4*)(zp + s*16 + h*8);
    float4 v1 = *(const float4*)(zp + s*16 + h*8 + 4);
    float vv[8] = {v0.x,v0.y,v0.z,v0.w,v1.x,v1.y,v1.z,v1.w};
    #pragma unroll
    for(int i = 0; i < 8; i++){
      unsigned short hi = bf16rne(vv[i]);
      ah[s][i] = (short)hi;
      al[s][i] = (short)bf16rne(vv[i] - bf16tof(hi));
    }
  }

  unsigned int bk[16], sk[16];
  #pragma unroll
  for(int r = 0; r < 16; r++){ bk[r] = 0xFFFFFFFFu; sk[r] = 0xFFFFFFFFu; }
  f32x16 zv;
  #pragma unroll
  for(int i = 0; i < 16; i++) zv[i] = 0.f;

  int c0 = chunk * 1024;
  const char* csrc = (const char*)cbsw + (size_t)c0*256;
  #pragma unroll
  for(int c2 = 0; c2 < 4; c2++)
    gl_lds(csrc + c2*4096 + tid*16, &cbuf[0][0] + c2*4096 + tid*16);
  __syncthreads();

  int cl = wc*32 + (lane & 31);
  unsigned swz = (unsigned)(cl & 15) << 4;
  unsigned col = (unsigned)(c0 + cl);
  for(int tile = 0; tile < 16; ++tile){
    int bsel = tile & 1;
    if(tile < 15){
      const char* ns = csrc + (size_t)(tile+1)*16384;
      #pragma unroll
      for(int c2 = 0; c2 < 4; c2++)
        gl_lds(ns + c2*4096 + tid*16, &cbuf[bsel^1][0] + c2*4096 + tid*16);
    }
    const unsigned char* bp = &cbuf[bsel][0] + cl*256;
    s8v bh[4], bl[4];
    #pragma unroll
    for(int s = 0; s < 4; s++){
      bh[s] = *(const s8v*)(bp + (((unsigned)(s*32 + h*16)) ^ swz));
      bl[s] = *(const s8v*)(bp + (((unsigned)(128 + s*32 + h*16)) ^ swz));
    }
    float cnv2 = cnw2[col];
    f32x16 a1 = __builtin_amdgcn_mfma_f32_32x32x16_bf16(ah[0], bh[0], zv, 0, 0, 0);
    f32x16 a2 = __builtin_amdgcn_mfma_f32_32x32x16_bf16(al[0], bh[0], zv, 0, 0, 0);
    a2 = __builtin_amdgcn_mfma_f32_32x32x16_bf16(ah[0], bl[0], a2, 0, 0, 0);
    #pragma unroll
    for(int s = 1; s < 4; s++){
      a1 = __builtin_amdgcn_mfma_f32_32x32x16_bf16(ah[s], bh[s], a1, 0, 0, 0);
      a2 = __builtin_amdgcn_mfma_f32_32x32x16_bf16(al[s], bh[s], a2, 0, 0, 0);
      a2 = __builtin_amdgcn_mfma_f32_32x32x16_bf16(ah[s], bl[s], a2, 0, 0, 0);
    }
    #pragma unroll
    for(int r = 0; r < 16; r++){
      float q = fmaf(-512.f, a1[r], cnv2);
      q = fmaf(-512.f, a2[r], q);
      q = fminf(q, 524287.f);
      unsigned k = (((unsigned)q) << 13) | col;
      unsigned nb = bk[r] < k ? bk[r] : k;
      sk[r] = umed3(sk[r], bk[r], k);
      bk[r] = nb;
    }
    col += 64;
    __syncthreads();
  }

  #pragma unroll
  for(int m = 1; m <= 16; m <<= 1){
    #pragma unroll
    for(int r = 0; r < 16; r++){
      unsigned int ob = (unsigned int)__shfl_xor((int)bk[r], m);
      unsigned int os = (unsigned int)__shfl_xor((int)sk[r], m);
      unsigned int s2 = sk[r] < os ? sk[r] : os;
      sk[r] = umed3(s2, bk[r], ob);
      bk[r] = bk[r] < ob ? bk[r] : ob;
    }
  }
  if((lane & 31) == 0){
    #pragma unroll
    for(int r = 0; r < 16; r++){
      int lr = wr*32 + (r&3) + 8*(r>>2) + 4*h;
      redb[lr][wc] = bk[r]; reds[lr][wc] = sk[r];
    }
  }
  __syncthreads();
  if(tid < 64){
    unsigned int b0 = redb[tid][0], b1v = redb[tid][1];
    unsigned int s0 = reds[tid][0], s1v = reds[tid][1];
    unsigned int ss = s0 < s1v ? s0 : s1v;
    ss = umed3(ss, b0, b1v);
    unsigned int bb = b0 < b1v ? b0 : b1v;
    size_t o = (size_t)chunk*16384 + m0 + tid;
    pbk[o] = bb;
    psk[o] = ss;
  }
}

// =========================================================================
// K5r: merge chunk partials; write idx; flag close calls.
__global__ void k5r(const unsigned int* __restrict__ pbk,
                    const unsigned int* __restrict__ psk, int* __restrict__ idxw,
                    float* __restrict__ out_idx, int* __restrict__ list, int* cnt){
  int row = blockIdx.x*256 + threadIdx.x;  // grid 64
  unsigned int bk = pbk[row], sk = psk[row];
  #pragma unroll
  for(int c = 1; c < NCHUNK; c++){
    unsigned int ob = pbk[(size_t)c*16384 + row];
    unsigned int os = psk[(size_t)c*16384 + row];
    unsigned int s2 = sk < os ? sk : os;
    sk = umed3(s2, bk, ob);
    bk = bk < ob ? bk : ob;
  }
  int idx = (int)(bk & 0x1FFFu);
  idxw[row] = idx;
  out_idx[row] = (float)idx;
  if((sk >> 13) - (bk >> 13) <= EPSQ){
    int p = atomicAdd(cnt, 1);
    list[p] = row;
  }
}

// =========================================================================
// K5x: exact f32 rescore, row-parallel.
__global__ __launch_bounds__(256) void k5x(const float* __restrict__ zn,
    const float* __restrict__ cb, const float* __restrict__ cnw,
    const int* __restrict__ list, const int* cnt,
    float* __restrict__ pxd, int* __restrict__ pxi){
  int tid = threadIdx.x;
  int chunk = blockIdx.x;
  int n = *cnt;
  int rgrp = tid >> 6, cs = tid & 63;
  int c0 = chunk * 1024;
  for(int bat = blockIdx.y; bat*4 < n; bat += 256){
    int e = bat*4 + rgrp;
    int ec = e < n ? e : n-1;
    int row = list[ec];
    float4 zr[16];
    const float4* zp = (const float4*)(zn + (size_t)row*64);
    #pragma unroll
    for(int q = 0; q < 16; q++) zr[q] = zp[q];
    float bd = 3.4e38f; int bi = 0;
    for(int step = 0; step < 16; step++){
      int j = c0 + step*64 + cs;
      const float4* cp = (const float4*)(cb + (size_t)j*64);
      float cnv = cnw[j];
      float da = 0.f, db = 0.f;
      #pragma unroll
      for(int q = 0; q < 16; q += 2){
        float4 ca = cp[q], cb4 = cp[q+1];
        da = fmaf(ca.x, zr[q].x, da);  da = fmaf(ca.y, zr[q].y, da);
        da = fmaf(ca.z, zr[q].z, da);  da = fmaf(ca.w, zr[q].w, da);
        db = fmaf(cb4.x, zr[q+1].x, db); db = fmaf(cb4.y, zr[q+1].y, db);
        db = fmaf(cb4.z, zr[q+1].z, db); db = fmaf(cb4.w, zr[q+1].w, db);
      }
      float d = fmaf(-2.f, da + db, cnv);
      if(d < bd){ bd = d; bi = j; }
    }
    #pragma unroll
    for(int m = 1; m <= 32; m <<= 1){
      float od = __shfl_xor(bd, m);
      int   oi = __shfl_xor(bi, m);
      if(od < bd || (od == bd && oi < bi)){ bd = od; bi = oi; }
    }
    if(cs == 0 && e < n){
      pxd[(size_t)chunk*16384 + e] = bd;
      pxi[(size_t)chunk*16384 + e] = bi;
    }
  }
}

// =========================================================================
// K5x2: merge chunk partials per flagged row -> final idx.
__global__ void k5x2(const float* __restrict__ pxd, const int* __restrict__ pxi,
                     const int* __restrict__ list, const int* cnt,
                     int* __restrict__ idxw, float* __restrict__ out_idx){
  int e = blockIdx.x*256 + threadIdx.x;  // grid 64
  int n = *cnt;
  if(e >= n) return;
  float bd = pxd[e]; int bi = pxi[e];
  #pragma unroll
  for(int c = 1; c < NCHUNK; c++){
    float od = pxd[(size_t)c*16384 + e];
    int   oi = pxi[(size_t)c*16384 + e];
    if(od < bd || (od == bd && oi < bi)){ bd = od; bi = oi; }
  }
  int row = list[e];
  idxw[row] = bi;
  out_idx[row] = (float)bi;
}

// =========================================================================
// K_loss: commit loss from final indices
__global__ void k_loss(const float* __restrict__ zn, const float* __restrict__ cb,
                       const int* __restrict__ idxw, float* stats){
  int row = blockIdx.x*256 + threadIdx.x;  // grid 64
  int code = idxw[row];
  const float* cp = cb + (size_t)code*64;
  const float* zp = zn + (size_t)row*64;
  float s = 0.f;
  #pragma unroll
  for(int k = 0; k < 64; k++){
    float dd = cp[k] - zp[k];
    s = fmaf(dd, dd, s);
  }
  float tot = wredsum(s);
  if((threadIdx.x & 63) == 0) atomicAdd(stats + SLOSS, tot);
}

// =========================================================================
// K6: finalize commit loss
__global__ void k6(const float* stats, float* out){
  if(threadIdx.x == 0) out[0] = 2.f * stats[SLOSS] / 1048576.f;
}

// =========================================================================
// K7z: zero only h4t pad rows (r in {0,1} U [10238,10248) per batch).
__global__ void k7z(unsigned int* __restrict__ h4t){
  for(int i = threadIdx.x; i < 3072; i += 256){
    int b = i / 384, r = i - b*384;
    int row12 = r >> 5, word = r & 31;
    int row = row12 < 2 ? row12 : 10236 + row12;
    h4t[((size_t)b*10248 + row)*32 + word] = 0u;
  }
}

// =========================================================================
// K7m: transposed conv as MFMA GEMM. Block = 32 u x 5 phases x 64 ch, batch b.
// A = gathered codebook rows (37 x 64 bf16, LDS, swz (m&7)<<4); B = wb7 from
// global (L1/L2-hot). Wave v computes phase v: 2 c-tiles x 5 taps x 4 kfrag.
// Epilogue: silu + dbn1 stats + swizzled bf16 store (old-k7 path).
__global__ __launch_bounds__(320) void k7m(const int* __restrict__ idxp,
    const unsigned short* __restrict__ cbb, const unsigned short* __restrict__ wb7,
    unsigned short* __restrict__ h4t, float* stats){
  __shared__ __align__(16) unsigned char lA[37*128];
  __shared__ float tb[5*64*33];
  __shared__ float ssum[64], ssq[64];
  int tid = threadIdx.x, b = blockIdx.y, u0 = blockIdx.x*32;
  if(tid < 64){ ssum[tid] = 0.f; ssq[tid] = 0.f; }
  { // stage A: rows m=[0,37) <-> u = u0-2+m, zero outside [0,2048)
    int m = tid >> 3, part = tid & 7;
    if(m < 37){
      int u = u0 - 2 + m;
      uint4 val = make_uint4(0,0,0,0);
      if(u >= 0 && u < 2048){
        int code = idxp[b*2048 + u];
        val = *(const uint4*)((const char*)cbb + (size_t)code*128 + part*16);
      }
      *(uint4*)(lA + m*128 + (((unsigned)(part*16)) ^ (((unsigned)m & 7) << 4))) = val;
    }
  }
  __syncthreads();
  int lane = tid & 63, h = lane >> 5, cl = lane & 31;
  int v = tid >> 6;                       // phase 0..4
  const int km[5]  = {2,3,4,0,1};
  const int ovv[5] = {2,2,2,3,3};
  f32x16 acc0, acc1;
  #pragma unroll
  for(int i = 0; i < 16; i++){ acc0[i] = 0.f; acc1[i] = 0.f; }
  #pragma unroll
  for(int r = 0; r < 5; r++){
    int off = ovv[v] - r + 2;             // 0..5
    int m = cl + off;
    unsigned aswz = ((unsigned)m & 7) << 4;
    int k = km[v] + 5*r;
    const char* b0p = (const char*)wb7 + (size_t)(k*64 + cl)*128;
    const char* b1p = b0p + 32*128;
    #pragma unroll
    for(int s = 0; s < 4; s++){
      unsigned o = (unsigned)(s*32 + h*16);
      s8v a  = *(const s8v*)(lA + m*128 + (o ^ aswz));
      s8v b0 = *(const s8v*)(b0p + o);
      s8v b1 = *(const s8v*)(b1p + o);
      acc0 = __builtin_amdgcn_mfma_f32_32x32x16_bf16(a, b0, acc0, 0, 0, 0);
      acc1 = __builtin_amdgcn_mfma_f32_32x32x16_bf16(a, b1, acc1, 0, 0, 0);
    }
  }
  float ps0 = 0.f, pq0 = 0.f, ps1 = 0.f, pq1 = 0.f;
  #pragma unroll
  for(int r = 0; r < 16; r++){
    int ul = (r&3) + 8*(r>>2) + 4*h;
    int u = u0 + ul;
    float v0 = siluf(acc0[r]), v1 = siluf(acc1[r]);
    tb[(v*64 + cl)*33 + ul]      = v0;
    tb[(v*64 + 32 + cl)*33 + ul] = v1;
    if(v == 0 || u < 2047){ ps0 += v0; pq0 += v0*v0; ps1 += v1; pq1 += v1*v1; }
  }
  atomicAdd(&ssum[cl], ps0);      atomicAdd(&ssq[cl], pq0);
  atomicAdd(&ssum[32 + cl], ps1); atomicAdd(&ssq[32 + cl], pq1);
  __syncthreads();
  if(tid < 64){ atomicAdd(stats+S4+tid, ssum[tid]); atomicAdd(stats+Q4+tid, ssq[tid]); }
  // coalesced swizzled bf16 store (5120 ch-pairs)
  #pragma unroll
  for(int j = 0; j < 16; j++){
    int flat = j*320 + tid;
    int tl = flat >> 5;
    int chp = flat & 31;
    int t = u0*5 + tl;
    if(t < 10236){
      int vv = tl % 5, ul = tl / 5;
      float f0 = tb[(vv*64 + 2*chp)*33 + ul];
      float f1 = tb[(vv*64 + 2*chp + 1)*33 + ul];
      unsigned int pk = (unsigned int)bf16rne(f0) | ((unsigned int)bf16rne(f1) << 16);
      size_t rowb = ((size_t)b*10248 + 2 + t)*128;
      *(unsigned int*)((char*)h4t + rowb + (((unsigned)(4*chp)) ^ (((unsigned)t & 7) << 4))) = pk;
    }
  }
}

// =========================================================================
// K8w: fold dbn1 into decoder conv2 weights (bf16, swizzled) + beta.
__global__ void k8w(const float* __restrict__ w2d, const float* __restrict__ b2d,
                    const float* __restrict__ g4, const float* __restrict__ bb4,
                    const float* __restrict__ stats, unsigned short* __restrict__ wbt,
                    float* __restrict__ beta){
  __shared__ float A4[64], B4[64];
  int tid = threadIdx.x;
  if(tid < 64){
    float mu = stats[S4+tid]/81888.f;
    float var = stats[Q4+tid]/81888.f - mu*mu;
    float rs = rsqrtf(var + 1e-5f);
    A4[tid] = rs*g4[tid];
    B4[tid] = bb4[tid] - mu*rs*g4[tid];
  }
  __syncthreads();
  for(int e = tid; e < 64*64*5; e += 256){
    int c = e/320, r = e - c*320, i = r/5, k = r - i*5;
    unsigned short hw = bf16rne(w2d[e] * A4[i]);
    int row = k*64 + c;
    *(unsigned short*)((char*)wbt + (size_t)row*128 + (((unsigned)(2*i)) ^ (((unsigned)c & 7) << 4))) = hw;
  }
  if(tid < 64){
    float s = b2d[tid];
    for(int i = 0; i < 64; i++){
      float wsum = 0.f;
      #pragma unroll
      for(int k = 0; k < 5; k++) wsum += w2d[(tid*64 + i)*5 + k];
      s += wsum * B4[i];
    }
    beta[tid] = s;
  }
}

// =========================================================================
// K8: decoder conv2 as MFMA GEMM.
__global__ __launch_bounds__(256) void k8(const unsigned short* __restrict__ h4t,
    const unsigned short* __restrict__ wbt, const float* __restrict__ beta,
    unsigned short* __restrict__ h5b, float* stats){
  __shared__ __align__(16) unsigned char lA[17408];
  __shared__ __align__(16) unsigned char lB[40960];
  __shared__ float ssum[64], ssq[64];
  int tid = threadIdx.x, b = blockIdx.y, t0 = blockIdx.x*128;
  if(tid < 64){ ssum[tid] = 0.f; ssq[tid] = 0.f; }
  #pragma unroll
  for(int c2 = 0; c2 < 10; c2++)
    gl_lds((const char*)wbt + c2*4096 + tid*16, lB + c2*4096 + tid*16);
  const char* srcA = (const char*)h4t + ((size_t)b*10248 + t0)*128;
  #pragma unroll
  for(int c2 = 0; c2 < 4; c2++)
    gl_lds(srcA + c2*4096 + tid*16, lA + c2*4096 + tid*16);
  if(tid < 64) gl_lds(srcA + 16384 + tid*16, lA + 16384 + tid*16);
  __syncthreads();

  int lane = tid & 63, h = lane >> 5, cl = lane & 31;
  int wt0 = (tid >> 6) * 32;
  f32x16 acc0, acc1;
  #pragma unroll
  for(int i = 0; i < 16; i++){ acc0[i] = 0.f; acc1[i] = 0.f; }
  unsigned bswz = (unsigned)(cl & 7) << 4;
  #pragma unroll
  for(int k = 0; k < 5; k++){
    int l = wt0 + cl + k;
    unsigned aswz = (unsigned)((l + 6) & 7) << 4;
    int arow = l*128;
    int brow = (k*64 + cl)*128;
    #pragma unroll
    for(int s = 0; s < 4; s++){
      unsigned o = (unsigned)(s*32 + h*16);
      s8v a  = *(const s8v*)(lA + arow + (o ^ aswz));
      s8v b0 = *(const s8v*)(lB + brow + (o ^ bswz));
      s8v b1 = *(const s8v*)(lB + brow + 4096 + (o ^ bswz));
      acc0 = __builtin_amdgcn_mfma_f32_32x32x16_bf16(a, b0, acc0, 0, 0, 0);
      acc1 = __builtin_amdgcn_mfma_f32_32x32x16_bf16(a, b1, acc1, 0, 0, 0);
    }
  }
  float bet0 = beta[cl], bet1 = beta[32 + cl];
  float ps0 = 0.f, pq0 = 0.f, ps1 = 0.f, pq1 = 0.f;
  #pragma unroll
  for(int r = 0; r < 16; r++){
    int t = t0 + wt0 + (r&3) + 8*(r>>2) + 4*h;
    float v0 = siluf(acc0[r] + bet0);
    float v1 = siluf(acc1[r] + bet1);
    if(t < 10236){
      size_t o = ((size_t)b*10240 + t)*64;
      h5b[o + cl]      = bf16rne(v0);
      h5b[o + 32 + cl] = bf16rne(v1);
      ps0 += v0; pq0 += v0*v0; ps1 += v1; pq1 += v1*v1;
    }
  }
  atomicAdd(&ssum[cl], ps0);      atomicAdd(&ssq[cl], pq0);
  atomicAdd(&ssum[32 + cl], ps1); atomicAdd(&ssq[32 + cl], pq1);
  __syncthreads();
  if(tid < 64){ atomicAdd(stats+S5+tid, ssum[tid]); atomicAdd(stats+Q5+tid, ssq[tid]); }
}

// =========================================================================
// K9: dbn2 normalize + 1x1 conv (64->1) + bias
__global__ void k9(const unsigned short* __restrict__ h5b, const float* __restrict__ w3,
                   const float* __restrict__ b3, const float* __restrict__ g5,
                   const float* __restrict__ bb5, const float* stats,
                   float* __restrict__ out){
  __shared__ float WA[64], WB[64];
  int tid = threadIdx.x;
  if(tid < 64){
    float mu = stats[S5+tid]/81888.f;
    float var = stats[Q5+tid]/81888.f - mu*mu;
    float rs = rsqrtf(var + 1e-5f);
    float A = rs*g5[tid], B = bb5[tid] - mu*rs*g5[tid];
    float w = w3[tid];
    WA[tid] = w*A; WB[tid] = w*B;
  }
  __syncthreads();
  int b = blockIdx.y;
  int t = blockIdx.x*256 + tid;
  float acc = b3[0];
  if(t < 10236){
    const unsigned short* hp = h5b + ((size_t)b*10240 + t)*64;
    #pragma unroll
    for(int q = 0; q < 8; q++){
      uint4 u = *(const uint4*)(hp + q*8);
      unsigned int ua[4] = {u.x, u.y, u.z, u.w};
      #pragma unroll
      for(int w = 0; w < 4; w++){
        int c = q*8 + w*2;
        acc += WA[c]*bf16tof((unsigned short)(ua[w] & 0xFFFFu)) + WB[c];
        acc += WA[c+1]*bf16tof((unsigned short)(ua[w] >> 16)) + WB[c+1];
      }
    }
  } else acc = 0.f;
  out[b*10240 + t] = acc;
}

// =========================================================================
extern "C" void kernel_launch(void* const* d_in, const int* in_sizes, int n_in,
                              void* d_out, int out_size, void* d_ws, size_t ws_size,
                              hipStream_t stream){
  const float* x   = (const float*)d_in[0];
  const float* ew1 = (const float*)d_in[1];
  const float* eb1 = (const float*)d_in[2];
  const float* g1  = (const float*)d_in[3];
  const float* bb1 = (const float*)d_in[4];
  const float* ew2 = (const float*)d_in[5];
  const float* eb2 = (const float*)d_in[6];
  const float* g2  = (const float*)d_in[7];
  const float* bb2 = (const float*)d_in[8];
  const float* ew3 = (const float*)d_in[9];
  const float* eb3 = (const float*)d_in[10];
  const float* g3  = (const float*)d_in[11];
  const float* bb3 = (const float*)d_in[12];
  const float* cb  = (const float*)d_in[13];
  const float* dwt = (const float*)d_in[14];
  const float* g4  = (const float*)d_in[15];
  const float* bb4 = (const float*)d_in[16];
  const float* w2d = (const float*)d_in[17];
  const float* b2d = (const float*)d_in[18];
  const float* g5  = (const float*)d_in[19];
  const float* bb5 = (const float*)d_in[20];
  const float* w3d = (const float*)d_in[21];
  const float* b3d = (const float*)d_in[22];

  char* ws = (char*)d_ws;
  float* h1   = (float*)(ws + 0);
  unsigned short* cbsw = (unsigned short*)(ws + 0);         // 2,097,152
  float* cnw  = (float*)(ws + 2097152);                     // 32,768
  float* cnw2 = (float*)(ws + 2129920);                     // 32,768
  float* h2   = (float*)(ws + 5242880);
  float* zn   = (float*)(ws + 15728640);
  unsigned short* h4t = (unsigned short*)(ws + 0);          // 10,493,952
  unsigned short* h5b = (unsigned short*)(ws + 20971520);   // 10,485,760
  int*   list = (int*)  (ws + 20971520);                    // 65,536 (time-disjoint vs h5b)
  int*   cnt  = (int*)  (ws + 21037056);                    // 256
  unsigned int* pbk = (unsigned int*)(ws + 21037312);       // 524,288
  unsigned int* psk = (unsigned int*)(ws + 21561600);       // 524,288
  float* pxd  = (float*)(ws + 22085888);                    // 524,288
  int*   pxi  = (int*)  (ws + 22610176);                    // 524,288
  unsigned short* wbt = (unsigned short*)(ws + 31457280);   // 40,960
  float* beta = (float*)(ws + 31498240);                    // 256
  unsigned short* wb7 = (unsigned short*)(ws + 32000000);   // 204,800 (gap)
  unsigned short* cbb = (unsigned short*)(ws + 32300032);   // 1,048,576 (gap)
  float* w3t  = (float*)(ws + 41934848);
  float* dwtt = (float*)(ws + 42139648);
  int*   idxw = (int*)  (ws + 42549248);
  float* stats= (float*)(ws + 42614784);
  if(ws_size < 42616832) return;

  float* out = (float*)d_out;  // f32: [recon 81920][idx 16384][loss 1]

  hipMemsetAsync(stats, 0, NSTATF*4, stream);
  k_prep<<<600, 256, 0, stream>>>(ew3, dwt, w3t, dwtt, wb7);
  k1<<<dim3(40,8), 256, 0, stream>>>(x, ew1, eb1, h1, stats);
  k2<<<dim3(40,8), 256, 0, stream>>>(h1, ew2, eb2, g1, bb1, h2, stats);
  k_prep2<<<32, 256, 0, stream>>>(cb, cbsw, cnw, cnw2, cbb, cnt);
  k3<<<dim3(64,8), 256, 0, stream>>>(h2, w3t, eb3, g2, bb2, zn, stats);
  k3b<<<1024, 256, 0, stream>>>(zn, g3, bb3, stats);
  k5m<<<dim3(NCHUNK,256), 256, 0, stream>>>(zn, cbsw, cnw2, pbk, psk);
  k5r<<<64, 256, 0, stream>>>(pbk, psk, idxw, out + 81920, list, cnt);
  k5x<<<dim3(NCHUNK,256), 256, 0, stream>>>(zn, cb, cnw, list, cnt, pxd, pxi);
  k5x2<<<64, 256, 0, stream>>>(pxd, pxi, list, cnt, idxw, out + 81920);
  k_loss<<<64, 256, 0, stream>>>(zn, cb, idxw, stats);
  k6<<<1, 64, 0, stream>>>(stats, out + 98304);
  k7z<<<1, 256, 0, stream>>>((unsigned int*)h4t);
  k7m<<<dim3(64,8), 320, 0, stream>>>(idxw, cbb, wb7, h4t, stats);
  k8w<<<1, 256, 0, stream>>>(w2d, b2d, g4, bb4, stats, wbt, beta);
  k8<<<dim3(80,8), 256, 0, stream>>>(h4t, wbt, beta, h5b, stats);
  k9<<<dim3(40,8), 256, 0, stream>>>(h5b, w3d, b3d, g5, bb5, stats, out);
}

// Round 9
// 389.038 us; speedup vs baseline: 1.7346x; 1.0465x over previous
//
#include <hip/hip_runtime.h>
#include <hip/hip_bf16.h>

#define DEV __device__ __forceinline__

typedef __attribute__((ext_vector_type(8))) short s8v;     // 8 bf16 (4 VGPR)
typedef __attribute__((ext_vector_type(16))) float f32x16; // MFMA 32x32 acc
typedef __attribute__((address_space(1))) const unsigned int u32g;
typedef __attribute__((address_space(3))) unsigned int u32l;

DEV void gl_lds(const void* g, void* l){   // 16B async global->LDS
  __builtin_amdgcn_global_load_lds((u32g*)g, (u32l*)l, 16, 0, 0);
}

DEV float siluf(float x){ return x / (1.f + expf(-x)); }

DEV float wredsum(float v){
  #pragma unroll
  for(int m = 32; m; m >>= 1) v += __shfl_xor(v, m);
  return v;
}

DEV unsigned short bf16rne(float f){
  unsigned int u = __float_as_uint(f);
  u += 0x7FFFu + ((u >> 16) & 1u);
  return (unsigned short)(u >> 16);
}
DEV float bf16tof(unsigned short h){ return __uint_as_float(((unsigned int)h) << 16); }

// sk' = min(sk, max(bk, k)) given bk<=sk  ==  median(sk, bk, k), one VALU op.
DEV unsigned umed3(unsigned a, unsigned b, unsigned c){
  unsigned d;
  asm("v_med3_u32 %0, %1, %2, %3" : "=v"(d) : "v"(a), "v"(b), "v"(c));
  return d;
}

// ---- stats layout (float offsets within stats block) ----
#define S1 0
#define Q1 16
#define S2 32
#define Q2 64
#define S3 96
#define Q3 160
#define S4 224
#define Q4 288
#define S5 352
#define Q5 416
#define SLOSS 480
#define NSTATF 512

#define EPSQ 6u
#define NCHUNK 8

// =========================================================================
// K_prep: transpose enc_w3 -> w3t; dec_wt -> dwtt (f32) and wb7 (bf16 GEMM-B)
__global__ void k_prep(const float* ew3, const float* dwt, float* w3t, float* dwtt,
                       unsigned short* wb7){
  const int n1 = 64*32*25, n2 = 64*64*25;
  for(int i = blockIdx.x*blockDim.x + threadIdx.x; i < n1+n2; i += gridDim.x*blockDim.x){
    if(i < n1){
      int c = i/(32*25), r = i - c*(32*25), ii = r/25, k = r - ii*25;
      w3t[(ii*25 + k)*64 + c] = ew3[i];
    } else {
      int j = i - n1;
      int ii = j/(64*25), r = j - ii*(64*25), o = r/25, k = r - o*25;
      float w = dwt[j];
      dwtt[(ii*25 + k)*64 + o] = w;
      wb7[((size_t)(k*64 + o))*64 + ii] = bf16rne(w);
    }
  }
}

// =========================================================================
// K_prep2: codebook -> pre-swizzled bf16 hi/lo rows + norms + plain bf16 cbb.
__global__ void k_prep2(const float* __restrict__ cb, unsigned short* __restrict__ cbsw,
                        float* __restrict__ cnw, float* __restrict__ cnw2,
                        unsigned short* __restrict__ cbb, int* cnt){
  if(blockIdx.x == 0 && threadIdx.x == 0) *cnt = 0;
  int j = blockIdx.x*256 + threadIdx.x;
  if(j < 8192){
    float nrm = 0.f;
    unsigned swz = (j & 15) << 4;
    char* rowp = (char*)cbsw + (size_t)j*256;
    #pragma unroll
    for(int k = 0; k < 64; k++){
      float x = cb[(size_t)j*64 + k];
      unsigned short hi = bf16rne(x);
      float lo = x - bf16tof(hi);
      *(unsigned short*)(rowp + (((unsigned)(2*k)) ^ swz)) = hi;
      *(unsigned short*)(rowp + (((unsigned)(128 + 2*k)) ^ swz)) = bf16rne(lo);
      cbb[(size_t)j*64 + k] = hi;
      nrm = fmaf(x, x, nrm);
    }
    cnw[j] = nrm;
    cnw2[j] = (nrm + 1024.f) * 256.f;
  }
}

// =========================================================================
// K1: conv1 (1->16, K=5, pad2) + silu + bn1 stats
__global__ void k1(const float* __restrict__ x, const float* __restrict__ w1,
                   const float* __restrict__ b1, float* __restrict__ h1, float* stats){
  __shared__ float xs[260];
  __shared__ float ssum[16], ssq[16];
  int tid = threadIdx.x, b = blockIdx.y, t0 = blockIdx.x*256;
  if(tid < 16){ ssum[tid] = 0.f; ssq[tid] = 0.f; }
  for(int i = tid; i < 260; i += 256){
    int t = t0 + i - 2;
    xs[i] = (t >= 0 && t < 10240) ? x[b*10240 + t] : 0.f;
  }
  __syncthreads();
  int t = t0 + tid;
  #pragma unroll
  for(int c = 0; c < 16; c++){
    float a = b1[c];
    #pragma unroll
    for(int k = 0; k < 5; k++) a = fmaf(w1[c*5+k], xs[tid+k], a);
    a = siluf(a);
    h1[((b*16 + c)*10240) + t] = a;
    float s = wredsum(a), s2 = wredsum(a*a);
    if((tid & 63) == 0){ atomicAdd(&ssum[c], s); atomicAdd(&ssq[c], s2); }
  }
  __syncthreads();
  if(tid < 16){ atomicAdd(stats+S1+tid, ssum[tid]); atomicAdd(stats+Q1+tid, ssq[tid]); }
}

// =========================================================================
// K2: bn1 normalize + conv2 (16->32, K=5, pad2) + silu + bn2 stats
__global__ void k2(const float* __restrict__ h1, const float* __restrict__ w2,
                   const float* __restrict__ b2, const float* __restrict__ g1,
                   const float* __restrict__ bb1, float* __restrict__ h2out, float* stats){
  __shared__ float hs[16*264];
  __shared__ float wl[2560];
  __shared__ float A1[16], B1[16];
  __shared__ float ssum[32], ssq[32];
  int tid = threadIdx.x, b = blockIdx.y, t0 = blockIdx.x*256;
  for(int i = tid; i < 2560; i += 256) wl[i] = w2[i];
  if(tid < 16){
    float mu = stats[S1+tid]/81920.f;
    float var = stats[Q1+tid]/81920.f - mu*mu;
    float rs = rsqrtf(var + 1e-5f);
    A1[tid] = rs*g1[tid];
    B1[tid] = bb1[tid] - mu*rs*g1[tid];
  }
  if(tid < 32){ ssum[tid] = 0.f; ssq[tid] = 0.f; }
  __syncthreads();
  for(int i = tid; i < 16*260; i += 256){
    int ch = i/260, tt = i - ch*260;
    int t = t0 + tt - 2;
    hs[ch*264 + tt] = (t >= 0 && t < 10240) ? (h1[((b*16+ch)*10240)+t]*A1[ch] + B1[ch]) : 0.f;
  }
  __syncthreads();
  int t = t0 + tid;
  float acc[32];
  #pragma unroll
  for(int c = 0; c < 32; c++) acc[c] = b2[c];
  for(int i = 0; i < 16; i++){
    float z0 = hs[i*264+tid], z1 = hs[i*264+tid+1], z2 = hs[i*264+tid+2],
          z3 = hs[i*264+tid+3], z4 = hs[i*264+tid+4];
    #pragma unroll
    for(int c = 0; c < 32; c++){
      const float* wp = &wl[(c*16+i)*5];
      acc[c] = fmaf(wp[0],z0,fmaf(wp[1],z1,fmaf(wp[2],z2,fmaf(wp[3],z3,fmaf(wp[4],z4,acc[c])))));
    }
  }
  #pragma unroll
  for(int c = 0; c < 32; c++){
    float a = siluf(acc[c]);
    h2out[((b*32 + c)*10240) + t] = a;
    float s = wredsum(a), s2 = wredsum(a*a);
    if((tid & 63) == 0){ atomicAdd(&ssum[c], s); atomicAdd(&ssq[c], s2); }
  }
  __syncthreads();
  if(tid < 32){ atomicAdd(stats+S2+tid, ssum[tid]); atomicAdd(stats+Q2+tid, ssq[tid]); }
}

// =========================================================================
// K3: bn2 normalize + conv3 (32->64, K=25, stride5, pad12) + tanh + bn3 stats
// Retiled: 16 l per block (grid 128x8), float4 LDS reads. Same FMA order per
// output as before -> zn bitwise identical.
__global__ void k3(const float* __restrict__ h2, const float* __restrict__ w3t,
                   const float* __restrict__ eb3, const float* __restrict__ g2,
                   const float* __restrict__ bb2, float* __restrict__ zn, float* stats){
  __shared__ __align__(16) float X[5*32*24];   // [kk][ch][m], m<20 valid
  __shared__ float A2[32], B2[32];
  __shared__ float ssum[64], ssq[64];
  int tid = threadIdx.x, b = blockIdx.y, l0 = blockIdx.x*16;
  if(tid < 32){
    float mu = stats[S2+tid]/81920.f;
    float var = stats[Q2+tid]/81920.f - mu*mu;
    float rs = rsqrtf(var + 1e-5f);
    A2[tid] = rs*g2[tid];
    B2[tid] = bb2[tid] - mu*rs*g2[tid];
  }
  if(tid < 64){ ssum[tid] = 0.f; ssq[tid] = 0.f; }
  __syncthreads();
  for(int i2 = tid; i2 < 5*32*20; i2 += 256){
    int kk = i2/640;
    int r  = i2 - kk*640;
    int ch = r/20, m = r - ch*20;
    int t = 5*(l0 + m) + kk - 12;
    float v = 0.f;
    if(t >= 0 && t < 10240) v = h2[((b*32+ch)*10240)+t]*A2[ch] + B2[ch];
    X[(kk*32+ch)*24 + m] = v;
  }
  __syncthreads();
  int c = tid & 63, lslot = tid >> 6;   // 4 slots x 4 l
  float acc[4];
  float bias = eb3[c];
  #pragma unroll
  for(int s = 0; s < 4; s++) acc[s] = bias;
  for(int i = 0; i < 32; i++){
    #pragma unroll
    for(int kk = 0; kk < 5; kk++){
      const float* xp = &X[(kk*32+i)*24 + lslot*4];
      float4 za = *(const float4*)(xp);
      float4 zb = *(const float4*)(xp + 4);
      float z[8] = {za.x,za.y,za.z,za.w,zb.x,zb.y,zb.z,zb.w};
      #pragma unroll
      for(int kap = 0; kap < 5; kap++){
        float w = w3t[(i*25 + kap*5 + kk)*64 + c];
        #pragma unroll
        for(int s = 0; s < 4; s++) acc[s] = fmaf(w, z[s+kap], acc[s]);
      }
    }
  }
  float ls = 0.f, lq = 0.f;
  #pragma unroll
  for(int s = 0; s < 4; s++){
    int l = l0 + lslot*4 + s;
    float a = tanhf(acc[s]);
    zn[((b*2048 + l)*64) + c] = a;
    ls += a; lq += a*a;
  }
  atomicAdd(&ssum[c], ls); atomicAdd(&ssq[c], lq);
  __syncthreads();
  if(tid < 64){ atomicAdd(stats+S3+tid, ssum[tid]); atomicAdd(stats+Q3+tid, ssq[tid]); }
}

// =========================================================================
// K3b: bn3 normalize zn in place
__global__ void k3b(float* zn, const float* g3, const float* b3, const float* stats){
  __shared__ float A[64], B[64];
  int tid = threadIdx.x;
  if(tid < 64){
    float mu = stats[S3+tid]/16384.f;
    float var = stats[Q3+tid]/16384.f - mu*mu;
    float rs = rsqrtf(var + 1e-5f);
    A[tid] = rs*g3[tid];
    B[tid] = b3[tid] - mu*rs*g3[tid];
  }
  __syncthreads();
  for(int i = blockIdx.x*256 + tid; i < 16384*64; i += gridDim.x*256){
    int c = i & 63;
    zn[i] = zn[i]*A[c] + B[c];
  }
}

// =========================================================================
// K5m: MFMA VQ pass, M=128 rows/block. Each wave owns 32 rows x all 64 cols
// (2 sequential col-halves into the same bk/sk). No cross-wave merge needed.
__global__ __launch_bounds__(256, 3) void k5m(const float* __restrict__ zn,
    const unsigned short* __restrict__ cbsw, const float* __restrict__ cnw2,
    unsigned int* __restrict__ pbk, unsigned int* __restrict__ psk){
  __shared__ __align__(16) unsigned char cbuf[2][16384];
  int tid = threadIdx.x;
  int chunk = blockIdx.x;
  int m0 = blockIdx.y * 128;
  int lane = tid & 63, wr = tid >> 6;
  int h = lane >> 5, cll = lane & 31;
  int row = m0 + wr*32 + cll;

  s8v ah[4], al[4];
  const float* zp = zn + (size_t)row*64;
  #pragma unroll
  for(int s = 0; s < 4; s++){
    float4 v0 = *(const float4*)(zp + s*16 + h*8);
    float4 v1 = *(const float4*)(zp + s*16 + h*8 + 4);
    float vv[8] = {v0.x,v0.y,v0.z,v0.w,v1.x,v1.y,v1.z,v1.w};
    #pragma unroll
    for(int i = 0; i < 8; i++){
      unsigned short hi = bf16rne(vv[i]);
      ah[s][i] = (short)hi;
      al[s][i] = (short)bf16rne(vv[i] - bf16tof(hi));
    }
  }

  unsigned int bk[16], sk[16];
  #pragma unroll
  for(int r = 0; r < 16; r++){ bk[r] = 0xFFFFFFFFu; sk[r] = 0xFFFFFFFFu; }
  f32x16 zv;
  #pragma unroll
  for(int i = 0; i < 16; i++) zv[i] = 0.f;

  int c0 = chunk * 1024;
  const char* csrc = (const char*)cbsw + (size_t)c0*256;
  #pragma unroll
  for(int c2 = 0; c2 < 4; c2++)
    gl_lds(csrc + c2*4096 + tid*16, &cbuf[0][0] + c2*4096 + tid*16);
  __syncthreads();

  unsigned swz = (unsigned)(cll & 15) << 4;
  for(int tile = 0; tile < 16; ++tile){
    int bsel = tile & 1;
    if(tile < 15){
      const char* ns = csrc + (size_t)(tile+1)*16384;
      #pragma unroll
      for(int c2 = 0; c2 < 4; c2++)
        gl_lds(ns + c2*4096 + tid*16, &cbuf[bsel^1][0] + c2*4096 + tid*16);
    }
    #pragma unroll
    for(int half = 0; half < 2; half++){
      const unsigned char* bp = &cbuf[bsel][0] + (half*32 + cll)*256;
      s8v bh[4], bl[4];
      #pragma unroll
      for(int s = 0; s < 4; s++){
        bh[s] = *(const s8v*)(bp + (((unsigned)(s*32 + h*16)) ^ swz));
        bl[s] = *(const s8v*)(bp + (((unsigned)(128 + s*32 + h*16)) ^ swz));
      }
      unsigned col = (unsigned)(c0 + tile*64 + half*32 + cll);
      float cnv2 = cnw2[col];
      f32x16 a1 = __builtin_amdgcn_mfma_f32_32x32x16_bf16(ah[0], bh[0], zv, 0, 0, 0);
      f32x16 a2 = __builtin_amdgcn_mfma_f32_32x32x16_bf16(al[0], bh[0], zv, 0, 0, 0);
      a2 = __builtin_amdgcn_mfma_f32_32x32x16_bf16(ah[0], bl[0], a2, 0, 0, 0);
      #pragma unroll
      for(int s = 1; s < 4; s++){
        a1 = __builtin_amdgcn_mfma_f32_32x32x16_bf16(ah[s], bh[s], a1, 0, 0, 0);
        a2 = __builtin_amdgcn_mfma_f32_32x32x16_bf16(al[s], bh[s], a2, 0, 0, 0);
        a2 = __builtin_amdgcn_mfma_f32_32x32x16_bf16(ah[s], bl[s], a2, 0, 0, 0);
      }
      #pragma unroll
      for(int r = 0; r < 16; r++){
        float q = fmaf(-512.f, a1[r], cnv2);
        q = fmaf(-512.f, a2[r], q);
        q = fminf(q, 524287.f);
        unsigned k = (((unsigned)q) << 13) | col;
        unsigned nb = bk[r] < k ? bk[r] : k;
        sk[r] = umed3(sk[r], bk[r], k);
        bk[r] = nb;
      }
    }
    __syncthreads();
  }

  // wave-local reduce over 32 col-lanes; lanes 0 and 32 hold 16 rows each
  #pragma unroll
  for(int m = 1; m <= 16; m <<= 1){
    #pragma unroll
    for(int r = 0; r < 16; r++){
      unsigned int ob = (unsigned int)__shfl_xor((int)bk[r], m);
      unsigned int os = (unsigned int)__shfl_xor((int)sk[r], m);
      unsigned int s2 = sk[r] < os ? sk[r] : os;
      sk[r] = umed3(s2, bk[r], ob);
      bk[r] = bk[r] < ob ? bk[r] : ob;
    }
  }
  if(cll == 0){
    size_t base = (size_t)chunk*16384 + m0 + wr*32 + 4*h;
    #pragma unroll
    for(int r = 0; r < 16; r++){
      int lr = (r&3) + 8*(r>>2);
      pbk[base + lr] = bk[r];
      psk[base + lr] = sk[r];
    }
  }
}

// =========================================================================
// K5r: merge chunk partials; write idx; flag close calls.
__global__ void k5r(const unsigned int* __restrict__ pbk,
                    const unsigned int* __restrict__ psk, int* __restrict__ idxw,
                    float* __restrict__ out_idx, int* __restrict__ list, int* cnt){
  int row = blockIdx.x*256 + threadIdx.x;  // grid 64
  unsigned int bk = pbk[row], sk = psk[row];
  #pragma unroll
  for(int c = 1; c < NCHUNK; c++){
    unsigned int ob = pbk[(size_t)c*16384 + row];
    unsigned int os = psk[(size_t)c*16384 + row];
    unsigned int s2 = sk < os ? sk : os;
    sk = umed3(s2, bk, ob);
    bk = bk < ob ? bk : ob;
  }
  int idx = (int)(bk & 0x1FFFu);
  idxw[row] = idx;
  out_idx[row] = (float)idx;
  if((sk >> 13) - (bk >> 13) <= EPSQ){
    int p = atomicAdd(cnt, 1);
    list[p] = row;
  }
}

// =========================================================================
// K5x: exact f32 rescore, row-parallel.
__global__ __launch_bounds__(256) void k5x(const float* __restrict__ zn,
    const float* __restrict__ cb, const float* __restrict__ cnw,
    const int* __restrict__ list, const int* cnt,
    float* __restrict__ pxd, int* __restrict__ pxi){
  int tid = threadIdx.x;
  int chunk = blockIdx.x;
  int n = *cnt;
  int rgrp = tid >> 6, cs = tid & 63;
  int c0 = chunk * 1024;
  for(int bat = blockIdx.y; bat*4 < n; bat += 256){
    int e = bat*4 + rgrp;
    int ec = e < n ? e : n-1;
    int row = list[ec];
    float4 zr[16];
    const float4* zp = (const float4*)(zn + (size_t)row*64);
    #pragma unroll
    for(int q = 0; q < 16; q++) zr[q] = zp[q];
    float bd = 3.4e38f; int bi = 0;
    for(int step = 0; step < 16; step++){
      int j = c0 + step*64 + cs;
      const float4* cp = (const float4*)(cb + (size_t)j*64);
      float cnv = cnw[j];
      float da = 0.f, db = 0.f;
      #pragma unroll
      for(int q = 0; q < 16; q += 2){
        float4 ca = cp[q], cb4 = cp[q+1];
        da = fmaf(ca.x, zr[q].x, da);  da = fmaf(ca.y, zr[q].y, da);
        da = fmaf(ca.z, zr[q].z, da);  da = fmaf(ca.w, zr[q].w, da);
        db = fmaf(cb4.x, zr[q+1].x, db); db = fmaf(cb4.y, zr[q+1].y, db);
        db = fmaf(cb4.z, zr[q+1].z, db); db = fmaf(cb4.w, zr[q+1].w, db);
      }
      float d = fmaf(-2.f, da + db, cnv);
      if(d < bd){ bd = d; bi = j; }
    }
    #pragma unroll
    for(int m = 1; m <= 32; m <<= 1){
      float od = __shfl_xor(bd, m);
      int   oi = __shfl_xor(bi, m);
      if(od < bd || (od == bd && oi < bi)){ bd = od; bi = oi; }
    }
    if(cs == 0 && e < n){
      pxd[(size_t)chunk*16384 + e] = bd;
      pxi[(size_t)chunk*16384 + e] = bi;
    }
  }
}

// =========================================================================
// K5x2: merge chunk partials per flagged row -> final idx.
__global__ void k5x2(const float* __restrict__ pxd, const int* __restrict__ pxi,
                     const int* __restrict__ list, const int* cnt,
                     int* __restrict__ idxw, float* __restrict__ out_idx){
  int e = blockIdx.x*256 + threadIdx.x;  // grid 64
  int n = *cnt;
  if(e >= n) return;
  float bd = pxd[e]; int bi = pxi[e];
  #pragma unroll
  for(int c = 1; c < NCHUNK; c++){
    float od = pxd[(size_t)c*16384 + e];
    int   oi = pxi[(size_t)c*16384 + e];
    if(od < bd || (od == bd && oi < bi)){ bd = od; bi = oi; }
  }
  int row = list[e];
  idxw[row] = bi;
  out_idx[row] = (float)bi;
}

// =========================================================================
// K_loss: commit loss from final indices
__global__ void k_loss(const float* __restrict__ zn, const float* __restrict__ cb,
                       const int* __restrict__ idxw, float* stats){
  int row = blockIdx.x*256 + threadIdx.x;  // grid 64
  int code = idxw[row];
  const float* cp = cb + (size_t)code*64;
  const float* zp = zn + (size_t)row*64;
  float s = 0.f;
  #pragma unroll
  for(int k = 0; k < 64; k++){
    float dd = cp[k] - zp[k];
    s = fmaf(dd, dd, s);
  }
  float tot = wredsum(s);
  if((threadIdx.x & 63) == 0) atomicAdd(stats + SLOSS, tot);
}

// =========================================================================
// K7m: transposed conv as MFMA GEMM (unchanged).
__global__ __launch_bounds__(320) void k7m(const int* __restrict__ idxp,
    const unsigned short* __restrict__ cbb, const unsigned short* __restrict__ wb7,
    unsigned short* __restrict__ h4t, float* stats){
  __shared__ __align__(16) unsigned char lA[37*128];
  __shared__ float tb[5*64*33];
  __shared__ float ssum[64], ssq[64];
  int tid = threadIdx.x, b = blockIdx.y, u0 = blockIdx.x*32;
  if(tid < 64){ ssum[tid] = 0.f; ssq[tid] = 0.f; }
  {
    int m = tid >> 3, part = tid & 7;
    if(m < 37){
      int u = u0 - 2 + m;
      uint4 val = make_uint4(0,0,0,0);
      if(u >= 0 && u < 2048){
        int code = idxp[b*2048 + u];
        val = *(const uint4*)((const char*)cbb + (size_t)code*128 + part*16);
      }
      *(uint4*)(lA + m*128 + (((unsigned)(part*16)) ^ (((unsigned)m & 7) << 4))) = val;
    }
  }
  __syncthreads();
  int lane = tid & 63, h = lane >> 5, cl = lane & 31;
  int v = tid >> 6;
  const int km[5]  = {2,3,4,0,1};
  const int ovv[5] = {2,2,2,3,3};
  f32x16 acc0, acc1;
  #pragma unroll
  for(int i = 0; i < 16; i++){ acc0[i] = 0.f; acc1[i] = 0.f; }
  #pragma unroll
  for(int r = 0; r < 5; r++){
    int off = ovv[v] - r + 2;
    int m = cl + off;
    unsigned aswz = ((unsigned)m & 7) << 4;
    int k = km[v] + 5*r;
    const char* b0p = (const char*)wb7 + (size_t)(k*64 + cl)*128;
    const char* b1p = b0p + 32*128;
    #pragma unroll
    for(int s = 0; s < 4; s++){
      unsigned o = (unsigned)(s*32 + h*16);
      s8v a  = *(const s8v*)(lA + m*128 + (o ^ aswz));
      s8v b0 = *(const s8v*)(b0p + o);
      s8v b1 = *(const s8v*)(b1p + o);
      acc0 = __builtin_amdgcn_mfma_f32_32x32x16_bf16(a, b0, acc0, 0, 0, 0);
      acc1 = __builtin_amdgcn_mfma_f32_32x32x16_bf16(a, b1, acc1, 0, 0, 0);
    }
  }
  float ps0 = 0.f, pq0 = 0.f, ps1 = 0.f, pq1 = 0.f;
  #pragma unroll
  for(int r = 0; r < 16; r++){
    int ul = (r&3) + 8*(r>>2) + 4*h;
    int u = u0 + ul;
    float v0 = siluf(acc0[r]), v1 = siluf(acc1[r]);
    tb[(v*64 + cl)*33 + ul]      = v0;
    tb[(v*64 + 32 + cl)*33 + ul] = v1;
    if(v == 0 || u < 2047){ ps0 += v0; pq0 += v0*v0; ps1 += v1; pq1 += v1*v1; }
  }
  atomicAdd(&ssum[cl], ps0);      atomicAdd(&ssq[cl], pq0);
  atomicAdd(&ssum[32 + cl], ps1); atomicAdd(&ssq[32 + cl], pq1);
  __syncthreads();
  if(tid < 64){ atomicAdd(stats+S4+tid, ssum[tid]); atomicAdd(stats+Q4+tid, ssq[tid]); }
  #pragma unroll
  for(int j = 0; j < 16; j++){
    int flat = j*320 + tid;
    int tl = flat >> 5;
    int chp = flat & 31;
    int t = u0*5 + tl;
    if(t < 10236){
      int vv = tl % 5, ul = tl / 5;
      float f0 = tb[(vv*64 + 2*chp)*33 + ul];
      float f1 = tb[(vv*64 + 2*chp + 1)*33 + ul];
      unsigned int pk = (unsigned int)bf16rne(f0) | ((unsigned int)bf16rne(f1) << 16);
      size_t rowb = ((size_t)b*10248 + 2 + t)*128;
      *(unsigned int*)((char*)h4t + rowb + (((unsigned)(4*chp)) ^ (((unsigned)t & 7) << 4))) = pk;
    }
  }
}

// =========================================================================
// K8w: fold dbn1 into decoder conv2 weights + beta; also zero h4t pad rows.
__global__ void k8w(const float* __restrict__ w2d, const float* __restrict__ b2d,
                    const float* __restrict__ g4, const float* __restrict__ bb4,
                    const float* __restrict__ stats, unsigned short* __restrict__ wbt,
                    float* __restrict__ beta, unsigned int* __restrict__ h4tz){
  __shared__ float A4[64], B4[64];
  int tid = threadIdx.x;
  // zero h4t pad rows: rows {0,1} U [10238,10248) per batch
  for(int i = tid; i < 3072; i += 256){
    int b = i / 384, r = i - b*384;
    int row12 = r >> 5, word = r & 31;
    int row = row12 < 2 ? row12 : 10236 + row12;
    h4tz[((size_t)b*10248 + row)*32 + word] = 0u;
  }
  if(tid < 64){
    float mu = stats[S4+tid]/81888.f;
    float var = stats[Q4+tid]/81888.f - mu*mu;
    float rs = rsqrtf(var + 1e-5f);
    A4[tid] = rs*g4[tid];
    B4[tid] = bb4[tid] - mu*rs*g4[tid];
  }
  __syncthreads();
  for(int e = tid; e < 64*64*5; e += 256){
    int c = e/320, r = e - c*320, i = r/5, k = r - i*5;
    unsigned short hw = bf16rne(w2d[e] * A4[i]);
    int row = k*64 + c;
    *(unsigned short*)((char*)wbt + (size_t)row*128 + (((unsigned)(2*i)) ^ (((unsigned)c & 7) << 4))) = hw;
  }
  if(tid < 64){
    float s = b2d[tid];
    for(int i = 0; i < 64; i++){
      float wsum = 0.f;
      #pragma unroll
      for(int k = 0; k < 5; k++) wsum += w2d[(tid*64 + i)*5 + k];
      s += wsum * B4[i];
    }
    beta[tid] = s;
  }
}

// =========================================================================
// K8: decoder conv2 as MFMA GEMM. Retiled: 64 t x 64 ch per block, 4 waves as
// 2 t-groups x 2 ch-groups; B read straight from L2-hot global (no lB stage).
__global__ __launch_bounds__(256) void k8(const unsigned short* __restrict__ h4t,
    const unsigned short* __restrict__ wbt, const float* __restrict__ beta,
    unsigned short* __restrict__ h5b, float* stats){
  __shared__ __align__(16) unsigned char lA[68*128];
  __shared__ float ssum[64], ssq[64];
  int tid = threadIdx.x, b = blockIdx.y, t0 = blockIdx.x*64;
  if(tid < 64){ ssum[tid] = 0.f; ssq[tid] = 0.f; }
  const char* srcA = (const char*)h4t + ((size_t)b*10248 + t0)*128; // rows t0-2..t0+65
  #pragma unroll
  for(int c2 = 0; c2 < 2; c2++)
    gl_lds(srcA + c2*4096 + tid*16, lA + c2*4096 + tid*16);
  if(tid < 32) gl_lds(srcA + 8192 + tid*16, lA + 8192 + tid*16);
  __syncthreads();

  int lane = tid & 63, h = lane >> 5, cl = lane & 31;
  int widx = tid >> 6;
  int wt0 = (widx >> 1) * 32;
  int wch = (widx & 1) * 32;
  f32x16 acc;
  #pragma unroll
  for(int i = 0; i < 16; i++) acc[i] = 0.f;
  unsigned bswz = (unsigned)(cl & 7) << 4;
  #pragma unroll
  for(int k = 0; k < 5; k++){
    int l = wt0 + cl + k;                        // LDS row = t - (t0-2)
    unsigned aswz = (unsigned)((l + 6) & 7) << 4; // == (t&7)<<4
    const char* bp = (const char*)wbt + (size_t)(k*64 + wch + cl)*128;
    #pragma unroll
    for(int s = 0; s < 4; s++){
      unsigned o = (unsigned)(s*32 + h*16);
      s8v a  = *(const s8v*)(lA + l*128 + (o ^ aswz));
      s8v bb = *(const s8v*)(bp + (o ^ bswz));
      acc = __builtin_amdgcn_mfma_f32_32x32x16_bf16(a, bb, acc, 0, 0, 0);
    }
  }
  float bet = beta[wch + cl];
  float ps = 0.f, pq = 0.f;
  #pragma unroll
  for(int r = 0; r < 16; r++){
    int t = t0 + wt0 + (r&3) + 8*(r>>2) + 4*h;
    float v0 = siluf(acc[r] + bet);
    if(t < 10236){
      h5b[((size_t)b*10240 + t)*64 + wch + cl] = bf16rne(v0);
      ps += v0; pq += v0*v0;
    }
  }
  atomicAdd(&ssum[wch + cl], ps); atomicAdd(&ssq[wch + cl], pq);
  __syncthreads();
  if(tid < 64){ atomicAdd(stats+S5+tid, ssum[tid]); atomicAdd(stats+Q5+tid, ssq[tid]); }
}

// =========================================================================
// K9: dbn2 normalize + 1x1 conv (64->1) + bias; also writes commit loss.
__global__ void k9(const unsigned short* __restrict__ h5b, const float* __restrict__ w3,
                   const float* __restrict__ b3, const float* __restrict__ g5,
                   const float* __restrict__ bb5, const float* stats,
                   float* __restrict__ out){
  __shared__ float WA[64], WB[64];
  int tid = threadIdx.x;
  if(blockIdx.x == 0 && blockIdx.y == 0 && tid == 0)
    out[98304] = 2.f * stats[SLOSS] / 1048576.f;
  if(tid < 64){
    float mu = stats[S5+tid]/81888.f;
    float var = stats[Q5+tid]/81888.f - mu*mu;
    float rs = rsqrtf(var + 1e-5f);
    float A = rs*g5[tid], B = bb5[tid] - mu*rs*g5[tid];
    float w = w3[tid];
    WA[tid] = w*A; WB[tid] = w*B;
  }
  __syncthreads();
  int b = blockIdx.y;
  int t = blockIdx.x*256 + tid;
  float acc = b3[0];
  if(t < 10236){
    const unsigned short* hp = h5b + ((size_t)b*10240 + t)*64;
    #pragma unroll
    for(int q = 0; q < 8; q++){
      uint4 u = *(const uint4*)(hp + q*8);
      unsigned int ua[4] = {u.x, u.y, u.z, u.w};
      #pragma unroll
      for(int w = 0; w < 4; w++){
        int c = q*8 + w*2;
        acc += WA[c]*bf16tof((unsigned short)(ua[w] & 0xFFFFu)) + WB[c];
        acc += WA[c+1]*bf16tof((unsigned short)(ua[w] >> 16)) + WB[c+1];
      }
    }
  } else acc = 0.f;
  out[b*10240 + t] = acc;
}

// =========================================================================
extern "C" void kernel_launch(void* const* d_in, const int* in_sizes, int n_in,
                              void* d_out, int out_size, void* d_ws, size_t ws_size,
                              hipStream_t stream){
  const float* x   = (const float*)d_in[0];
  const float* ew1 = (const float*)d_in[1];
  const float* eb1 = (const float*)d_in[2];
  const float* g1  = (const float*)d_in[3];
  const float* bb1 = (const float*)d_in[4];
  const float* ew2 = (const float*)d_in[5];
  const float* eb2 = (const float*)d_in[6];
  const float* g2  = (const float*)d_in[7];
  const float* bb2 = (const float*)d_in[8];
  const float* ew3 = (const float*)d_in[9];
  const float* eb3 = (const float*)d_in[10];
  const float* g3  = (const float*)d_in[11];
  const float* bb3 = (const float*)d_in[12];
  const float* cb  = (const float*)d_in[13];
  const float* dwt = (const float*)d_in[14];
  const float* g4  = (const float*)d_in[15];
  const float* bb4 = (const float*)d_in[16];
  const float* w2d = (const float*)d_in[17];
  const float* b2d = (const float*)d_in[18];
  const float* g5  = (const float*)d_in[19];
  const float* bb5 = (const float*)d_in[20];
  const float* w3d = (const float*)d_in[21];
  const float* b3d = (const float*)d_in[22];

  char* ws = (char*)d_ws;
  float* h1   = (float*)(ws + 0);
  unsigned short* cbsw = (unsigned short*)(ws + 0);         // 2,097,152
  float* cnw  = (float*)(ws + 2097152);                     // 32,768
  float* cnw2 = (float*)(ws + 2129920);                     // 32,768
  float* h2   = (float*)(ws + 5242880);
  float* zn   = (float*)(ws + 15728640);
  unsigned short* h4t = (unsigned short*)(ws + 0);          // 10,493,952
  unsigned short* h5b = (unsigned short*)(ws + 20971520);   // 10,485,760
  int*   list = (int*)  (ws + 20971520);                    // 65,536 (time-disjoint vs h5b)
  int*   cnt  = (int*)  (ws + 21037056);                    // 256
  unsigned int* pbk = (unsigned int*)(ws + 21037312);       // 524,288
  unsigned int* psk = (unsigned int*)(ws + 21561600);       // 524,288
  float* pxd  = (float*)(ws + 22085888);                    // 524,288
  int*   pxi  = (int*)  (ws + 22610176);                    // 524,288
  unsigned short* wbt = (unsigned short*)(ws + 31457280);   // 40,960
  float* beta = (float*)(ws + 31498240);                    // 256
  unsigned short* wb7 = (unsigned short*)(ws + 32000000);   // 204,800 (gap)
  unsigned short* cbb = (unsigned short*)(ws + 32300032);   // 1,048,576 (gap)
  float* w3t  = (float*)(ws + 41934848);
  float* dwtt = (float*)(ws + 42139648);
  int*   idxw = (int*)  (ws + 42549248);
  float* stats= (float*)(ws + 42614784);
  if(ws_size < 42616832) return;

  float* out = (float*)d_out;  // f32: [recon 81920][idx 16384][loss 1]

  hipMemsetAsync(stats, 0, NSTATF*4, stream);
  k_prep<<<600, 256, 0, stream>>>(ew3, dwt, w3t, dwtt, wb7);
  k1<<<dim3(40,8), 256, 0, stream>>>(x, ew1, eb1, h1, stats);
  k2<<<dim3(40,8), 256, 0, stream>>>(h1, ew2, eb2, g1, bb1, h2, stats);
  k_prep2<<<32, 256, 0, stream>>>(cb, cbsw, cnw, cnw2, cbb, cnt);
  k3<<<dim3(128,8), 256, 0, stream>>>(h2, w3t, eb3, g2, bb2, zn, stats);
  k3b<<<1024, 256, 0, stream>>>(zn, g3, bb3, stats);
  k5m<<<dim3(NCHUNK,128), 256, 0, stream>>>(zn, cbsw, cnw2, pbk, psk);
  k5r<<<64, 256, 0, stream>>>(pbk, psk, idxw, out + 81920, list, cnt);
  k5x<<<dim3(NCHUNK,256), 256, 0, stream>>>(zn, cb, cnw, list, cnt, pxd, pxi);
  k5x2<<<64, 256, 0, stream>>>(pxd, pxi, list, cnt, idxw, out + 81920);
  k_loss<<<64, 256, 0, stream>>>(zn, cb, idxw, stats);
  k7m<<<dim3(64,8), 320, 0, stream>>>(idxw, cbb, wb7, h4t, stats);
  k8w<<<1, 256, 0, stream>>>(w2d, b2d, g4, bb4, stats, wbt, beta, (unsigned int*)h4t);
  k8<<<dim3(160,8), 256, 0, stream>>>(h4t, wbt, beta, h5b, stats);
  k9<<<dim3(40,8), 256, 0, stream>>>(h5b, w3d, b3d, g5, bb5, stats, out);
}

// Round 10
// 360.505 us; speedup vs baseline: 1.8718x; 1.0791x over previous
//
#include <hip/hip_runtime.h>
#include <hip/hip_bf16.h>

#define DEV __device__ __forceinline__

typedef __attribute__((ext_vector_type(8))) short s8v;     // 8 bf16 (4 VGPR)
typedef __attribute__((ext_vector_type(16))) float f32x16; // MFMA 32x32 acc
typedef __attribute__((address_space(1))) const unsigned int u32g;
typedef __attribute__((address_space(3))) unsigned int u32l;

DEV void gl_lds(const void* g, void* l){   // 16B async global->LDS
  __builtin_amdgcn_global_load_lds((u32g*)g, (u32l*)l, 16, 0, 0);
}

DEV float siluf(float x){ return x / (1.f + expf(-x)); }

DEV float wredsum(float v){
  #pragma unroll
  for(int m = 32; m; m >>= 1) v += __shfl_xor(v, m);
  return v;
}

DEV unsigned short bf16rne(float f){
  unsigned int u = __float_as_uint(f);
  u += 0x7FFFu + ((u >> 16) & 1u);
  return (unsigned short)(u >> 16);
}
DEV float bf16tof(unsigned short h){ return __uint_as_float(((unsigned int)h) << 16); }

// sk' = min(sk, max(bk, k)) given bk<=sk  ==  median(sk, bk, k), one VALU op.
DEV unsigned umed3(unsigned a, unsigned b, unsigned c){
  unsigned d;
  asm("v_med3_u32 %0, %1, %2, %3" : "=v"(d) : "v"(a), "v"(b), "v"(c));
  return d;
}

// ---- stats layout (float offsets within stats block) ----
#define S1 0
#define Q1 16
#define S2 32
#define Q2 64
#define S3 96
#define Q3 160
#define S4 224
#define Q4 288
#define S5 352
#define Q5 416
#define SLOSS 480
#define NSTATF 512

#define EPSQ 6u
#define NCHUNK 8

// =========================================================================
// K_prep: transpose enc_w3 -> w3t; dec_wt -> dwtt (f32) and wb7 (bf16 GEMM-B)
__global__ void k_prep(const float* ew3, const float* dwt, float* w3t, float* dwtt,
                       unsigned short* wb7){
  const int n1 = 64*32*25, n2 = 64*64*25;
  for(int i = blockIdx.x*blockDim.x + threadIdx.x; i < n1+n2; i += gridDim.x*blockDim.x){
    if(i < n1){
      int c = i/(32*25), r = i - c*(32*25), ii = r/25, k = r - ii*25;
      w3t[(ii*25 + k)*64 + c] = ew3[i];
    } else {
      int j = i - n1;
      int ii = j/(64*25), r = j - ii*(64*25), o = r/25, k = r - o*25;
      float w = dwt[j];
      dwtt[(ii*25 + k)*64 + o] = w;
      wb7[((size_t)(k*64 + o))*64 + ii] = bf16rne(w);
    }
  }
}

// =========================================================================
// K_prep2: codebook -> pre-swizzled bf16 hi/lo rows + norms + plain bf16 cbb.
__global__ void k_prep2(const float* __restrict__ cb, unsigned short* __restrict__ cbsw,
                        float* __restrict__ cnw, float* __restrict__ cnw2,
                        unsigned short* __restrict__ cbb, int* cnt){
  if(blockIdx.x == 0 && threadIdx.x == 0) *cnt = 0;
  int j = blockIdx.x*256 + threadIdx.x;
  if(j < 8192){
    float nrm = 0.f;
    unsigned swz = (j & 15) << 4;
    char* rowp = (char*)cbsw + (size_t)j*256;
    #pragma unroll
    for(int k = 0; k < 64; k++){
      float x = cb[(size_t)j*64 + k];
      unsigned short hi = bf16rne(x);
      float lo = x - bf16tof(hi);
      *(unsigned short*)(rowp + (((unsigned)(2*k)) ^ swz)) = hi;
      *(unsigned short*)(rowp + (((unsigned)(128 + 2*k)) ^ swz)) = bf16rne(lo);
      cbb[(size_t)j*64 + k] = hi;
      nrm = fmaf(x, x, nrm);
    }
    cnw[j] = nrm;
    cnw2[j] = (nrm + 1024.f) * 256.f;
  }
}

// =========================================================================
// K1: conv1 (1->16, K=5, pad2) + silu + bn1 stats.
// Lane owns a channel (c = tid&15, weights in VGPR); 128-t tiles, grid (80,8).
__global__ void k1(const float* __restrict__ x, const float* __restrict__ w1,
                   const float* __restrict__ b1, float* __restrict__ h1, float* stats){
  __shared__ float xs[136];
  __shared__ float ssum[16], ssq[16];
  int tid = threadIdx.x, b = blockIdx.y, t0 = blockIdx.x*128;
  if(tid < 16){ ssum[tid] = 0.f; ssq[tid] = 0.f; }
  for(int i = tid; i < 132; i += 256){
    int t = t0 + i - 2;
    xs[i] = (t >= 0 && t < 10240) ? x[b*10240 + t] : 0.f;
  }
  __syncthreads();
  int c = tid & 15, sgrp = tid >> 4;     // 16 channels x 16 t-groups of 8
  float w[5];
  #pragma unroll
  for(int k = 0; k < 5; k++) w[k] = w1[c*5 + k];
  float bias = b1[c];
  float outv[8];
  float ps = 0.f, pq = 0.f;
  #pragma unroll
  for(int s = 0; s < 8; s++){
    float a = bias;
    #pragma unroll
    for(int k = 0; k < 5; k++) a = fmaf(w[k], xs[sgrp*8 + s + k], a);
    a = siluf(a);
    outv[s] = a;
    ps += a; pq += a*a;
  }
  float* op = h1 + ((size_t)(b*16 + c))*10240 + t0 + sgrp*8;
  #pragma unroll
  for(int q = 0; q < 2; q++)
    *(float4*)(op + q*4) = make_float4(outv[q*4], outv[q*4+1], outv[q*4+2], outv[q*4+3]);
  ps += __shfl_xor(ps, 16); pq += __shfl_xor(pq, 16);
  ps += __shfl_xor(ps, 32); pq += __shfl_xor(pq, 32);
  if((tid & 48) == 0){ atomicAdd(&ssum[c], ps); atomicAdd(&ssq[c], pq); }
  __syncthreads();
  if(tid < 16){ atomicAdd(stats+S1+tid, ssum[tid]); atomicAdd(stats+Q1+tid, ssq[tid]); }
}

// =========================================================================
// K2: bn1 normalize + conv2 (16->32, K=5, pad2) + silu + bn2 stats.
// Lane owns a channel (c = tid&31, 80 weights in VGPR, 4x20 chunks); 128-t
// tiles, grid (80,8). Per-output FMA nest identical to original -> h2 bitwise.
__global__ __launch_bounds__(256) void k2(const float* __restrict__ h1,
                   const float* __restrict__ w2, const float* __restrict__ b2,
                   const float* __restrict__ g1, const float* __restrict__ bb1,
                   float* __restrict__ h2out, float* stats){
  __shared__ float hs[16][136];
  __shared__ float A1s[16], B1s[16];
  __shared__ float ssum[32], ssq[32];
  int tid = threadIdx.x, b = blockIdx.y, t0 = blockIdx.x*128;
  if(tid < 16){
    float mu = stats[S1+tid]/81920.f;
    float var = stats[Q1+tid]/81920.f - mu*mu;
    float rs = rsqrtf(var + 1e-5f);
    A1s[tid] = rs*g1[tid];
    B1s[tid] = bb1[tid] - mu*rs*g1[tid];
  }
  if(tid < 32){ ssum[tid] = 0.f; ssq[tid] = 0.f; }
  __syncthreads();
  {
    int ch = tid >> 4, j0 = tid & 15;
    float A = A1s[ch], B = B1s[ch];
    const float* hp = h1 + ((size_t)(b*16 + ch))*10240;
    for(int j = j0; j < 132; j += 16){
      int t = t0 + j - 2;
      hs[ch][j] = (t >= 0 && t < 10240) ? hp[t]*A + B : 0.f;
    }
  }
  __syncthreads();
  int c = tid & 31, tgrp = tid >> 5;     // 32 channels x 8 t-groups of 16
  int tb = tgrp*16;
  float acc[16];
  float bias = b2[c];
  #pragma unroll
  for(int s = 0; s < 16; s++) acc[s] = bias;
  for(int ic = 0; ic < 4; ic++){
    float wf[20];
    const float* wp = w2 + c*80 + ic*20;
    #pragma unroll
    for(int q = 0; q < 5; q++) *(float4*)(wf + q*4) = *(const float4*)(wp + q*4);
    #pragma unroll
    for(int di = 0; di < 4; di++){
      int i = ic*4 + di;
      float z[20];
      #pragma unroll
      for(int q = 0; q < 5; q++) *(float4*)(z + q*4) = *(const float4*)(&hs[i][tb] + q*4);
      float w0 = wf[di*5], w1 = wf[di*5+1], w2v = wf[di*5+2], w3 = wf[di*5+3], w4 = wf[di*5+4];
      #pragma unroll
      for(int s = 0; s < 16; s++)
        acc[s] = fmaf(w0, z[s], fmaf(w1, z[s+1], fmaf(w2v, z[s+2],
                 fmaf(w3, z[s+3], fmaf(w4, z[s+4], acc[s])))));
    }
  }
  float ps = 0.f, pq = 0.f;
  #pragma unroll
  for(int s = 0; s < 16; s++){
    float a = siluf(acc[s]);
    acc[s] = a;
    ps += a; pq += a*a;
  }
  float* op = h2out + ((size_t)(b*32 + c))*10240 + t0 + tb;
  #pragma unroll
  for(int q = 0; q < 4; q++)
    *(float4*)(op + q*4) = make_float4(acc[q*4], acc[q*4+1], acc[q*4+2], acc[q*4+3]);
  ps += __shfl_xor(ps, 32); pq += __shfl_xor(pq, 32);
  if((tid & 32) == 0){ atomicAdd(&ssum[c], ps); atomicAdd(&ssq[c], pq); }
  __syncthreads();
  if(tid < 32){ atomicAdd(stats+S2+tid, ssum[tid]); atomicAdd(stats+Q2+tid, ssq[tid]); }
}

// =========================================================================
// K3: bn2 normalize + conv3 (32->64, K=25, stride5, pad12) + tanh + bn3 stats
__global__ void k3(const float* __restrict__ h2, const float* __restrict__ w3t,
                   const float* __restrict__ eb3, const float* __restrict__ g2,
                   const float* __restrict__ bb2, float* __restrict__ zn, float* stats){
  __shared__ __align__(16) float X[5*32*24];   // [kk][ch][m], m<20 valid
  __shared__ float A2[32], B2[32];
  __shared__ float ssum[64], ssq[64];
  int tid = threadIdx.x, b = blockIdx.y, l0 = blockIdx.x*16;
  if(tid < 32){
    float mu = stats[S2+tid]/81920.f;
    float var = stats[Q2+tid]/81920.f - mu*mu;
    float rs = rsqrtf(var + 1e-5f);
    A2[tid] = rs*g2[tid];
    B2[tid] = bb2[tid] - mu*rs*g2[tid];
  }
  if(tid < 64){ ssum[tid] = 0.f; ssq[tid] = 0.f; }
  __syncthreads();
  for(int i2 = tid; i2 < 5*32*20; i2 += 256){
    int kk = i2/640;
    int r  = i2 - kk*640;
    int ch = r/20, m = r - ch*20;
    int t = 5*(l0 + m) + kk - 12;
    float v = 0.f;
    if(t >= 0 && t < 10240) v = h2[((b*32+ch)*10240)+t]*A2[ch] + B2[ch];
    X[(kk*32+ch)*24 + m] = v;
  }
  __syncthreads();
  int c = tid & 63, lslot = tid >> 6;   // 4 slots x 4 l
  float acc[4];
  float bias = eb3[c];
  #pragma unroll
  for(int s = 0; s < 4; s++) acc[s] = bias;
  for(int i = 0; i < 32; i++){
    #pragma unroll
    for(int kk = 0; kk < 5; kk++){
      const float* xp = &X[(kk*32+i)*24 + lslot*4];
      float4 za = *(const float4*)(xp);
      float4 zb = *(const float4*)(xp + 4);
      float z[8] = {za.x,za.y,za.z,za.w,zb.x,zb.y,zb.z,zb.w};
      #pragma unroll
      for(int kap = 0; kap < 5; kap++){
        float w = w3t[(i*25 + kap*5 + kk)*64 + c];
        #pragma unroll
        for(int s = 0; s < 4; s++) acc[s] = fmaf(w, z[s+kap], acc[s]);
      }
    }
  }
  float ls = 0.f, lq = 0.f;
  #pragma unroll
  for(int s = 0; s < 4; s++){
    int l = l0 + lslot*4 + s;
    float a = tanhf(acc[s]);
    zn[((b*2048 + l)*64) + c] = a;
    ls += a; lq += a*a;
  }
  atomicAdd(&ssum[c], ls); atomicAdd(&ssq[c], lq);
  __syncthreads();
  if(tid < 64){ atomicAdd(stats+S3+tid, ssum[tid]); atomicAdd(stats+Q3+tid, ssq[tid]); }
}

// =========================================================================
// K3b: bn3 normalize zn in place
__global__ void k3b(float* zn, const float* g3, const float* b3, const float* stats){
  __shared__ float A[64], B[64];
  int tid = threadIdx.x;
  if(tid < 64){
    float mu = stats[S3+tid]/16384.f;
    float var = stats[Q3+tid]/16384.f - mu*mu;
    float rs = rsqrtf(var + 1e-5f);
    A[tid] = rs*g3[tid];
    B[tid] = b3[tid] - mu*rs*g3[tid];
  }
  __syncthreads();
  for(int i = blockIdx.x*256 + tid; i < 16384*64; i += gridDim.x*256){
    int c = i & 63;
    zn[i] = zn[i]*A[c] + B[c];
  }
}

// =========================================================================
// K5m: MFMA VQ pass, M=128 rows/block. launch_bounds(256,4) caps combined
// regs at 128 to lift occupancy (round-9 diagnosis: AGPR pressure -> 20%).
__global__ __launch_bounds__(256, 4) void k5m(const float* __restrict__ zn,
    const unsigned short* __restrict__ cbsw, const float* __restrict__ cnw2,
    unsigned int* __restrict__ pbk, unsigned int* __restrict__ psk){
  __shared__ __align__(16) unsigned char cbuf[2][16384];
  int tid = threadIdx.x;
  int chunk = blockIdx.x;
  int m0 = blockIdx.y * 128;
  int lane = tid & 63, wr = tid >> 6;
  int h = lane >> 5, cll = lane & 31;
  int row = m0 + wr*32 + cll;

  s8v ah[4], al[4];
  const float* zp = zn + (size_t)row*64;
  #pragma unroll
  for(int s = 0; s < 4; s++){
    float4 v0 = *(const float4*)(zp + s*16 + h*8);
    float4 v1 = *(const float4*)(zp + s*16 + h*8 + 4);
    float vv[8] = {v0.x,v0.y,v0.z,v0.w,v1.x,v1.y,v1.z,v1.w};
    #pragma unroll
    for(int i = 0; i < 8; i++){
      unsigned short hi = bf16rne(vv[i]);
      ah[s][i] = (short)hi;
      al[s][i] = (short)bf16rne(vv[i] - bf16tof(hi));
    }
  }

  unsigned int bk[16], sk[16];
  #pragma unroll
  for(int r = 0; r < 16; r++){ bk[r] = 0xFFFFFFFFu; sk[r] = 0xFFFFFFFFu; }
  f32x16 zv;
  #pragma unroll
  for(int i = 0; i < 16; i++) zv[i] = 0.f;

  int c0 = chunk * 1024;
  const char* csrc = (const char*)cbsw + (size_t)c0*256;
  #pragma unroll
  for(int c2 = 0; c2 < 4; c2++)
    gl_lds(csrc + c2*4096 + tid*16, &cbuf[0][0] + c2*4096 + tid*16);
  __syncthreads();

  unsigned swz = (unsigned)(cll & 15) << 4;
  for(int tile = 0; tile < 16; ++tile){
    int bsel = tile & 1;
    if(tile < 15){
      const char* ns = csrc + (size_t)(tile+1)*16384;
      #pragma unroll
      for(int c2 = 0; c2 < 4; c2++)
        gl_lds(ns + c2*4096 + tid*16, &cbuf[bsel^1][0] + c2*4096 + tid*16);
    }
    #pragma unroll
    for(int half = 0; half < 2; half++){
      const unsigned char* bp = &cbuf[bsel][0] + (half*32 + cll)*256;
      s8v bh[4], bl[4];
      #pragma unroll
      for(int s = 0; s < 4; s++){
        bh[s] = *(const s8v*)(bp + (((unsigned)(s*32 + h*16)) ^ swz));
        bl[s] = *(const s8v*)(bp + (((unsigned)(128 + s*32 + h*16)) ^ swz));
      }
      unsigned col = (unsigned)(c0 + tile*64 + half*32 + cll);
      float cnv2 = cnw2[col];
      f32x16 a1 = __builtin_amdgcn_mfma_f32_32x32x16_bf16(ah[0], bh[0], zv, 0, 0, 0);
      f32x16 a2 = __builtin_amdgcn_mfma_f32_32x32x16_bf16(al[0], bh[0], zv, 0, 0, 0);
      a2 = __builtin_amdgcn_mfma_f32_32x32x16_bf16(ah[0], bl[0], a2, 0, 0, 0);
      #pragma unroll
      for(int s = 1; s < 4; s++){
        a1 = __builtin_amdgcn_mfma_f32_32x32x16_bf16(ah[s], bh[s], a1, 0, 0, 0);
        a2 = __builtin_amdgcn_mfma_f32_32x32x16_bf16(al[s], bh[s], a2, 0, 0, 0);
        a2 = __builtin_amdgcn_mfma_f32_32x32x16_bf16(ah[s], bl[s], a2, 0, 0, 0);
      }
      #pragma unroll
      for(int r = 0; r < 16; r++){
        float q = fmaf(-512.f, a1[r], cnv2);
        q = fmaf(-512.f, a2[r], q);
        q = fminf(q, 524287.f);
        unsigned k = (((unsigned)q) << 13) | col;
        unsigned nb = bk[r] < k ? bk[r] : k;
        sk[r] = umed3(sk[r], bk[r], k);
        bk[r] = nb;
      }
    }
    __syncthreads();
  }

  #pragma unroll
  for(int m = 1; m <= 16; m <<= 1){
    #pragma unroll
    for(int r = 0; r < 16; r++){
      unsigned int ob = (unsigned int)__shfl_xor((int)bk[r], m);
      unsigned int os = (unsigned int)__shfl_xor((int)sk[r], m);
      unsigned int s2 = sk[r] < os ? sk[r] : os;
      sk[r] = umed3(s2, bk[r], ob);
      bk[r] = bk[r] < ob ? bk[r] : ob;
    }
  }
  if(cll == 0){
    size_t base = (size_t)chunk*16384 + m0 + wr*32 + 4*h;
    #pragma unroll
    for(int r = 0; r < 16; r++){
      int lr = (r&3) + 8*(r>>2);
      pbk[base + lr] = bk[r];
      psk[base + lr] = sk[r];
    }
  }
}

// =========================================================================
// K5r: merge chunk partials; write idx; flag close calls.
__global__ void k5r(const unsigned int* __restrict__ pbk,
                    const unsigned int* __restrict__ psk, int* __restrict__ idxw,
                    float* __restrict__ out_idx, int* __restrict__ list, int* cnt){
  int row = blockIdx.x*256 + threadIdx.x;  // grid 64
  unsigned int bk = pbk[row], sk = psk[row];
  #pragma unroll
  for(int c = 1; c < NCHUNK; c++){
    unsigned int ob = pbk[(size_t)c*16384 + row];
    unsigned int os = psk[(size_t)c*16384 + row];
    unsigned int s2 = sk < os ? sk : os;
    sk = umed3(s2, bk, ob);
    bk = bk < ob ? bk : ob;
  }
  int idx = (int)(bk & 0x1FFFu);
  idxw[row] = idx;
  out_idx[row] = (float)idx;
  if((sk >> 13) - (bk >> 13) <= EPSQ){
    int p = atomicAdd(cnt, 1);
    list[p] = row;
  }
}

// =========================================================================
// K5x: exact f32 rescore, row-parallel.
__global__ __launch_bounds__(256) void k5x(const float* __restrict__ zn,
    const float* __restrict__ cb, const float* __restrict__ cnw,
    const int* __restrict__ list, const int* cnt,
    float* __restrict__ pxd, int* __restrict__ pxi){
  int tid = threadIdx.x;
  int chunk = blockIdx.x;
  int n = *cnt;
  int rgrp = tid >> 6, cs = tid & 63;
  int c0 = chunk * 1024;
  for(int bat = blockIdx.y; bat*4 < n; bat += 256){
    int e = bat*4 + rgrp;
    int ec = e < n ? e : n-1;
    int row = list[ec];
    float4 zr[16];
    const float4* zp = (const float4*)(zn + (size_t)row*64);
    #pragma unroll
    for(int q = 0; q < 16; q++) zr[q] = zp[q];
    float bd = 3.4e38f; int bi = 0;
    for(int step = 0; step < 16; step++){
      int j = c0 + step*64 + cs;
      const float4* cp = (const float4*)(cb + (size_t)j*64);
      float cnv = cnw[j];
      float da = 0.f, db = 0.f;
      #pragma unroll
      for(int q = 0; q < 16; q += 2){
        float4 ca = cp[q], cb4 = cp[q+1];
        da = fmaf(ca.x, zr[q].x, da);  da = fmaf(ca.y, zr[q].y, da);
        da = fmaf(ca.z, zr[q].z, da);  da = fmaf(ca.w, zr[q].w, da);
        db = fmaf(cb4.x, zr[q+1].x, db); db = fmaf(cb4.y, zr[q+1].y, db);
        db = fmaf(cb4.z, zr[q+1].z, db); db = fmaf(cb4.w, zr[q+1].w, db);
      }
      float d = fmaf(-2.f, da + db, cnv);
      if(d < bd){ bd = d; bi = j; }
    }
    #pragma unroll
    for(int m = 1; m <= 32; m <<= 1){
      float od = __shfl_xor(bd, m);
      int   oi = __shfl_xor(bi, m);
      if(od < bd || (od == bd && oi < bi)){ bd = od; bi = oi; }
    }
    if(cs == 0 && e < n){
      pxd[(size_t)chunk*16384 + e] = bd;
      pxi[(size_t)chunk*16384 + e] = bi;
    }
  }
}

// =========================================================================
// K5x2: merge chunk partials per flagged row -> final idx.
__global__ void k5x2(const float* __restrict__ pxd, const int* __restrict__ pxi,
                     const int* __restrict__ list, const int* cnt,
                     int* __restrict__ idxw, float* __restrict__ out_idx){
  int e = blockIdx.x*256 + threadIdx.x;  // grid 64
  int n = *cnt;
  if(e >= n) return;
  float bd = pxd[e]; int bi = pxi[e];
  #pragma unroll
  for(int c = 1; c < NCHUNK; c++){
    float od = pxd[(size_t)c*16384 + e];
    int   oi = pxi[(size_t)c*16384 + e];
    if(od < bd || (od == bd && oi < bi)){ bd = od; bi = oi; }
  }
  int row = list[e];
  idxw[row] = bi;
  out_idx[row] = (float)bi;
}

// =========================================================================
// K_loss: commit loss from final indices
__global__ void k_loss(const float* __restrict__ zn, const float* __restrict__ cb,
                       const int* __restrict__ idxw, float* stats){
  int row = blockIdx.x*256 + threadIdx.x;  // grid 64
  int code = idxw[row];
  const float* cp = cb + (size_t)code*64;
  const float* zp = zn + (size_t)row*64;
  float s = 0.f;
  #pragma unroll
  for(int k = 0; k < 64; k++){
    float dd = cp[k] - zp[k];
    s = fmaf(dd, dd, s);
  }
  float tot = wredsum(s);
  if((threadIdx.x & 63) == 0) atomicAdd(stats + SLOSS, tot);
}

// =========================================================================
// K7m: transposed conv as MFMA GEMM (unchanged).
__global__ __launch_bounds__(320) void k7m(const int* __restrict__ idxp,
    const unsigned short* __restrict__ cbb, const unsigned short* __restrict__ wb7,
    unsigned short* __restrict__ h4t, float* stats){
  __shared__ __align__(16) unsigned char lA[37*128];
  __shared__ float tb[5*64*33];
  __shared__ float ssum[64], ssq[64];
  int tid = threadIdx.x, b = blockIdx.y, u0 = blockIdx.x*32;
  if(tid < 64){ ssum[tid] = 0.f; ssq[tid] = 0.f; }
  {
    int m = tid >> 3, part = tid & 7;
    if(m < 37){
      int u = u0 - 2 + m;
      uint4 val = make_uint4(0,0,0,0);
      if(u >= 0 && u < 2048){
        int code = idxp[b*2048 + u];
        val = *(const uint4*)((const char*)cbb + (size_t)code*128 + part*16);
      }
      *(uint4*)(lA + m*128 + (((unsigned)(part*16)) ^ (((unsigned)m & 7) << 4))) = val;
    }
  }
  __syncthreads();
  int lane = tid & 63, h = lane >> 5, cl = lane & 31;
  int v = tid >> 6;
  const int km[5]  = {2,3,4,0,1};
  const int ovv[5] = {2,2,2,3,3};
  f32x16 acc0, acc1;
  #pragma unroll
  for(int i = 0; i < 16; i++){ acc0[i] = 0.f; acc1[i] = 0.f; }
  #pragma unroll
  for(int r = 0; r < 5; r++){
    int off = ovv[v] - r + 2;
    int m = cl + off;
    unsigned aswz = ((unsigned)m & 7) << 4;
    int k = km[v] + 5*r;
    const char* b0p = (const char*)wb7 + (size_t)(k*64 + cl)*128;
    const char* b1p = b0p + 32*128;
    #pragma unroll
    for(int s = 0; s < 4; s++){
      unsigned o = (unsigned)(s*32 + h*16);
      s8v a  = *(const s8v*)(lA + m*128 + (o ^ aswz));
      s8v b0 = *(const s8v*)(b0p + o);
      s8v b1 = *(const s8v*)(b1p + o);
      acc0 = __builtin_amdgcn_mfma_f32_32x32x16_bf16(a, b0, acc0, 0, 0, 0);
      acc1 = __builtin_amdgcn_mfma_f32_32x32x16_bf16(a, b1, acc1, 0, 0, 0);
    }
  }
  float ps0 = 0.f, pq0 = 0.f, ps1 = 0.f, pq1 = 0.f;
  #pragma unroll
  for(int r = 0; r < 16; r++){
    int ul = (r&3) + 8*(r>>2) + 4*h;
    int u = u0 + ul;
    float v0 = siluf(acc0[r]), v1 = siluf(acc1[r]);
    tb[(v*64 + cl)*33 + ul]      = v0;
    tb[(v*64 + 32 + cl)*33 + ul] = v1;
    if(v == 0 || u < 2047){ ps0 += v0; pq0 += v0*v0; ps1 += v1; pq1 += v1*v1; }
  }
  atomicAdd(&ssum[cl], ps0);      atomicAdd(&ssq[cl], pq0);
  atomicAdd(&ssum[32 + cl], ps1); atomicAdd(&ssq[32 + cl], pq1);
  __syncthreads();
  if(tid < 64){ atomicAdd(stats+S4+tid, ssum[tid]); atomicAdd(stats+Q4+tid, ssq[tid]); }
  #pragma unroll
  for(int j = 0; j < 16; j++){
    int flat = j*320 + tid;
    int tl = flat >> 5;
    int chp = flat & 31;
    int t = u0*5 + tl;
    if(t < 10236){
      int vv = tl % 5, ul = tl / 5;
      float f0 = tb[(vv*64 + 2*chp)*33 + ul];
      float f1 = tb[(vv*64 + 2*chp + 1)*33 + ul];
      unsigned int pk = (unsigned int)bf16rne(f0) | ((unsigned int)bf16rne(f1) << 16);
      size_t rowb = ((size_t)b*10248 + 2 + t)*128;
      *(unsigned int*)((char*)h4t + rowb + (((unsigned)(4*chp)) ^ (((unsigned)t & 7) << 4))) = pk;
    }
  }
}

// =========================================================================
// K8w: fold dbn1 into decoder conv2 weights + beta; also zero h4t pad rows.
__global__ void k8w(const float* __restrict__ w2d, const float* __restrict__ b2d,
                    const float* __restrict__ g4, const float* __restrict__ bb4,
                    const float* __restrict__ stats, unsigned short* __restrict__ wbt,
                    float* __restrict__ beta, unsigned int* __restrict__ h4tz){
  __shared__ float A4[64], B4[64];
  int tid = threadIdx.x;
  for(int i = tid; i < 3072; i += 256){
    int b = i / 384, r = i - b*384;
    int row12 = r >> 5, word = r & 31;
    int row = row12 < 2 ? row12 : 10236 + row12;
    h4tz[((size_t)b*10248 + row)*32 + word] = 0u;
  }
  if(tid < 64){
    float mu = stats[S4+tid]/81888.f;
    float var = stats[Q4+tid]/81888.f - mu*mu;
    float rs = rsqrtf(var + 1e-5f);
    A4[tid] = rs*g4[tid];
    B4[tid] = bb4[tid] - mu*rs*g4[tid];
  }
  __syncthreads();
  for(int e = tid; e < 64*64*5; e += 256){
    int c = e/320, r = e - c*320, i = r/5, k = r - i*5;
    unsigned short hw = bf16rne(w2d[e] * A4[i]);
    int row = k*64 + c;
    *(unsigned short*)((char*)wbt + (size_t)row*128 + (((unsigned)(2*i)) ^ (((unsigned)c & 7) << 4))) = hw;
  }
  if(tid < 64){
    float s = b2d[tid];
    for(int i = 0; i < 64; i++){
      float wsum = 0.f;
      #pragma unroll
      for(int k = 0; k < 5; k++) wsum += w2d[(tid*64 + i)*5 + k];
      s += wsum * B4[i];
    }
    beta[tid] = s;
  }
}

// =========================================================================
// K8: decoder conv2 as MFMA GEMM (unchanged from round 9).
__global__ __launch_bounds__(256) void k8(const unsigned short* __restrict__ h4t,
    const unsigned short* __restrict__ wbt, const float* __restrict__ beta,
    unsigned short* __restrict__ h5b, float* stats){
  __shared__ __align__(16) unsigned char lA[68*128];
  __shared__ float ssum[64], ssq[64];
  int tid = threadIdx.x, b = blockIdx.y, t0 = blockIdx.x*64;
  if(tid < 64){ ssum[tid] = 0.f; ssq[tid] = 0.f; }
  const char* srcA = (const char*)h4t + ((size_t)b*10248 + t0)*128;
  #pragma unroll
  for(int c2 = 0; c2 < 2; c2++)
    gl_lds(srcA + c2*4096 + tid*16, lA + c2*4096 + tid*16);
  if(tid < 32) gl_lds(srcA + 8192 + tid*16, lA + 8192 + tid*16);
  __syncthreads();

  int lane = tid & 63, h = lane >> 5, cl = lane & 31;
  int widx = tid >> 6;
  int wt0 = (widx >> 1) * 32;
  int wch = (widx & 1) * 32;
  f32x16 acc;
  #pragma unroll
  for(int i = 0; i < 16; i++) acc[i] = 0.f;
  unsigned bswz = (unsigned)(cl & 7) << 4;
  #pragma unroll
  for(int k = 0; k < 5; k++){
    int l = wt0 + cl + k;
    unsigned aswz = (unsigned)((l + 6) & 7) << 4;
    const char* bp = (const char*)wbt + (size_t)(k*64 + wch + cl)*128;
    #pragma unroll
    for(int s = 0; s < 4; s++){
      unsigned o = (unsigned)(s*32 + h*16);
      s8v a  = *(const s8v*)(lA + l*128 + (o ^ aswz));
      s8v bb = *(const s8v*)(bp + (o ^ bswz));
      acc = __builtin_amdgcn_mfma_f32_32x32x16_bf16(a, bb, acc, 0, 0, 0);
    }
  }
  float bet = beta[wch + cl];
  float ps = 0.f, pq = 0.f;
  #pragma unroll
  for(int r = 0; r < 16; r++){
    int t = t0 + wt0 + (r&3) + 8*(r>>2) + 4*h;
    float v0 = siluf(acc[r] + bet);
    if(t < 10236){
      h5b[((size_t)b*10240 + t)*64 + wch + cl] = bf16rne(v0);
      ps += v0; pq += v0*v0;
    }
  }
  atomicAdd(&ssum[wch + cl], ps); atomicAdd(&ssq[wch + cl], pq);
  __syncthreads();
  if(tid < 64){ atomicAdd(stats+S5+tid, ssum[tid]); atomicAdd(stats+Q5+tid, ssq[tid]); }
}

// =========================================================================
// K9: dbn2 normalize + 1x1 conv (64->1) + bias; also writes commit loss.
__global__ void k9(const unsigned short* __restrict__ h5b, const float* __restrict__ w3,
                   const float* __restrict__ b3, const float* __restrict__ g5,
                   const float* __restrict__ bb5, const float* stats,
                   float* __restrict__ out){
  __shared__ float WA[64], WB[64];
  int tid = threadIdx.x;
  if(blockIdx.x == 0 && blockIdx.y == 0 && tid == 0)
    out[98304] = 2.f * stats[SLOSS] / 1048576.f;
  if(tid < 64){
    float mu = stats[S5+tid]/81888.f;
    float var = stats[Q5+tid]/81888.f - mu*mu;
    float rs = rsqrtf(var + 1e-5f);
    float A = rs*g5[tid], B = bb5[tid] - mu*rs*g5[tid];
    float w = w3[tid];
    WA[tid] = w*A; WB[tid] = w*B;
  }
  __syncthreads();
  int b = blockIdx.y;
  int t = blockIdx.x*256 + tid;
  float acc = b3[0];
  if(t < 10236){
    const unsigned short* hp = h5b + ((size_t)b*10240 + t)*64;
    #pragma unroll
    for(int q = 0; q < 8; q++){
      uint4 u = *(const uint4*)(hp + q*8);
      unsigned int ua[4] = {u.x, u.y, u.z, u.w};
      #pragma unroll
      for(int w = 0; w < 4; w++){
        int c = q*8 + w*2;
        acc += WA[c]*bf16tof((unsigned short)(ua[w] & 0xFFFFu)) + WB[c];
        acc += WA[c+1]*bf16tof((unsigned short)(ua[w] >> 16)) + WB[c+1];
      }
    }
  } else acc = 0.f;
  out[b*10240 + t] = acc;
}

// =========================================================================
extern "C" void kernel_launch(void* const* d_in, const int* in_sizes, int n_in,
                              void* d_out, int out_size, void* d_ws, size_t ws_size,
                              hipStream_t stream){
  const float* x   = (const float*)d_in[0];
  const float* ew1 = (const float*)d_in[1];
  const float* eb1 = (const float*)d_in[2];
  const float* g1  = (const float*)d_in[3];
  const float* bb1 = (const float*)d_in[4];
  const float* ew2 = (const float*)d_in[5];
  const float* eb2 = (const float*)d_in[6];
  const float* g2  = (const float*)d_in[7];
  const float* bb2 = (const float*)d_in[8];
  const float* ew3 = (const float*)d_in[9];
  const float* eb3 = (const float*)d_in[10];
  const float* g3  = (const float*)d_in[11];
  const float* bb3 = (const float*)d_in[12];
  const float* cb  = (const float*)d_in[13];
  const float* dwt = (const float*)d_in[14];
  const float* g4  = (const float*)d_in[15];
  const float* bb4 = (const float*)d_in[16];
  const float* w2d = (const float*)d_in[17];
  const float* b2d = (const float*)d_in[18];
  const float* g5  = (const float*)d_in[19];
  const float* bb5 = (const float*)d_in[20];
  const float* w3d = (const float*)d_in[21];
  const float* b3d = (const float*)d_in[22];

  char* ws = (char*)d_ws;
  float* h1   = (float*)(ws + 0);
  unsigned short* cbsw = (unsigned short*)(ws + 0);         // 2,097,152
  float* cnw  = (float*)(ws + 2097152);                     // 32,768
  float* cnw2 = (float*)(ws + 2129920);                     // 32,768
  float* h2   = (float*)(ws + 5242880);
  float* zn   = (float*)(ws + 15728640);
  unsigned short* h4t = (unsigned short*)(ws + 0);          // 10,493,952
  unsigned short* h5b = (unsigned short*)(ws + 20971520);   // 10,485,760
  int*   list = (int*)  (ws + 20971520);                    // 65,536 (time-disjoint vs h5b)
  int*   cnt  = (int*)  (ws + 21037056);                    // 256
  unsigned int* pbk = (unsigned int*)(ws + 21037312);       // 524,288
  unsigned int* psk = (unsigned int*)(ws + 21561600);       // 524,288
  float* pxd  = (float*)(ws + 22085888);                    // 524,288
  int*   pxi  = (int*)  (ws + 22610176);                    // 524,288
  unsigned short* wbt = (unsigned short*)(ws + 31457280);   // 40,960
  float* beta = (float*)(ws + 31498240);                    // 256
  unsigned short* wb7 = (unsigned short*)(ws + 32000000);   // 204,800 (gap)
  unsigned short* cbb = (unsigned short*)(ws + 32300032);   // 1,048,576 (gap)
  float* w3t  = (float*)(ws + 41934848);
  float* dwtt = (float*)(ws + 42139648);
  int*   idxw = (int*)  (ws + 42549248);
  float* stats= (float*)(ws + 42614784);
  if(ws_size < 42616832) return;

  float* out = (float*)d_out;  // f32: [recon 81920][idx 16384][loss 1]

  hipMemsetAsync(stats, 0, NSTATF*4, stream);
  k_prep<<<600, 256, 0, stream>>>(ew3, dwt, w3t, dwtt, wb7);
  k1<<<dim3(80,8), 256, 0, stream>>>(x, ew1, eb1, h1, stats);
  k2<<<dim3(80,8), 256, 0, stream>>>(h1, ew2, eb2, g1, bb1, h2, stats);
  k_prep2<<<32, 256, 0, stream>>>(cb, cbsw, cnw, cnw2, cbb, cnt);
  k3<<<dim3(128,8), 256, 0, stream>>>(h2, w3t, eb3, g2, bb2, zn, stats);
  k3b<<<1024, 256, 0, stream>>>(zn, g3, bb3, stats);
  k5m<<<dim3(NCHUNK,128), 256, 0, stream>>>(zn, cbsw, cnw2, pbk, psk);
  k5r<<<64, 256, 0, stream>>>(pbk, psk, idxw, out + 81920, list, cnt);
  k5x<<<dim3(NCHUNK,256), 256, 0, stream>>>(zn, cb, cnw, list, cnt, pxd, pxi);
  k5x2<<<64, 256, 0, stream>>>(pxd, pxi, list, cnt, idxw, out + 81920);
  k_loss<<<64, 256, 0, stream>>>(zn, cb, idxw, stats);
  k7m<<<dim3(64,8), 320, 0, stream>>>(idxw, cbb, wb7, h4t, stats);
  k8w<<<1, 256, 0, stream>>>(w2d, b2d, g4, bb4, stats, wbt, beta, (unsigned int*)h4t);
  k8<<<dim3(160,8), 256, 0, stream>>>(h4t, wbt, beta, h5b, stats);
  k9<<<dim3(40,8), 256, 0, stream>>>(h5b, w3d, b3d, g5, bb5, stats, out);
}

// Round 11
// 330.267 us; speedup vs baseline: 2.0432x; 1.0916x over previous
//
#include <hip/hip_runtime.h>
#include <hip/hip_bf16.h>

#define DEV __device__ __forceinline__

typedef __attribute__((ext_vector_type(8))) short s8v;     // 8 bf16 (4 VGPR)
typedef __attribute__((ext_vector_type(16))) float f32x16; // MFMA 32x32 acc
typedef __attribute__((address_space(1))) const unsigned int u32g;
typedef __attribute__((address_space(3))) unsigned int u32l;

DEV void gl_lds(const void* g, void* l){   // 16B async global->LDS
  __builtin_amdgcn_global_load_lds((u32g*)g, (u32l*)l, 16, 0, 0);
}

DEV float siluf(float x){ return x / (1.f + expf(-x)); }

DEV float wredsum(float v){
  #pragma unroll
  for(int m = 32; m; m >>= 1) v += __shfl_xor(v, m);
  return v;
}

DEV unsigned short bf16rne(float f){
  unsigned int u = __float_as_uint(f);
  u += 0x7FFFu + ((u >> 16) & 1u);
  return (unsigned short)(u >> 16);
}
DEV float bf16tof(unsigned short h){ return __uint_as_float(((unsigned int)h) << 16); }

// sk' = min(sk, max(bk, k)) given bk<=sk  ==  median(sk, bk, k), one VALU op.
DEV unsigned umed3(unsigned a, unsigned b, unsigned c){
  unsigned d;
  asm("v_med3_u32 %0, %1, %2, %3" : "=v"(d) : "v"(a), "v"(b), "v"(c));
  return d;
}

// ---- stats layout (float offsets within stats block) ----
#define S1 0
#define Q1 16
#define S2 32
#define Q2 64
#define S3 96
#define Q3 160
#define S4 224
#define Q4 288
#define S5 352
#define Q5 416
#define SLOSS 480
#define NSTATF 512

#define EPSQ 6u
#define NCHUNK 8

// =========================================================================
// K_prep: transpose enc_w3 -> w3t; dec_wt -> dwtt (f32) and wb7 (bf16 GEMM-B)
__global__ void k_prep(const float* ew3, const float* dwt, float* w3t, float* dwtt,
                       unsigned short* wb7){
  const int n1 = 64*32*25, n2 = 64*64*25;
  for(int i = blockIdx.x*blockDim.x + threadIdx.x; i < n1+n2; i += gridDim.x*blockDim.x){
    if(i < n1){
      int c = i/(32*25), r = i - c*(32*25), ii = r/25, k = r - ii*25;
      w3t[(ii*25 + k)*64 + c] = ew3[i];
    } else {
      int j = i - n1;
      int ii = j/(64*25), r = j - ii*(64*25), o = r/25, k = r - o*25;
      float w = dwt[j];
      dwtt[(ii*25 + k)*64 + o] = w;
      wb7[((size_t)(k*64 + o))*64 + ii] = bf16rne(w);
    }
  }
}

// =========================================================================
// K_prep2: codebook -> pre-swizzled bf16 hi/lo rows + norms + plain bf16 cbb.
__global__ void k_prep2(const float* __restrict__ cb, unsigned short* __restrict__ cbsw,
                        float* __restrict__ cnw, float* __restrict__ cnw2,
                        unsigned short* __restrict__ cbb, int* cnt){
  if(blockIdx.x == 0 && threadIdx.x == 0) *cnt = 0;
  int j = blockIdx.x*256 + threadIdx.x;
  if(j < 8192){
    float nrm = 0.f;
    unsigned swz = (j & 15) << 4;
    char* rowp = (char*)cbsw + (size_t)j*256;
    #pragma unroll
    for(int k = 0; k < 64; k++){
      float x = cb[(size_t)j*64 + k];
      unsigned short hi = bf16rne(x);
      float lo = x - bf16tof(hi);
      *(unsigned short*)(rowp + (((unsigned)(2*k)) ^ swz)) = hi;
      *(unsigned short*)(rowp + (((unsigned)(128 + 2*k)) ^ swz)) = bf16rne(lo);
      cbb[(size_t)j*64 + k] = hi;
      nrm = fmaf(x, x, nrm);
    }
    cnw[j] = nrm;
    cnw2[j] = (nrm + 1024.f) * 256.f;
  }
}

// =========================================================================
// K1: conv1 (1->16, K=5, pad2) + silu + bn1 stats.
__global__ void k1(const float* __restrict__ x, const float* __restrict__ w1,
                   const float* __restrict__ b1, float* __restrict__ h1, float* stats){
  __shared__ float xs[136];
  __shared__ float ssum[16], ssq[16];
  int tid = threadIdx.x, b = blockIdx.y, t0 = blockIdx.x*128;
  if(tid < 16){ ssum[tid] = 0.f; ssq[tid] = 0.f; }
  for(int i = tid; i < 132; i += 256){
    int t = t0 + i - 2;
    xs[i] = (t >= 0 && t < 10240) ? x[b*10240 + t] : 0.f;
  }
  __syncthreads();
  int c = tid & 15, sgrp = tid >> 4;
  float w[5];
  #pragma unroll
  for(int k = 0; k < 5; k++) w[k] = w1[c*5 + k];
  float bias = b1[c];
  float outv[8];
  float ps = 0.f, pq = 0.f;
  #pragma unroll
  for(int s = 0; s < 8; s++){
    float a = bias;
    #pragma unroll
    for(int k = 0; k < 5; k++) a = fmaf(w[k], xs[sgrp*8 + s + k], a);
    a = siluf(a);
    outv[s] = a;
    ps += a; pq += a*a;
  }
  float* op = h1 + ((size_t)(b*16 + c))*10240 + t0 + sgrp*8;
  #pragma unroll
  for(int q = 0; q < 2; q++)
    *(float4*)(op + q*4) = make_float4(outv[q*4], outv[q*4+1], outv[q*4+2], outv[q*4+3]);
  ps += __shfl_xor(ps, 16); pq += __shfl_xor(pq, 16);
  ps += __shfl_xor(ps, 32); pq += __shfl_xor(pq, 32);
  if((tid & 48) == 0){ atomicAdd(&ssum[c], ps); atomicAdd(&ssq[c], pq); }
  __syncthreads();
  if(tid < 16){ atomicAdd(stats+S1+tid, ssum[tid]); atomicAdd(stats+Q1+tid, ssq[tid]); }
}

// =========================================================================
// K2: bn1 normalize + conv2 (16->32, K=5, pad2) + silu + bn2 stats.
__global__ __launch_bounds__(256) void k2(const float* __restrict__ h1,
                   const float* __restrict__ w2, const float* __restrict__ b2,
                   const float* __restrict__ g1, const float* __restrict__ bb1,
                   float* __restrict__ h2out, float* stats){
  __shared__ float hs[16][136];
  __shared__ float A1s[16], B1s[16];
  __shared__ float ssum[32], ssq[32];
  int tid = threadIdx.x, b = blockIdx.y, t0 = blockIdx.x*128;
  if(tid < 16){
    float mu = stats[S1+tid]/81920.f;
    float var = stats[Q1+tid]/81920.f - mu*mu;
    float rs = rsqrtf(var + 1e-5f);
    A1s[tid] = rs*g1[tid];
    B1s[tid] = bb1[tid] - mu*rs*g1[tid];
  }
  if(tid < 32){ ssum[tid] = 0.f; ssq[tid] = 0.f; }
  __syncthreads();
  {
    int ch = tid >> 4, j0 = tid & 15;
    float A = A1s[ch], B = B1s[ch];
    const float* hp = h1 + ((size_t)(b*16 + ch))*10240;
    for(int j = j0; j < 132; j += 16){
      int t = t0 + j - 2;
      hs[ch][j] = (t >= 0 && t < 10240) ? hp[t]*A + B : 0.f;
    }
  }
  __syncthreads();
  int c = tid & 31, tgrp = tid >> 5;
  int tb = tgrp*16;
  float acc[16];
  float bias = b2[c];
  #pragma unroll
  for(int s = 0; s < 16; s++) acc[s] = bias;
  for(int ic = 0; ic < 4; ic++){
    float wf[20];
    const float* wp = w2 + c*80 + ic*20;
    #pragma unroll
    for(int q = 0; q < 5; q++) *(float4*)(wf + q*4) = *(const float4*)(wp + q*4);
    #pragma unroll
    for(int di = 0; di < 4; di++){
      int i = ic*4 + di;
      float z[20];
      #pragma unroll
      for(int q = 0; q < 5; q++) *(float4*)(z + q*4) = *(const float4*)(&hs[i][tb] + q*4);
      float w0 = wf[di*5], w1 = wf[di*5+1], w2v = wf[di*5+2], w3 = wf[di*5+3], w4 = wf[di*5+4];
      #pragma unroll
      for(int s = 0; s < 16; s++)
        acc[s] = fmaf(w0, z[s], fmaf(w1, z[s+1], fmaf(w2v, z[s+2],
                 fmaf(w3, z[s+3], fmaf(w4, z[s+4], acc[s])))));
    }
  }
  float ps = 0.f, pq = 0.f;
  #pragma unroll
  for(int s = 0; s < 16; s++){
    float a = siluf(acc[s]);
    acc[s] = a;
    ps += a; pq += a*a;
  }
  float* op = h2out + ((size_t)(b*32 + c))*10240 + t0 + tb;
  #pragma unroll
  for(int q = 0; q < 4; q++)
    *(float4*)(op + q*4) = make_float4(acc[q*4], acc[q*4+1], acc[q*4+2], acc[q*4+3]);
  ps += __shfl_xor(ps, 32); pq += __shfl_xor(pq, 32);
  if((tid & 32) == 0){ atomicAdd(&ssum[c], ps); atomicAdd(&ssq[c], pq); }
  __syncthreads();
  if(tid < 32){ atomicAdd(stats+S2+tid, ssum[tid]); atomicAdd(stats+Q2+tid, ssq[tid]); }
}

// =========================================================================
// K3: bn2 normalize + conv3 (32->64, K=25, stride5, pad12) + tanh + bn3 stats
// zn holds RAW tanh outputs; bn3 affine applied by consumers (k5m/k5x/k_loss).
__global__ void k3(const float* __restrict__ h2, const float* __restrict__ w3t,
                   const float* __restrict__ eb3, const float* __restrict__ g2,
                   const float* __restrict__ bb2, float* __restrict__ zn, float* stats){
  __shared__ __align__(16) float X[5*32*24];
  __shared__ float A2[32], B2[32];
  __shared__ float ssum[64], ssq[64];
  int tid = threadIdx.x, b = blockIdx.y, l0 = blockIdx.x*16;
  if(tid < 32){
    float mu = stats[S2+tid]/81920.f;
    float var = stats[Q2+tid]/81920.f - mu*mu;
    float rs = rsqrtf(var + 1e-5f);
    A2[tid] = rs*g2[tid];
    B2[tid] = bb2[tid] - mu*rs*g2[tid];
  }
  if(tid < 64){ ssum[tid] = 0.f; ssq[tid] = 0.f; }
  __syncthreads();
  for(int i2 = tid; i2 < 5*32*20; i2 += 256){
    int kk = i2/640;
    int r  = i2 - kk*640;
    int ch = r/20, m = r - ch*20;
    int t = 5*(l0 + m) + kk - 12;
    float v = 0.f;
    if(t >= 0 && t < 10240) v = h2[((b*32+ch)*10240)+t]*A2[ch] + B2[ch];
    X[(kk*32+ch)*24 + m] = v;
  }
  __syncthreads();
  int c = tid & 63, lslot = tid >> 6;
  float acc[4];
  float bias = eb3[c];
  #pragma unroll
  for(int s = 0; s < 4; s++) acc[s] = bias;
  for(int i = 0; i < 32; i++){
    #pragma unroll
    for(int kk = 0; kk < 5; kk++){
      const float* xp = &X[(kk*32+i)*24 + lslot*4];
      float4 za = *(const float4*)(xp);
      float4 zb = *(const float4*)(xp + 4);
      float z[8] = {za.x,za.y,za.z,za.w,zb.x,zb.y,zb.z,zb.w};
      #pragma unroll
      for(int kap = 0; kap < 5; kap++){
        float w = w3t[(i*25 + kap*5 + kk)*64 + c];
        #pragma unroll
        for(int s = 0; s < 4; s++) acc[s] = fmaf(w, z[s+kap], acc[s]);
      }
    }
  }
  float ls = 0.f, lq = 0.f;
  #pragma unroll
  for(int s = 0; s < 4; s++){
    int l = l0 + lslot*4 + s;
    float a = tanhf(acc[s]);
    zn[((b*2048 + l)*64) + c] = a;
    ls += a; lq += a*a;
  }
  atomicAdd(&ssum[c], ls); atomicAdd(&ssq[c], lq);
  __syncthreads();
  if(tid < 64){ atomicAdd(stats+S3+tid, ssum[tid]); atomicAdd(stats+Q3+tid, ssq[tid]); }
}

// =========================================================================
// K5m: MFMA VQ pass, M=128 rows/block, (256,3) [round-9 best: 78us].
// bn3 affine fused into A-fragment build: v = fmaf(zraw, A3, B3).
__global__ __launch_bounds__(256, 3) void k5m(const float* __restrict__ zn,
    const unsigned short* __restrict__ cbsw, const float* __restrict__ cnw2,
    const float* __restrict__ g3, const float* __restrict__ b3,
    const float* __restrict__ stats,
    unsigned int* __restrict__ pbk, unsigned int* __restrict__ psk){
  __shared__ __align__(16) unsigned char cbuf[2][16384];
  __shared__ float A3s[64], B3s[64];
  int tid = threadIdx.x;
  int chunk = blockIdx.x;
  int m0 = blockIdx.y * 128;
  int lane = tid & 63, wr = tid >> 6;
  int h = lane >> 5, cll = lane & 31;
  int row = m0 + wr*32 + cll;

  if(tid < 64){
    float mu = stats[S3+tid]/16384.f;
    float var = stats[Q3+tid]/16384.f - mu*mu;
    float rs = rsqrtf(var + 1e-5f);
    A3s[tid] = rs*g3[tid];
    B3s[tid] = b3[tid] - mu*rs*g3[tid];
  }

  int c0 = chunk * 1024;
  const char* csrc = (const char*)cbsw + (size_t)c0*256;
  #pragma unroll
  for(int c2 = 0; c2 < 4; c2++)
    gl_lds(csrc + c2*4096 + tid*16, &cbuf[0][0] + c2*4096 + tid*16);
  __syncthreads();   // covers A3s and tile-0 staging

  s8v ah[4], al[4];
  const float* zp = zn + (size_t)row*64;
  #pragma unroll
  for(int s = 0; s < 4; s++){
    int koff = s*16 + h*8;
    float4 v0 = *(const float4*)(zp + koff);
    float4 v1 = *(const float4*)(zp + koff + 4);
    float vv[8] = {v0.x,v0.y,v0.z,v0.w,v1.x,v1.y,v1.z,v1.w};
    #pragma unroll
    for(int i = 0; i < 8; i++){
      float v = fmaf(vv[i], A3s[koff + i], B3s[koff + i]);
      unsigned short hi = bf16rne(v);
      ah[s][i] = (short)hi;
      al[s][i] = (short)bf16rne(v - bf16tof(hi));
    }
  }

  unsigned int bk[16], sk[16];
  #pragma unroll
  for(int r = 0; r < 16; r++){ bk[r] = 0xFFFFFFFFu; sk[r] = 0xFFFFFFFFu; }
  f32x16 zv;
  #pragma unroll
  for(int i = 0; i < 16; i++) zv[i] = 0.f;

  unsigned swz = (unsigned)(cll & 15) << 4;
  for(int tile = 0; tile < 16; ++tile){
    int bsel = tile & 1;
    if(tile < 15){
      const char* ns = csrc + (size_t)(tile+1)*16384;
      #pragma unroll
      for(int c2 = 0; c2 < 4; c2++)
        gl_lds(ns + c2*4096 + tid*16, &cbuf[bsel^1][0] + c2*4096 + tid*16);
    }
    #pragma unroll
    for(int half = 0; half < 2; half++){
      const unsigned char* bp = &cbuf[bsel][0] + (half*32 + cll)*256;
      s8v bh[4], bl[4];
      #pragma unroll
      for(int s = 0; s < 4; s++){
        bh[s] = *(const s8v*)(bp + (((unsigned)(s*32 + h*16)) ^ swz));
        bl[s] = *(const s8v*)(bp + (((unsigned)(128 + s*32 + h*16)) ^ swz));
      }
      unsigned col = (unsigned)(c0 + tile*64 + half*32 + cll);
      float cnv2 = cnw2[col];
      f32x16 a1 = __builtin_amdgcn_mfma_f32_32x32x16_bf16(ah[0], bh[0], zv, 0, 0, 0);
      f32x16 a2 = __builtin_amdgcn_mfma_f32_32x32x16_bf16(al[0], bh[0], zv, 0, 0, 0);
      a2 = __builtin_amdgcn_mfma_f32_32x32x16_bf16(ah[0], bl[0], a2, 0, 0, 0);
      #pragma unroll
      for(int s = 1; s < 4; s++){
        a1 = __builtin_amdgcn_mfma_f32_32x32x16_bf16(ah[s], bh[s], a1, 0, 0, 0);
        a2 = __builtin_amdgcn_mfma_f32_32x32x16_bf16(al[s], bh[s], a2, 0, 0, 0);
        a2 = __builtin_amdgcn_mfma_f32_32x32x16_bf16(ah[s], bl[s], a2, 0, 0, 0);
      }
      #pragma unroll
      for(int r = 0; r < 16; r++){
        float q = fmaf(-512.f, a1[r], cnv2);
        q = fmaf(-512.f, a2[r], q);
        q = fminf(q, 524287.f);
        unsigned k = (((unsigned)q) << 13) | col;
        unsigned nb = bk[r] < k ? bk[r] : k;
        sk[r] = umed3(sk[r], bk[r], k);
        bk[r] = nb;
      }
    }
    __syncthreads();
  }

  #pragma unroll
  for(int m = 1; m <= 16; m <<= 1){
    #pragma unroll
    for(int r = 0; r < 16; r++){
      unsigned int ob = (unsigned int)__shfl_xor((int)bk[r], m);
      unsigned int os = (unsigned int)__shfl_xor((int)sk[r], m);
      unsigned int s2 = sk[r] < os ? sk[r] : os;
      sk[r] = umed3(s2, bk[r], ob);
      bk[r] = bk[r] < ob ? bk[r] : ob;
    }
  }
  if(cll == 0){
    size_t base = (size_t)chunk*16384 + m0 + wr*32 + 4*h;
    #pragma unroll
    for(int r = 0; r < 16; r++){
      int lr = (r&3) + 8*(r>>2);
      pbk[base + lr] = bk[r];
      psk[base + lr] = sk[r];
    }
  }
}

// =========================================================================
// K5r: merge chunk partials; write idx; flag close calls.
__global__ void k5r(const unsigned int* __restrict__ pbk,
                    const unsigned int* __restrict__ psk, int* __restrict__ idxw,
                    float* __restrict__ out_idx, int* __restrict__ list, int* cnt){
  int row = blockIdx.x*256 + threadIdx.x;  // grid 64
  unsigned int bk = pbk[row], sk = psk[row];
  #pragma unroll
  for(int c = 1; c < NCHUNK; c++){
    unsigned int ob = pbk[(size_t)c*16384 + row];
    unsigned int os = psk[(size_t)c*16384 + row];
    unsigned int s2 = sk < os ? sk : os;
    sk = umed3(s2, bk, ob);
    bk = bk < ob ? bk : ob;
  }
  int idx = (int)(bk & 0x1FFFu);
  idxw[row] = idx;
  out_idx[row] = (float)idx;
  if((sk >> 13) - (bk >> 13) <= EPSQ){
    int p = atomicAdd(cnt, 1);
    list[p] = row;
  }
}

// =========================================================================
// K5x: exact f32 rescore, row-parallel; bn3 affine applied on z-row load.
__global__ __launch_bounds__(256) void k5x(const float* __restrict__ zn,
    const float* __restrict__ cb, const float* __restrict__ cnw,
    const float* __restrict__ g3, const float* __restrict__ b3,
    const float* __restrict__ stats,
    const int* __restrict__ list, const int* cnt,
    float* __restrict__ pxd, int* __restrict__ pxi){
  __shared__ float A3s[64], B3s[64];
  int tid = threadIdx.x;
  if(tid < 64){
    float mu = stats[S3+tid]/16384.f;
    float var = stats[Q3+tid]/16384.f - mu*mu;
    float rs = rsqrtf(var + 1e-5f);
    A3s[tid] = rs*g3[tid];
    B3s[tid] = b3[tid] - mu*rs*g3[tid];
  }
  __syncthreads();
  int chunk = blockIdx.x;
  int n = *cnt;
  int rgrp = tid >> 6, cs = tid & 63;
  int c0 = chunk * 1024;
  for(int bat = blockIdx.y; bat*4 < n; bat += 256){
    int e = bat*4 + rgrp;
    int ec = e < n ? e : n-1;
    int row = list[ec];
    float4 zr[16];
    const float4* zp = (const float4*)(zn + (size_t)row*64);
    #pragma unroll
    for(int q = 0; q < 16; q++){
      float4 v = zp[q];
      v.x = fmaf(v.x, A3s[q*4+0], B3s[q*4+0]);
      v.y = fmaf(v.y, A3s[q*4+1], B3s[q*4+1]);
      v.z = fmaf(v.z, A3s[q*4+2], B3s[q*4+2]);
      v.w = fmaf(v.w, A3s[q*4+3], B3s[q*4+3]);
      zr[q] = v;
    }
    float bd = 3.4e38f; int bi = 0;
    for(int step = 0; step < 16; step++){
      int j = c0 + step*64 + cs;
      const float4* cp = (const float4*)(cb + (size_t)j*64);
      float cnv = cnw[j];
      float da = 0.f, db = 0.f;
      #pragma unroll
      for(int q = 0; q < 16; q += 2){
        float4 ca = cp[q], cb4 = cp[q+1];
        da = fmaf(ca.x, zr[q].x, da);  da = fmaf(ca.y, zr[q].y, da);
        da = fmaf(ca.z, zr[q].z, da);  da = fmaf(ca.w, zr[q].w, da);
        db = fmaf(cb4.x, zr[q+1].x, db); db = fmaf(cb4.y, zr[q+1].y, db);
        db = fmaf(cb4.z, zr[q+1].z, db); db = fmaf(cb4.w, zr[q+1].w, db);
      }
      float d = fmaf(-2.f, da + db, cnv);
      if(d < bd){ bd = d; bi = j; }
    }
    #pragma unroll
    for(int m = 1; m <= 32; m <<= 1){
      float od = __shfl_xor(bd, m);
      int   oi = __shfl_xor(bi, m);
      if(od < bd || (od == bd && oi < bi)){ bd = od; bi = oi; }
    }
    if(cs == 0 && e < n){
      pxd[(size_t)chunk*16384 + e] = bd;
      pxi[(size_t)chunk*16384 + e] = bi;
    }
  }
}

// =========================================================================
// K5x2: merge chunk partials per flagged row -> final idx.
__global__ void k5x2(const float* __restrict__ pxd, const int* __restrict__ pxi,
                     const int* __restrict__ list, const int* cnt,
                     int* __restrict__ idxw, float* __restrict__ out_idx){
  int e = blockIdx.x*256 + threadIdx.x;  // grid 64
  int n = *cnt;
  if(e >= n) return;
  float bd = pxd[e]; int bi = pxi[e];
  #pragma unroll
  for(int c = 1; c < NCHUNK; c++){
    float od = pxd[(size_t)c*16384 + e];
    int   oi = pxi[(size_t)c*16384 + e];
    if(od < bd || (od == bd && oi < bi)){ bd = od; bi = oi; }
  }
  int row = list[e];
  idxw[row] = bi;
  out_idx[row] = (float)bi;
}

// =========================================================================
// K_loss: commit loss from final indices; bn3 affine applied on z load.
__global__ void k_loss(const float* __restrict__ zn, const float* __restrict__ cb,
                       const float* __restrict__ g3, const float* __restrict__ b3,
                       const int* __restrict__ idxw, float* stats){
  __shared__ float A3s[64], B3s[64];
  int tid = threadIdx.x;
  if(tid < 64){
    float mu = stats[S3+tid]/16384.f;
    float var = stats[Q3+tid]/16384.f - mu*mu;
    float rs = rsqrtf(var + 1e-5f);
    A3s[tid] = rs*g3[tid];
    B3s[tid] = b3[tid] - mu*rs*g3[tid];
  }
  __syncthreads();
  int row = blockIdx.x*256 + tid;  // grid 64
  int code = idxw[row];
  const float* cp = cb + (size_t)code*64;
  const float* zp = zn + (size_t)row*64;
  float s = 0.f;
  #pragma unroll
  for(int k = 0; k < 64; k++){
    float v = fmaf(zp[k], A3s[k], B3s[k]);
    float dd = cp[k] - v;
    s = fmaf(dd, dd, s);
  }
  float tot = wredsum(s);
  if((tid & 63) == 0) atomicAdd(stats + SLOSS, tot);
}

// =========================================================================
// K7m: transposed conv as MFMA GEMM (unchanged).
__global__ __launch_bounds__(320) void k7m(const int* __restrict__ idxp,
    const unsigned short* __restrict__ cbb, const unsigned short* __restrict__ wb7,
    unsigned short* __restrict__ h4t, float* stats){
  __shared__ __align__(16) unsigned char lA[37*128];
  __shared__ float tb[5*64*33];
  __shared__ float ssum[64], ssq[64];
  int tid = threadIdx.x, b = blockIdx.y, u0 = blockIdx.x*32;
  if(tid < 64){ ssum[tid] = 0.f; ssq[tid] = 0.f; }
  {
    int m = tid >> 3, part = tid & 7;
    if(m < 37){
      int u = u0 - 2 + m;
      uint4 val = make_uint4(0,0,0,0);
      if(u >= 0 && u < 2048){
        int code = idxp[b*2048 + u];
        val = *(const uint4*)((const char*)cbb + (size_t)code*128 + part*16);
      }
      *(uint4*)(lA + m*128 + (((unsigned)(part*16)) ^ (((unsigned)m & 7) << 4))) = val;
    }
  }
  __syncthreads();
  int lane = tid & 63, h = lane >> 5, cl = lane & 31;
  int v = tid >> 6;
  const int km[5]  = {2,3,4,0,1};
  const int ovv[5] = {2,2,2,3,3};
  f32x16 acc0, acc1;
  #pragma unroll
  for(int i = 0; i < 16; i++){ acc0[i] = 0.f; acc1[i] = 0.f; }
  #pragma unroll
  for(int r = 0; r < 5; r++){
    int off = ovv[v] - r + 2;
    int m = cl + off;
    unsigned aswz = ((unsigned)m & 7) << 4;
    int k = km[v] + 5*r;
    const char* b0p = (const char*)wb7 + (size_t)(k*64 + cl)*128;
    const char* b1p = b0p + 32*128;
    #pragma unroll
    for(int s = 0; s < 4; s++){
      unsigned o = (unsigned)(s*32 + h*16);
      s8v a  = *(const s8v*)(lA + m*128 + (o ^ aswz));
      s8v b0 = *(const s8v*)(b0p + o);
      s8v b1 = *(const s8v*)(b1p + o);
      acc0 = __builtin_amdgcn_mfma_f32_32x32x16_bf16(a, b0, acc0, 0, 0, 0);
      acc1 = __builtin_amdgcn_mfma_f32_32x32x16_bf16(a, b1, acc1, 0, 0, 0);
    }
  }
  float ps0 = 0.f, pq0 = 0.f, ps1 = 0.f, pq1 = 0.f;
  #pragma unroll
  for(int r = 0; r < 16; r++){
    int ul = (r&3) + 8*(r>>2) + 4*h;
    int u = u0 + ul;
    float v0 = siluf(acc0[r]), v1 = siluf(acc1[r]);
    tb[(v*64 + cl)*33 + ul]      = v0;
    tb[(v*64 + 32 + cl)*33 + ul] = v1;
    if(v == 0 || u < 2047){ ps0 += v0; pq0 += v0*v0; ps1 += v1; pq1 += v1*v1; }
  }
  atomicAdd(&ssum[cl], ps0);      atomicAdd(&ssq[cl], pq0);
  atomicAdd(&ssum[32 + cl], ps1); atomicAdd(&ssq[32 + cl], pq1);
  __syncthreads();
  if(tid < 64){ atomicAdd(stats+S4+tid, ssum[tid]); atomicAdd(stats+Q4+tid, ssq[tid]); }
  #pragma unroll
  for(int j = 0; j < 16; j++){
    int flat = j*320 + tid;
    int tl = flat >> 5;
    int chp = flat & 31;
    int t = u0*5 + tl;
    if(t < 10236){
      int vv = tl % 5, ul = tl / 5;
      float f0 = tb[(vv*64 + 2*chp)*33 + ul];
      float f1 = tb[(vv*64 + 2*chp + 1)*33 + ul];
      unsigned int pk = (unsigned int)bf16rne(f0) | ((unsigned int)bf16rne(f1) << 16);
      size_t rowb = ((size_t)b*10248 + 2 + t)*128;
      *(unsigned int*)((char*)h4t + rowb + (((unsigned)(4*chp)) ^ (((unsigned)t & 7) << 4))) = pk;
    }
  }
}

// =========================================================================
// K8w: fold dbn1 into decoder conv2 weights + beta; also zero h4t pad rows.
__global__ void k8w(const float* __restrict__ w2d, const float* __restrict__ b2d,
                    const float* __restrict__ g4, const float* __restrict__ bb4,
                    const float* __restrict__ stats, unsigned short* __restrict__ wbt,
                    float* __restrict__ beta, unsigned int* __restrict__ h4tz){
  __shared__ float A4[64], B4[64];
  int tid = threadIdx.x;
  for(int i = tid; i < 3072; i += 256){
    int b = i / 384, r = i - b*384;
    int row12 = r >> 5, word = r & 31;
    int row = row12 < 2 ? row12 : 10236 + row12;
    h4tz[((size_t)b*10248 + row)*32 + word] = 0u;
  }
  if(tid < 64){
    float mu = stats[S4+tid]/81888.f;
    float var = stats[Q4+tid]/81888.f - mu*mu;
    float rs = rsqrtf(var + 1e-5f);
    A4[tid] = rs*g4[tid];
    B4[tid] = bb4[tid] - mu*rs*g4[tid];
  }
  __syncthreads();
  for(int e = tid; e < 64*64*5; e += 256){
    int c = e/320, r = e - c*320, i = r/5, k = r - i*5;
    unsigned short hw = bf16rne(w2d[e] * A4[i]);
    int row = k*64 + c;
    *(unsigned short*)((char*)wbt + (size_t)row*128 + (((unsigned)(2*i)) ^ (((unsigned)c & 7) << 4))) = hw;
  }
  if(tid < 64){
    float s = b2d[tid];
    for(int i = 0; i < 64; i++){
      float wsum = 0.f;
      #pragma unroll
      for(int k = 0; k < 5; k++) wsum += w2d[(tid*64 + i)*5 + k];
      s += wsum * B4[i];
    }
    beta[tid] = s;
  }
}

// =========================================================================
// K8: decoder conv2 as MFMA GEMM (unchanged).
__global__ __launch_bounds__(256) void k8(const unsigned short* __restrict__ h4t,
    const unsigned short* __restrict__ wbt, const float* __restrict__ beta,
    unsigned short* __restrict__ h5b, float* stats){
  __shared__ __align__(16) unsigned char lA[68*128];
  __shared__ float ssum[64], ssq[64];
  int tid = threadIdx.x, b = blockIdx.y, t0 = blockIdx.x*64;
  if(tid < 64){ ssum[tid] = 0.f; ssq[tid] = 0.f; }
  const char* srcA = (const char*)h4t + ((size_t)b*10248 + t0)*128;
  #pragma unroll
  for(int c2 = 0; c2 < 2; c2++)
    gl_lds(srcA + c2*4096 + tid*16, lA + c2*4096 + tid*16);
  if(tid < 32) gl_lds(srcA + 8192 + tid*16, lA + 8192 + tid*16);
  __syncthreads();

  int lane = tid & 63, h = lane >> 5, cl = lane & 31;
  int widx = tid >> 6;
  int wt0 = (widx >> 1) * 32;
  int wch = (widx & 1) * 32;
  f32x16 acc;
  #pragma unroll
  for(int i = 0; i < 16; i++) acc[i] = 0.f;
  unsigned bswz = (unsigned)(cl & 7) << 4;
  #pragma unroll
  for(int k = 0; k < 5; k++){
    int l = wt0 + cl + k;
    unsigned aswz = (unsigned)((l + 6) & 7) << 4;
    const char* bp = (const char*)wbt + (size_t)(k*64 + wch + cl)*128;
    #pragma unroll
    for(int s = 0; s < 4; s++){
      unsigned o = (unsigned)(s*32 + h*16);
      s8v a  = *(const s8v*)(lA + l*128 + (o ^ aswz));
      s8v bb = *(const s8v*)(bp + (o ^ bswz));
      acc = __builtin_amdgcn_mfma_f32_32x32x16_bf16(a, bb, acc, 0, 0, 0);
    }
  }
  float bet = beta[wch + cl];
  float ps = 0.f, pq = 0.f;
  #pragma unroll
  for(int r = 0; r < 16; r++){
    int t = t0 + wt0 + (r&3) + 8*(r>>2) + 4*h;
    float v0 = siluf(acc[r] + bet);
    if(t < 10236){
      h5b[((size_t)b*10240 + t)*64 + wch + cl] = bf16rne(v0);
      ps += v0; pq += v0*v0;
    }
  }
  atomicAdd(&ssum[wch + cl], ps); atomicAdd(&ssq[wch + cl], pq);
  __syncthreads();
  if(tid < 64){ atomicAdd(stats+S5+tid, ssum[tid]); atomicAdd(stats+Q5+tid, ssq[tid]); }
}

// =========================================================================
// K9: dbn2 normalize + 1x1 conv (64->1) + bias; also writes commit loss.
__global__ void k9(const unsigned short* __restrict__ h5b, const float* __restrict__ w3,
                   const float* __restrict__ b3, const float* __restrict__ g5,
                   const float* __restrict__ bb5, const float* stats,
                   float* __restrict__ out){
  __shared__ float WA[64], WB[64];
  int tid = threadIdx.x;
  if(blockIdx.x == 0 && blockIdx.y == 0 && tid == 0)
    out[98304] = 2.f * stats[SLOSS] / 1048576.f;
  if(tid < 64){
    float mu = stats[S5+tid]/81888.f;
    float var = stats[Q5+tid]/81888.f - mu*mu;
    float rs = rsqrtf(var + 1e-5f);
    float A = rs*g5[tid], B = bb5[tid] - mu*rs*g5[tid];
    float w = w3[tid];
    WA[tid] = w*A; WB[tid] = w*B;
  }
  __syncthreads();
  int b = blockIdx.y;
  int t = blockIdx.x*256 + tid;
  float acc = b3[0];
  if(t < 10236){
    const unsigned short* hp = h5b + ((size_t)b*10240 + t)*64;
    #pragma unroll
    for(int q = 0; q < 8; q++){
      uint4 u = *(const uint4*)(hp + q*8);
      unsigned int ua[4] = {u.x, u.y, u.z, u.w};
      #pragma unroll
      for(int w = 0; w < 4; w++){
        int c = q*8 + w*2;
        acc += WA[c]*bf16tof((unsigned short)(ua[w] & 0xFFFFu)) + WB[c];
        acc += WA[c+1]*bf16tof((unsigned short)(ua[w] >> 16)) + WB[c+1];
      }
    }
  } else acc = 0.f;
  out[b*10240 + t] = acc;
}

// =========================================================================
extern "C" void kernel_launch(void* const* d_in, const int* in_sizes, int n_in,
                              void* d_out, int out_size, void* d_ws, size_t ws_size,
                              hipStream_t stream){
  const float* x   = (const float*)d_in[0];
  const float* ew1 = (const float*)d_in[1];
  const float* eb1 = (const float*)d_in[2];
  const float* g1  = (const float*)d_in[3];
  const float* bb1 = (const float*)d_in[4];
  const float* ew2 = (const float*)d_in[5];
  const float* eb2 = (const float*)d_in[6];
  const float* g2  = (const float*)d_in[7];
  const float* bb2 = (const float*)d_in[8];
  const float* ew3 = (const float*)d_in[9];
  const float* eb3 = (const float*)d_in[10];
  const float* g3  = (const float*)d_in[11];
  const float* bb3 = (const float*)d_in[12];
  const float* cb  = (const float*)d_in[13];
  const float* dwt = (const float*)d_in[14];
  const float* g4  = (const float*)d_in[15];
  const float* bb4 = (const float*)d_in[16];
  const float* w2d = (const float*)d_in[17];
  const float* b2d = (const float*)d_in[18];
  const float* g5  = (const float*)d_in[19];
  const float* bb5 = (const float*)d_in[20];
  const float* w3d = (const float*)d_in[21];
  const float* b3d = (const float*)d_in[22];

  char* ws = (char*)d_ws;
  float* h1   = (float*)(ws + 0);
  unsigned short* cbsw = (unsigned short*)(ws + 0);         // 2,097,152
  float* cnw  = (float*)(ws + 2097152);                     // 32,768
  float* cnw2 = (float*)(ws + 2129920);                     // 32,768
  float* h2   = (float*)(ws + 5242880);
  float* zn   = (float*)(ws + 15728640);
  unsigned short* h4t = (unsigned short*)(ws + 0);          // 10,493,952
  unsigned short* h5b = (unsigned short*)(ws + 20971520);   // 10,485,760
  int*   list = (int*)  (ws + 20971520);                    // 65,536 (time-disjoint vs h5b)
  int*   cnt  = (int*)  (ws + 21037056);                    // 256
  unsigned int* pbk = (unsigned int*)(ws + 21037312);       // 524,288
  unsigned int* psk = (unsigned int*)(ws + 21561600);       // 524,288
  float* pxd  = (float*)(ws + 22085888);                    // 524,288
  int*   pxi  = (int*)  (ws + 22610176);                    // 524,288
  unsigned short* wbt = (unsigned short*)(ws + 31457280);   // 40,960
  float* beta = (float*)(ws + 31498240);                    // 256
  unsigned short* wb7 = (unsigned short*)(ws + 32000000);   // 204,800 (gap)
  unsigned short* cbb = (unsigned short*)(ws + 32300032);   // 1,048,576 (gap)
  float* w3t  = (float*)(ws + 41934848);
  float* dwtt = (float*)(ws + 42139648);
  int*   idxw = (int*)  (ws + 42549248);
  float* stats= (float*)(ws + 42614784);
  if(ws_size < 42616832) return;

  float* out = (float*)d_out;  // f32: [recon 81920][idx 16384][loss 1]

  hipMemsetAsync(stats, 0, NSTATF*4, stream);
  k_prep<<<600, 256, 0, stream>>>(ew3, dwt, w3t, dwtt, wb7);
  k1<<<dim3(80,8), 256, 0, stream>>>(x, ew1, eb1, h1, stats);
  k2<<<dim3(80,8), 256, 0, stream>>>(h1, ew2, eb2, g1, bb1, h2, stats);
  k_prep2<<<32, 256, 0, stream>>>(cb, cbsw, cnw, cnw2, cbb, cnt);
  k3<<<dim3(128,8), 256, 0, stream>>>(h2, w3t, eb3, g2, bb2, zn, stats);
  k5m<<<dim3(NCHUNK,128), 256, 0, stream>>>(zn, cbsw, cnw2, g3, bb3, stats, pbk, psk);
  k5r<<<64, 256, 0, stream>>>(pbk, psk, idxw, out + 81920, list, cnt);
  k5x<<<dim3(NCHUNK,256), 256, 0, stream>>>(zn, cb, cnw, g3, bb3, stats, list, cnt, pxd, pxi);
  k5x2<<<64, 256, 0, stream>>>(pxd, pxi, list, cnt, idxw, out + 81920);
  k_loss<<<64, 256, 0, stream>>>(zn, cb, g3, bb3, idxw, stats);
  k7m<<<dim3(64,8), 320, 0, stream>>>(idxw, cbb, wb7, h4t, stats);
  k8w<<<1, 256, 0, stream>>>(w2d, b2d, g4, bb4, stats, wbt, beta, (unsigned int*)h4t);
  k8<<<dim3(160,8), 256, 0, stream>>>(h4t, wbt, beta, h5b, stats);
  k9<<<dim3(40,8), 256, 0, stream>>>(h5b, w3d, b3d, g5, bb5, stats, out);
}